// Round 13
// baseline (72.735 us; speedup 1.0000x reference)
//
#include <hip/hip_runtime.h>

#define EPSLN 1e-5f

typedef short bf16x8 __attribute__((ext_vector_type(8)));
typedef float f32x4 __attribute__((ext_vector_type(4)));
typedef unsigned short u16;
typedef unsigned short u16x8 __attribute__((ext_vector_type(8)));

__device__ __forceinline__ float wsum(float v){
  #pragma unroll
  for(int o=32;o;o>>=1) v += __shfl_xor(v,o);
  return v;
}
__device__ __forceinline__ float wmax(float v){
  #pragma unroll
  for(int o=32;o;o>>=1) v = fmaxf(v,__shfl_xor(v,o));
  return v;
}
__device__ __forceinline__ u16 f2bf(float f){
  unsigned int u = __float_as_uint(f);
  u = (u + 0x7FFFu + ((u>>16)&1u)) >> 16;
  return (u16)u;
}
__device__ __forceinline__ float bf2f(u16 h){
  return __uint_as_float(((unsigned int)h)<<16);
}

// k1: blocks 0..127 = kB (self-sufficient: recomputes xe/xa from xin; blocks
//     0..15 also pack W2); blocks 128..1151 = kA-lite (Sv/SSv + bf16 packs).
__global__ void __launch_bounds__(256) k1(
    const float* __restrict__ xin, const float* __restrict__ pxp,
    const float* __restrict__ W2,  const float* __restrict__ sw,
    const float* __restrict__ bs,  const float* __restrict__ om,
    const float* __restrict__ tau, const float* __restrict__ temp,
    float* __restrict__ Sv, float* __restrict__ SSv,
    u16* __restrict__ xinb, u16* __restrict__ phi, u16* __restrict__ plo,
    u16* __restrict__ w2B,
    float* __restrict__ er2, float* __restrict__ mask, float* __restrict__ cc){
  __shared__ float shmF[1172];   // swL 1072 | bsL 16 | omL 16 | red 4 | redE 64
  int tid = threadIdx.x;
  if(blockIdx.x < 128){
    // ---- kB body (xe/xa self-computed) ----
    float* swL = shmF;
    float* bsL = swL + 1072;
    float* omL = bsL + 16;
    float* red = omL + 16;
    float* redE= red + 4;              // [16][4]
    int bi = blockIdx.x;               // (b*16+i)
    int i = bi & 15;
    int w = tid>>6, lane = tid&63;
    for(int k=tid;k<16*67;k+=256) swL[k] = sw[i*16*67 + k];
    if(tid<16){ bsL[tid]=bs[i*16+tid]; omL[tid]=fabsf(om[i*16+tid]); }
    float xs=0.f, xas=0.f;
    {
      const float4* xr = (const float4*)(xin + ((size_t)bi*256 + tid)*64);
      #pragma unroll
      for(int k=0;k<16;k++){
        float4 v4 = xr[k];
        xs  += v4.x+v4.y+v4.z+v4.w;
        xas += fabsf(v4.x)+fabsf(v4.y)+fabsf(v4.z)+fabsf(v4.w);
      }
    }
    float v   = xs *(1.f/64.f);
    float xav = xas*(1.f/64.f);
    float m = wmax(fabsf(v));
    if(lane==0) red[w]=m;
    __syncthreads();
    m = fmaxf(fmaxf(red[0],red[1]),fmaxf(red[2],red[3]));
    float xn = v/(m+1e-8f);
    xn = fminf(fmaxf(xn,-0.99f),0.99f);
    float sil = xn/(1.f+expf(-xn));
    float vv = (xn+1.f)*33.f;
    int c0 = (int)floorf(vv)-1;
    float acc[16];
    #pragma unroll
    for(int j=0;j<16;j++) acc[j]=0.f;
    #pragma unroll
    for(int k=0;k<4;k++){
      int c = c0+k;
      if(c<0||c>66) continue;
      float d = fabsf(vv-(float)c);
      float bas = d<1.f ? (2.f/3.f - d*d + d*d*d*0.5f)
                : (d<2.f ? (2.f-d)*(2.f-d)*(2.f-d)*(1.f/6.f) : 0.f);
      #pragma unroll
      for(int j=0;j<16;j++) acc[j] += bas*swL[j*67+c];
    }
    #pragma unroll
    for(int j=0;j<16;j++){
      float ev = sil*bsL[j] + acc[j] + omL[j];
      er2[(bi*16+j)*256+tid] = ev;
      float pe = wsum(fabsf(ev)*xav);
      if(lane==0) redE[j*4+w]=pe;
    }
    __syncthreads();
    if(tid<16){
      float e = (redE[tid*4+0]+redE[tid*4+1]+redE[tid*4+2]+redE[tid*4+3])*(1.f/256.f);
      float tv = fabsf(temp[0])+1e-4f;
      float ta = fabsf(tau[i*16+tid]);
      float mk = 1.f/(1.f+expf(-(e-ta)/tv));
      mask[bi*16+tid]=mk;
      cc[bi*16+tid]= e/(ta+1e-8f)*mk;
    }
    if(bi<16){
      int j = bi;
      for(int idx=tid; idx<4096; idx+=256){
        int f = idx>>6, o = idx&63;
        float vw = W2[j*4096 + idx];
        int ks = f>>5, kb = (f>>3)&3, ii = f&7;
        int nt = o>>4, col = o&15;
        int ln = kb*16 + col;
        w2B[((j*2+ks)*4 + nt)*512 + ln*8 + ii] = f2bf(vw);
      }
    }
  } else {
    // ---- kA-lite body ----
    int rl = tid>>3, q = tid&7;
    int row = (blockIdx.x-128)*32 + rl;
    const float4* xr = (const float4*)(xin + row*64 + q*8);
    const float4* pr = (const float4*)(pxp + row*64 + q*8);
    float s3=0.f,s4=0.f;
    u16x8 xb, ph, pl;
    #pragma unroll
    for(int k=0;k<2;k++){
      float4 xv = xr[k];
      float4 pv = pr[k];
      s3 += pv.x+pv.y+pv.z+pv.w;
      s4 += pv.x*pv.x+pv.y*pv.y+pv.z*pv.z+pv.w*pv.w;
      int o = k*4;
      xb[o+0]=f2bf(xv.x); xb[o+1]=f2bf(xv.y); xb[o+2]=f2bf(xv.z); xb[o+3]=f2bf(xv.w);
      u16 h0=f2bf(pv.x), h1=f2bf(pv.y), h2=f2bf(pv.z), h3=f2bf(pv.w);
      ph[o+0]=h0; ph[o+1]=h1; ph[o+2]=h2; ph[o+3]=h3;
      pl[o+0]=f2bf(pv.x-bf2f(h0)); pl[o+1]=f2bf(pv.y-bf2f(h1));
      pl[o+2]=f2bf(pv.z-bf2f(h2)); pl[o+3]=f2bf(pv.w-bf2f(h3));
    }
    *(u16x8*)(xinb + row*64 + q*8) = xb;
    *(u16x8*)(phi  + row*64 + q*8) = ph;
    *(u16x8*)(plo  + row*64 + q*8) = pl;
    s3 += __shfl_xor(s3,1); s3 += __shfl_xor(s3,2); s3 += __shfl_xor(s3,4);
    s4 += __shfl_xor(s4,1); s4 += __shfl_xor(s4,2); s4 += __shfl_xor(s4,4);
    if(q==0){ Sv[row]=s3; SSv[row]=s4; }
  }
}

// k2: blocks 0..1023 = E2 gram MFMA, fragments loaded DIRECTLY from global
//     (no LDS, no barriers); blocks 1024..3071 = kD (2.1KB LDS, 8 blocks/CU).
__global__ void __launch_bounds__(256) k2(
    const u16* __restrict__ phi, const u16* __restrict__ plo, float* __restrict__ G,
    const u16* __restrict__ xinb, const float* __restrict__ er2,
    const float* __restrict__ mask, const u16* __restrict__ w2B,
    const float* __restrict__ lnw, const float* __restrict__ lnb,
    const float* __restrict__ bp,
    u16* __restrict__ xvb, float* __restrict__ xp, u16* __restrict__ xpB){
  __shared__ __align__(16) unsigned char shm[2112];   // kD only
  int tid = threadIdx.x;
  if(blockIdx.x < 1024){
    // ---- E2 body: register-direct fragments ----
    int e = blockIdx.x;
    int b = e&7, m = (e>>3)&7, sx = (e>>6)&3, ty = e>>8;  // b lowest -> XCD=b
    int bm = b*8+m;
    int s0 = sx*64, t0 = ty*64;
    int w = tid>>6, lane = tid&63;
    int lr = lane&15, hk = lane>>4;     // frag row/col, k-octet
    size_t aoff = ((size_t)(b*16+m  )*256 + s0 + w*16 + lr)*64 + hk*8;
    size_t boff = ((size_t)(b*16+m+8)*256 + t0        + lr)*64 + hk*8;
    bf16x8 ah0 = *(const bf16x8*)(phi + aoff);
    bf16x8 ah1 = *(const bf16x8*)(phi + aoff + 32);
    bf16x8 al0 = *(const bf16x8*)(plo + aoff);
    bf16x8 al1 = *(const bf16x8*)(plo + aoff + 32);
    f32x4 acc[4];
    #pragma unroll
    for(int tt=0;tt<4;tt++) acc[tt] = (f32x4){0.f,0.f,0.f,0.f};
    #pragma unroll
    for(int tt=0;tt<4;tt++){
      size_t bo = boff + (size_t)tt*16*64;
      bf16x8 bh0 = *(const bf16x8*)(phi + bo);
      bf16x8 bh1 = *(const bf16x8*)(phi + bo + 32);
      bf16x8 bl0 = *(const bf16x8*)(plo + bo);
      bf16x8 bl1 = *(const bf16x8*)(plo + bo + 32);
      acc[tt] = __builtin_amdgcn_mfma_f32_16x16x32_bf16(ah0, bh0, acc[tt], 0,0,0);
      acc[tt] = __builtin_amdgcn_mfma_f32_16x16x32_bf16(ah1, bh1, acc[tt], 0,0,0);
      acc[tt] = __builtin_amdgcn_mfma_f32_16x16x32_bf16(ah0, bl0, acc[tt], 0,0,0);
      acc[tt] = __builtin_amdgcn_mfma_f32_16x16x32_bf16(ah1, bl1, acc[tt], 0,0,0);
      acc[tt] = __builtin_amdgcn_mfma_f32_16x16x32_bf16(al0, bh0, acc[tt], 0,0,0);
      acc[tt] = __builtin_amdgcn_mfma_f32_16x16x32_bf16(al1, bh1, acc[tt], 0,0,0);
    }
    int col = lane&15, r4 = lane>>4;
    #pragma unroll
    for(int tt=0;tt<4;tt++){
      #pragma unroll
      for(int r=0;r<4;r++){
        G[((size_t)bm*256 + s0 + w*16 + r4*4 + r)*256 + t0 + tt*16 + col] = acc[tt][r];
      }
    }
  } else {
    // ---- kD body ----
    int idx = blockIdx.x - 1024;        // 1024%8==0 -> XCD = b preserved
    int b = idx&7, j = (idx>>3)&15, st = idx>>7;
    int w = tid>>6, lane = tid&63;
    u16* xnS = (u16*)shm;               // 2KB bf16, XOR-swizzled
    float* mcL = (float*)(shm + 2048);
    if(tid<16) mcL[tid]=mask[(b*16+tid)*16+j];
    __syncthreads();
    float lw = lnw[j*64+lane], lb = lnb[j*64+lane];
    int bj = b*16+j;
    unsigned char* xnB = (unsigned char*)xnS;
    #pragma unroll
    for(int ri=0;ri<4;ri++){
      int sl = w*4 + ri;
      int s = st*16 + sl;
      float acc=0.f;
      #pragma unroll
      for(int i=0;i<16;i++){
        acc += er2[((b*16+i)*16+j)*256+s]*mcL[i]*bf2f(xinb[((b*16+i)*256+s)*64+lane]);
      }
      float xval = acc*(1.f/16.f);
      xvb[((size_t)bj*256+s)*64+lane]=f2bf(xval);
      float mu = wsum(xval)*(1.f/64.f);
      float dv = xval-mu;
      float var = wsum(dv*dv)*(1.f/64.f);
      float xnv = dv*rsqrtf(var+EPSLN)*lw + lb;
      *(u16*)(xnB + ((sl*128 + lane*2) ^ ((sl&7)<<4))) = f2bf(xnv);
    }
    __syncthreads();
    f32x4 acc = {0.f,0.f,0.f,0.f};
    int m = lane&15, kb = lane>>4;
    #pragma unroll
    for(int ks=0;ks<2;ks++){
      bf16x8 a = *(const bf16x8*)(xnB + ((m*128 + ks*64 + kb*16) ^ ((m&7)<<4)));
      bf16x8 bfr = *(const bf16x8*)(w2B + ((j*2+ks)*4 + w)*512 + lane*8);
      acc = __builtin_amdgcn_mfma_f32_16x16x32_bf16(a, bfr, acc, 0, 0, 0);
    }
    int f = w*16 + m;
    u16 pk[4];
    #pragma unroll
    for(int r=0;r<4;r++){
      int si = kb*4 + r;
      int s = st*16 + si;
      float xpr = acc[r] + bp[((size_t)j*256+s)*64+f];
      xp[((size_t)bj*256+s)*64+f] = xpr;
      pk[r] = f2bf(xpr);
    }
    int s0 = st*16 + kb*4;
    int flat = ((s0>>5)*4 + w)*512 + ((s0>>3)&3)*128 + m*8 + (s0&7);
    *(ushort4*)(xpB + (size_t)bj*16384 + flat) = *(ushort4*)pk;
  }
}

// kF: 2 j per block; LDS 25.5KB; defer-max softmax; MFMA AV; LDS conv;
//     residuals. b in blockIdx.x -> XCD=b.
__global__ void __launch_bounds__(256) kF(
    const float* __restrict__ G, const float* __restrict__ cc,
    const float* __restrict__ Sv, const float* __restrict__ SSv,
    const float* __restrict__ xp, const u16* __restrict__ xpB,
    const float* __restrict__ cw,
    const u16* __restrict__ xarrb, const float* __restrict__ temp,
    const float* __restrict__ alpha, const float* __restrict__ beta,
    const float* __restrict__ gamma_, const float* __restrict__ theta,
    float* __restrict__ out){
  int b = blockIdx.x, jp = blockIdx.y, st = blockIdx.z;
  int j0 = jp*2, j1 = j0+1;
  int tid = threadIdx.x, w = tid>>6, lane = tid&63;
  __shared__ __align__(16) unsigned char ovl[26112];
  unsigned char* prB0 = ovl;
  unsigned char* prB1 = ovl + 8192;
  float* mQL0 = (float*)(ovl + 16384);
  float* rQL0 = (float*)(ovl + 17408);
  float* mQL1 = (float*)(ovl + 18432);
  float* rQL1 = (float*)(ovl + 19456);
  float* mK2  = (float*)(ovl + 20480);   // [2][16]
  float* rK2  = (float*)(ovl + 20608);   // [2][16]
  float* xpT  = (float*)ovl;             // overlay after AV
  float tv = fabsf(temp[0])+1e-4f;
  float inv = 1.f/(sqrtf(512.f)*tv);
  float ck0[8],cq0[8],ck1[8],cq1[8],aM0[8],aM1[8];
  #pragma unroll
  for(int m=0;m<8;m++){
    ck0[m]=cc[(b*16+m)*16+j0];  cq0[m]=cc[(b*16+m+8)*16+j0];
    ck1[m]=cc[(b*16+m)*16+j1];  cq1[m]=cc[(b*16+m+8)*16+j1];
    aM0[m]=ck0[m]*cq0[m];       aM1[m]=ck1[m]*cq1[m];
  }
  {
    int t = tid;
    float sk0=0,ssk0=0,sq0=0,ssq0=0,sk1=0,ssk1=0,sq1=0,ssq1=0;
    #pragma unroll
    for(int m=0;m<8;m++){
      float svk = Sv [(b*16+m)*256+t];
      float ssvk= SSv[(b*16+m)*256+t];
      float svq = Sv [(b*16+m+8)*256+t];
      float ssvq= SSv[(b*16+m+8)*256+t];
      sk0 += ck0[m]*svk;  ssk0 += ck0[m]*ck0[m]*ssvk;
      sq0 += cq0[m]*svq;  ssq0 += cq0[m]*cq0[m]*ssvq;
      sk1 += ck1[m]*svk;  ssk1 += ck1[m]*ck1[m]*ssvk;
      sq1 += cq1[m]*svq;  ssq1 += cq1[m]*cq1[m]*ssvq;
    }
    float mq0 = sq0*(1.f/512.f), mq1 = sq1*(1.f/512.f);
    mQL0[t]=mq0; rQL0[t]=rsqrtf(ssq0*(1.f/512.f)-mq0*mq0+EPSLN);
    mQL1[t]=mq1; rQL1[t]=rsqrtf(ssq1*(1.f/512.f)-mq1*mq1+EPSLN);
    if((t>>4)==st){
      int si = t&15;
      float mk0 = sk0*(1.f/512.f), mk1 = sk1*(1.f/512.f);
      mK2[si]   =mk0; rK2[si]   =rsqrtf(ssk0*(1.f/512.f)-mk0*mk0+EPSLN);
      mK2[16+si]=mk1; rK2[16+si]=rsqrtf(ssk1*(1.f/512.f)-mk1*mk1+EPSLN);
    }
  }
  __syncthreads();
  int bj0 = b*16+j0, bj1 = b*16+j1;
  const float* Gb = G + (size_t)(b*8)*65536;
  float4 mQ40 = *(const float4*)&mQL0[lane*4];
  float4 rQ40 = *(const float4*)&rQL0[lane*4];
  float4 mQ41 = *(const float4*)&mQL1[lane*4];
  float4 rQ41 = *(const float4*)&rQL1[lane*4];
  #pragma unroll
  for(int q=0;q<4;q++){
    int si = w*4+q;
    int s = st*16 + si;
    f32x4 dot0 = {0.f,0.f,0.f,0.f}, dot1 = {0.f,0.f,0.f,0.f};
    #pragma unroll
    for(int m=0;m<8;m++){
      f32x4 g4 = *(const f32x4*)(Gb + (size_t)m*65536 + s*256 + lane*4);
      dot0 += aM0[m]*g4;
      dot1 += aM1[m]*g4;
    }
    // defer-max: LN'd rows => |raw| <= sqrt(512)/tv ~ 22.6, exp safe without max-sub
    {
      float mKs = 512.f*mK2[si], rKs = rK2[si];
      float e0 = expf((dot0[0] - mKs*mQ40.x)*rKs*rQ40.x*inv);
      float e1 = expf((dot0[1] - mKs*mQ40.y)*rKs*rQ40.y*inv);
      float e2 = expf((dot0[2] - mKs*mQ40.z)*rKs*rQ40.z*inv);
      float e3 = expf((dot0[3] - mKs*mQ40.w)*rKs*rQ40.w*inv);
      float isf = 1.f/wsum(e0+e1+e2+e3);
      u16 pk[4] = {f2bf(e0*isf), f2bf(e1*isf), f2bf(e2*isf), f2bf(e3*isf)};
      *(ushort4*)(prB0 + ((si*512 + lane*8) ^ ((si&7)<<4))) = *(ushort4*)pk;
    }
    {
      float mKs = 512.f*mK2[16+si], rKs = rK2[16+si];
      float e0 = expf((dot1[0] - mKs*mQ41.x)*rKs*rQ41.x*inv);
      float e1 = expf((dot1[1] - mKs*mQ41.y)*rKs*rQ41.y*inv);
      float e2 = expf((dot1[2] - mKs*mQ41.z)*rKs*rQ41.z*inv);
      float e3 = expf((dot1[3] - mKs*mQ41.w)*rKs*rQ41.w*inv);
      float isf = 1.f/wsum(e0+e1+e2+e3);
      u16 pk[4] = {f2bf(e0*isf), f2bf(e1*isf), f2bf(e2*isf), f2bf(e3*isf)};
      *(ushort4*)(prB1 + ((si*512 + lane*8) ^ ((si&7)<<4))) = *(ushort4*)pk;
    }
  }
  __syncthreads();
  int m_ = lane&15, kb = lane>>4;
  f32x4 acc0 = {0.f,0.f,0.f,0.f}, acc1 = {0.f,0.f,0.f,0.f};
  const u16* xpB0 = xpB + (size_t)bj0*16384;
  const u16* xpB1 = xpB + (size_t)bj1*16384;
  #pragma unroll
  for(int ks=0;ks<8;ks++){
    int aoff = (m_*512 + ks*64 + kb*16) ^ ((m_&7)<<4);
    int boff = ((ks*4 + w)*64 + lane)*8;
    bf16x8 a0 = *(const bf16x8*)(prB0 + aoff);
    bf16x8 a1 = *(const bf16x8*)(prB1 + aoff);
    acc0 = __builtin_amdgcn_mfma_f32_16x16x32_bf16(a0, *(const bf16x8*)(xpB0 + boff), acc0, 0,0,0);
    acc1 = __builtin_amdgcn_mfma_f32_16x16x32_bf16(a1, *(const bf16x8*)(xpB1 + boff), acc1, 0,0,0);
  }
  __syncthreads();   // prob reads done; stats dead; overlay xpT
  for(int idx4 = tid; idx4 < 1536; idx4 += 256){
    int jj = idx4 / 768;
    int rem = idx4 - jj*768;
    int rr_i = rem >> 8;
    int pos = rem & 255;
    int ci = pos>>4, f4 = pos&15;
    int grow = st - 1 + rr_i;
    float4 v = {0.f,0.f,0.f,0.f};
    if(grow>=0 && grow<16){
      v = *(const float4*)(xp + ((size_t)(b*16+j0+jj)*256 + grow*16 + ci)*64 + f4*4);
    }
    *(float4*)(xpT + ((jj*3+rr_i)*16+ci)*68 + f4*4) = v;
  }
  __syncthreads();
  int f = w*16 + m_;
  #pragma unroll
  for(int jj=0;jj<2;jj++){
    int j = j0+jj;
    int bj = b*16+j;
    f32x4 acc = jj ? acc1 : acc0;
    float al = fabsf(alpha[j]), be=fabsf(beta[j]), th=fabsf(theta[j]), ga=gamma_[j];
    const float* wq = cw + (j*64+f)*9;
    float w0=wq[0],w1=wq[1],w2=wq[2],w3v=wq[3],w4=wq[4],w5=wq[5],w6=wq[6],w7=wq[7],w8=wq[8];
    #pragma unroll
    for(int r=0;r<4;r++){
      int si = kb*4 + r;
      int s = st*16 + si;
      float gl = acc[r];
      float cv=0.f;
      #pragma unroll
      for(int dr=0;dr<3;dr++){
        float kw0 = dr==0?w0:(dr==1?w3v:w6);
        float kw1 = dr==0?w1:(dr==1?w4:w7);
        float kw2 = dr==0?w2:(dr==1?w5:w8);
        const float* rowp = xpT + ((jj*3+dr)*16)*68;
        if(si>0)  cv += rowp[(si-1)*68+f]*kw0;
                  cv += rowp[(si  )*68+f]*kw1;
        if(si<15) cv += rowp[(si+1)*68+f]*kw2;
      }
      float diag = xpT[((jj*3+1)*16+si)*68+f];
      size_t gi = ((size_t)bj*256+s)*64+f;
      out[gi] = be*gl + al*diag + th*cv + ga*bf2f(xarrb[gi]);
    }
  }
}

extern "C" void kernel_launch(void* const* d_in, const int* in_sizes, int n_in,
                              void* d_out, int out_size, void* d_ws, size_t ws_size,
                              hipStream_t stream) {
  const float* xin = (const float*)d_in[0];
  const float* pxp = (const float*)d_in[1];
  const float* sw  = (const float*)d_in[2];
  const float* bs  = (const float*)d_in[3];
  const float* tau = (const float*)d_in[4];
  const float* temp= (const float*)d_in[5];
  const float* om  = (const float*)d_in[6];
  const float* W2  = (const float*)d_in[7];
  const float* bp  = (const float*)d_in[8];
  const float* lnw = (const float*)d_in[9];
  const float* lnb = (const float*)d_in[10];
  const float* alpha=(const float*)d_in[11];
  const float* beta= (const float*)d_in[12];
  const float* gam = (const float*)d_in[13];
  const float* theta=(const float*)d_in[14];
  const float* cw  = (const float*)d_in[15];
  float* outp = (float*)d_out;
  float* xpo  = outp + 2097152;   // x_prime = second output

  float* ws  = (float*)d_ws;
  float* Sv  = ws;                // 32768
  float* SSv = Sv + 32768;        // 32768
  float* er2 = SSv + 32768;       // 524288
  float* mask= er2 + 524288;      // 2048
  float* ccv = mask + 2048;       // 2048
  float* Gv  = ccv + 2048;        // 4194304
  u16* xvb = (u16*)(Gv + 4194304);    // 2097152 u16 (bf16 x)
  u16* xpB = xvb + 2097152;           // 2097152 u16
  u16* w2B = xpB + 2097152;           // 65536 u16
  u16* xinb= w2B + 65536;             // 2097152 u16
  u16* phi = xinb + 2097152;          // 2097152 u16
  u16* plo = phi + 2097152;           // 2097152 u16

  k1<<<1152,256,0,stream>>>(xin,pxp,W2,sw,bs,om,tau,temp,
                            Sv,SSv,xinb,phi,plo,w2B,er2,mask,ccv);
  k2<<<3072,256,0,stream>>>(phi,plo,Gv,xinb,er2,mask,w2B,lnw,lnb,bp,xvb,xpo,xpB);
  kF<<<dim3(8,8,16),256,0,stream>>>(Gv,ccv,Sv,SSv,xpo,xpB,cw,xvb,temp,
                                    alpha,beta,gam,theta,outp);
}

// Round 14
// 58.005 us; speedup vs baseline: 1.2540x; 1.2540x over previous
//
#include <hip/hip_runtime.h>

#define EPSLN 1e-5f

typedef short bf16x8 __attribute__((ext_vector_type(8)));
typedef float f32x4 __attribute__((ext_vector_type(4)));
typedef unsigned short u16;
typedef unsigned short u16x8 __attribute__((ext_vector_type(8)));

__device__ __forceinline__ float wsum(float v){
  #pragma unroll
  for(int o=32;o;o>>=1) v += __shfl_xor(v,o);
  return v;
}
__device__ __forceinline__ float wmax(float v){
  #pragma unroll
  for(int o=32;o;o>>=1) v = fmaxf(v,__shfl_xor(v,o));
  return v;
}
__device__ __forceinline__ u16 f2bf(float f){
  unsigned int u = __float_as_uint(f);
  u = (u + 0x7FFFu + ((u>>16)&1u)) >> 16;
  return (u16)u;
}
__device__ __forceinline__ float bf2f(u16 h){
  return __uint_as_float(((unsigned int)h)<<16);
}

// A: eighth-row per thread. Blocks 0..15 also pack W2 into bf16 B-frag order.
__global__ void __launch_bounds__(256) kA(
                   const float* __restrict__ xin, const float* __restrict__ p,
                   const float* __restrict__ W2,
                   float* __restrict__ xe, float* __restrict__ xa,
                   float* __restrict__ Sv, float* __restrict__ SSv,
                   u16* __restrict__ xinb, u16* __restrict__ phi, u16* __restrict__ plo,
                   u16* __restrict__ w2B){
  int t = threadIdx.x;
  int rl = t>>3, q = t&7;
  int row = blockIdx.x*32 + rl;
  const float4* xr = (const float4*)(xin + row*64 + q*8);
  const float4* pr = (const float4*)(p   + row*64 + q*8);
  float s1=0.f,s2=0.f,s3=0.f,s4=0.f;
  u16x8 xb, ph, pl;
  #pragma unroll
  for(int k=0;k<2;k++){
    float4 xv = xr[k];
    float4 pv = pr[k];
    s1 += xv.x+xv.y+xv.z+xv.w;
    s2 += fabsf(xv.x)+fabsf(xv.y)+fabsf(xv.z)+fabsf(xv.w);
    s3 += pv.x+pv.y+pv.z+pv.w;
    s4 += pv.x*pv.x+pv.y*pv.y+pv.z*pv.z+pv.w*pv.w;
    int o = k*4;
    xb[o+0]=f2bf(xv.x); xb[o+1]=f2bf(xv.y); xb[o+2]=f2bf(xv.z); xb[o+3]=f2bf(xv.w);
    u16 h0=f2bf(pv.x), h1=f2bf(pv.y), h2=f2bf(pv.z), h3=f2bf(pv.w);
    ph[o+0]=h0; ph[o+1]=h1; ph[o+2]=h2; ph[o+3]=h3;
    pl[o+0]=f2bf(pv.x-bf2f(h0)); pl[o+1]=f2bf(pv.y-bf2f(h1));
    pl[o+2]=f2bf(pv.z-bf2f(h2)); pl[o+3]=f2bf(pv.w-bf2f(h3));
  }
  *(u16x8*)(xinb + row*64 + q*8) = xb;
  *(u16x8*)(phi  + row*64 + q*8) = ph;
  *(u16x8*)(plo  + row*64 + q*8) = pl;
  s1 += __shfl_xor(s1,1); s1 += __shfl_xor(s1,2); s1 += __shfl_xor(s1,4);
  s2 += __shfl_xor(s2,1); s2 += __shfl_xor(s2,2); s2 += __shfl_xor(s2,4);
  s3 += __shfl_xor(s3,1); s3 += __shfl_xor(s3,2); s3 += __shfl_xor(s3,4);
  s4 += __shfl_xor(s4,1); s4 += __shfl_xor(s4,2); s4 += __shfl_xor(s4,4);
  if(q==0){ xe[row]=s1*(1.f/64.f); xa[row]=s2*(1.f/64.f); Sv[row]=s3; SSv[row]=s4; }
  if(blockIdx.x<16){
    int j = blockIdx.x;
    for(int idx=threadIdx.x; idx<4096; idx+=256){
      int f = idx>>6, o = idx&63;
      float v = W2[j*4096 + idx];
      int ks = f>>5, kb = (f>>3)&3, i = f&7;
      int nt = o>>4, col = o&15;
      int ln = kb*16 + col;
      w2B[((j*2+ks)*4 + nt)*512 + ln*8 + i] = f2bf(v);
    }
  }
}

// BE: fused kB (blocks 0..127) + kE2 gram MFMA (blocks 128..1151). 32KB LDS union.
__global__ void __launch_bounds__(256) kBE(
                   const float* __restrict__ xe, const float* __restrict__ sw,
                   const float* __restrict__ bs, const float* __restrict__ om,
                   const float* __restrict__ xa, const float* __restrict__ tau,
                   const float* __restrict__ temp,
                   float* __restrict__ er2, float* __restrict__ mask,
                   float* __restrict__ cc,
                   const u16* __restrict__ phi, const u16* __restrict__ plo,
                   float* __restrict__ G){
  __shared__ __align__(16) unsigned char shm[32768];
  int tid = threadIdx.x;
  if(blockIdx.x < 128){
    // ---- kB body ----
    float* swL = (float*)shm;
    float* bsL = swL + 1072;
    float* omL = bsL + 16;
    float* red = omL + 16;
    float* redE= red + 4;              // [16][4]
    int bi = blockIdx.x;
    int i = bi & 15;
    int w = tid>>6, lane = tid&63;
    for(int k=tid;k<16*67;k+=256) swL[k] = sw[i*16*67 + k];
    if(tid<16){ bsL[tid]=bs[i*16+tid]; omL[tid]=fabsf(om[i*16+tid]); }
    float v = xe[bi*256+tid];
    float m = wmax(fabsf(v));
    if(lane==0) red[w]=m;
    __syncthreads();
    m = fmaxf(fmaxf(red[0],red[1]),fmaxf(red[2],red[3]));
    float xn = v/(m+1e-8f);
    xn = fminf(fmaxf(xn,-0.99f),0.99f);
    float sil = xn/(1.f+expf(-xn));
    float vv = (xn+1.f)*33.f;
    int c0 = (int)floorf(vv)-1;
    float acc[16];
    #pragma unroll
    for(int j=0;j<16;j++) acc[j]=0.f;
    #pragma unroll
    for(int k=0;k<4;k++){
      int c = c0+k;
      if(c<0||c>66) continue;
      float d = fabsf(vv-(float)c);
      float bas = d<1.f ? (2.f/3.f - d*d + d*d*d*0.5f)
                : (d<2.f ? (2.f-d)*(2.f-d)*(2.f-d)*(1.f/6.f) : 0.f);
      #pragma unroll
      for(int j=0;j<16;j++) acc[j] += bas*swL[j*67+c];
    }
    float xav = xa[bi*256+tid];
    #pragma unroll
    for(int j=0;j<16;j++){
      float ev = sil*bsL[j] + acc[j] + omL[j];
      er2[(bi*16+j)*256+tid] = ev;
      float pe = wsum(fabsf(ev)*xav);
      if(lane==0) redE[j*4+w]=pe;
    }
    __syncthreads();
    if(tid<16){
      float e = (redE[tid*4+0]+redE[tid*4+1]+redE[tid*4+2]+redE[tid*4+3])*(1.f/256.f);
      float tv = fabsf(temp[0])+1e-4f;
      float ta = fabsf(tau[i*16+tid]);
      float mk = 1.f/(1.f+expf(-(e-ta)/tv));
      mask[bi*16+tid]=mk;
      cc[bi*16+tid]= e/(ta+1e-8f)*mk;
    }
  } else {
    // ---- kE2 body ----
    u16* AfB = (u16*)shm;
    u16* BfB = AfB + 8192;
    int e = blockIdx.x - 128;
    int b = e&7, m = (e>>3)&7, sx = (e>>6)&3, ty = e>>8;  // b lowest -> XCD=b
    int bm = b*8+m;
    int s0 = sx*64, t0 = ty*64;
    int row = tid>>2, dseg = tid&3;
    size_t offA = ((size_t)(b*16+m  )*256 + s0 + row)*64 + dseg*16;
    size_t offB = ((size_t)(b*16+m+8)*256 + t0 + row)*64 + dseg*16;
    int d0 = dseg*16;
    int ks0 = d0>>5, kb0 = (d0>>3)&3;
    int ks1 = (d0+8)>>5, kb1 = ((d0+8)>>3)&3;
    int lr = row&15, stile = row>>4;
    #define AOFF(h,stl,ks,ln) (((((h)*4+(stl))*2+(ks))*64 + (ln))*8)
    {
      uint4 v0 = *(const uint4*)(phi + offA);
      uint4 v1 = *(const uint4*)(phi + offA + 8);
      *(uint4*)(AfB + AOFF(0,stile,ks0,kb0*16+lr)) = v0;
      *(uint4*)(AfB + AOFF(0,stile,ks1,kb1*16+lr)) = v1;
      uint4 w0 = *(const uint4*)(plo + offA);
      uint4 w1 = *(const uint4*)(plo + offA + 8);
      *(uint4*)(AfB + AOFF(1,stile,ks0,kb0*16+lr)) = w0;
      *(uint4*)(AfB + AOFF(1,stile,ks1,kb1*16+lr)) = w1;
      uint4 x0 = *(const uint4*)(phi + offB);
      uint4 x1 = *(const uint4*)(phi + offB + 8);
      *(uint4*)(BfB + AOFF(0,stile,ks0,kb0*16+lr)) = x0;
      *(uint4*)(BfB + AOFF(0,stile,ks1,kb1*16+lr)) = x1;
      uint4 y0 = *(const uint4*)(plo + offB);
      uint4 y1 = *(const uint4*)(plo + offB + 8);
      *(uint4*)(BfB + AOFF(1,stile,ks0,kb0*16+lr)) = y0;
      *(uint4*)(BfB + AOFF(1,stile,ks1,kb1*16+lr)) = y1;
    }
    __syncthreads();
    int w = tid>>6, lane = tid&63;
    bf16x8 ah0 = *(const bf16x8*)(AfB + AOFF(0,w,0,lane));
    bf16x8 ah1 = *(const bf16x8*)(AfB + AOFF(0,w,1,lane));
    bf16x8 al0 = *(const bf16x8*)(AfB + AOFF(1,w,0,lane));
    bf16x8 al1 = *(const bf16x8*)(AfB + AOFF(1,w,1,lane));
    f32x4 acc[4];
    #pragma unroll
    for(int tt=0;tt<4;tt++) acc[tt] = (f32x4){0.f,0.f,0.f,0.f};
    #pragma unroll
    for(int tt=0;tt<4;tt++){
      bf16x8 bh0 = *(const bf16x8*)(BfB + AOFF(0,tt,0,lane));
      bf16x8 bh1 = *(const bf16x8*)(BfB + AOFF(0,tt,1,lane));
      bf16x8 bl0 = *(const bf16x8*)(BfB + AOFF(1,tt,0,lane));
      bf16x8 bl1 = *(const bf16x8*)(BfB + AOFF(1,tt,1,lane));
      acc[tt] = __builtin_amdgcn_mfma_f32_16x16x32_bf16(ah0, bh0, acc[tt], 0,0,0);
      acc[tt] = __builtin_amdgcn_mfma_f32_16x16x32_bf16(ah1, bh1, acc[tt], 0,0,0);
      acc[tt] = __builtin_amdgcn_mfma_f32_16x16x32_bf16(ah0, bl0, acc[tt], 0,0,0);
      acc[tt] = __builtin_amdgcn_mfma_f32_16x16x32_bf16(ah1, bl1, acc[tt], 0,0,0);
      acc[tt] = __builtin_amdgcn_mfma_f32_16x16x32_bf16(al0, bh0, acc[tt], 0,0,0);
      acc[tt] = __builtin_amdgcn_mfma_f32_16x16x32_bf16(al1, bh1, acc[tt], 0,0,0);
    }
    int col = lane&15, r4 = lane>>4;
    #pragma unroll
    for(int tt=0;tt<4;tt++){
      #pragma unroll
      for(int r=0;r<4;r++){
        G[((size_t)bm*256 + s0 + w*16 + r4*4 + r)*256 + t0 + tt*16 + col] = acc[tt][r];
      }
    }
    #undef AOFF
  }
}

// D v2: vectorized gather — wave covers 4 s-rows x 64 f per load (512B);
// thread owns 4 f (ushort4). LN via 16-lane butterfly. MFMA part unchanged.
__global__ void __launch_bounds__(256) kD(
                   const u16* __restrict__ xinb, const float* __restrict__ er2,
                   const float* __restrict__ mask, const u16* __restrict__ w2B,
                   const float* __restrict__ lnw, const float* __restrict__ lnb,
                   const float* __restrict__ bp,
                   u16* __restrict__ xoutb, float* __restrict__ xp,
                   u16* __restrict__ xpB){
  int b = blockIdx.x, j = blockIdx.y, st = blockIdx.z;
  int tid = threadIdx.x, w = tid>>6, lane = tid&63;
  __shared__ __align__(16) u16 xnS[16*64];  // bf16, XOR-swizzled
  __shared__ float mcL[16];
  if(tid<16) mcL[tid]=mask[(b*16+tid)*16+j];
  __syncthreads();
  int bj = b*16+j;
  unsigned char* xnB = (unsigned char*)xnS;
  int ss = lane>>4, fq = lane&15;
  int sl = w*4 + ss;
  int s  = st*16 + sl;
  float4 lw4 = *(const float4*)(lnw + j*64 + fq*4);
  float4 lb4 = *(const float4*)(lnb + j*64 + fq*4);
  float acc0=0.f,acc1=0.f,acc2=0.f,acc3=0.f;
  #pragma unroll
  for(int i=0;i<16;i++){
    float er = er2[((b*16+i)*16+j)*256+s]*mcL[i];
    ushort4 xv = *(const ushort4*)(xinb + ((size_t)(b*16+i)*256+s)*64 + fq*4);
    acc0 += er*bf2f(xv.x);
    acc1 += er*bf2f(xv.y);
    acc2 += er*bf2f(xv.z);
    acc3 += er*bf2f(xv.w);
  }
  acc0*=(1.f/16.f); acc1*=(1.f/16.f); acc2*=(1.f/16.f); acc3*=(1.f/16.f);
  {
    u16 pk[4]={f2bf(acc0),f2bf(acc1),f2bf(acc2),f2bf(acc3)};
    *(ushort4*)(xoutb + ((size_t)bj*256+s)*64 + fq*4) = *(ushort4*)pk;
  }
  float part = acc0+acc1+acc2+acc3;
  part += __shfl_xor(part,1); part += __shfl_xor(part,2);
  part += __shfl_xor(part,4); part += __shfl_xor(part,8);
  float mu = part*(1.f/64.f);
  float d0=acc0-mu, d1=acc1-mu, d2=acc2-mu, d3=acc3-mu;
  float p2 = d0*d0+d1*d1+d2*d2+d3*d3;
  p2 += __shfl_xor(p2,1); p2 += __shfl_xor(p2,2);
  p2 += __shfl_xor(p2,4); p2 += __shfl_xor(p2,8);
  float rstd = rsqrtf(p2*(1.f/64.f)+EPSLN);
  {
    u16 xn[4] = { f2bf(d0*rstd*lw4.x + lb4.x), f2bf(d1*rstd*lw4.y + lb4.y),
                  f2bf(d2*rstd*lw4.z + lb4.z), f2bf(d3*rstd*lw4.w + lb4.w) };
    *(ushort4*)(xnB + ((sl*128 + fq*8) ^ ((sl&7)<<4))) = *(ushort4*)xn;
  }
  __syncthreads();
  f32x4 acc = {0.f,0.f,0.f,0.f};
  int m = lane&15, kb = lane>>4;
  #pragma unroll
  for(int ks=0;ks<2;ks++){
    bf16x8 a = *(const bf16x8*)(xnB + ((m*128 + ks*64 + kb*16) ^ ((m&7)<<4)));
    bf16x8 bfr = *(const bf16x8*)(w2B + ((j*2+ks)*4 + w)*512 + lane*8);
    acc = __builtin_amdgcn_mfma_f32_16x16x32_bf16(a, bfr, acc, 0, 0, 0);
  }
  int f = w*16 + m;
  u16 pk[4];
  #pragma unroll
  for(int r=0;r<4;r++){
    int si = kb*4 + r;
    int s2 = st*16 + si;
    float xpr = acc[r] + bp[((size_t)j*256+s2)*64+f];
    xp[((size_t)bj*256+s2)*64+f] = xpr;
    pk[r] = f2bf(xpr);
  }
  int s0 = st*16 + kb*4;
  int flat = ((s0>>5)*4 + w)*512 + ((s0>>3)&3)*128 + m*8 + (s0&7);
  *(ushort4*)(xpB + (size_t)bj*16384 + flat) = *(ushort4*)pk;
}

// F: 2 j per block; LDS 25.5KB; defer-max softmax; MFMA AV; LDS conv;
//     residuals. b in blockIdx.x -> XCD=b.
__global__ void __launch_bounds__(256) kF(
    const float* __restrict__ G, const float* __restrict__ cc,
    const float* __restrict__ Sv, const float* __restrict__ SSv,
    const float* __restrict__ xp, const u16* __restrict__ xpB,
    const float* __restrict__ cw,
    const u16* __restrict__ xarrb, const float* __restrict__ temp,
    const float* __restrict__ alpha, const float* __restrict__ beta,
    const float* __restrict__ gamma_, const float* __restrict__ theta,
    float* __restrict__ out){
  int b = blockIdx.x, jp = blockIdx.y, st = blockIdx.z;
  int j0 = jp*2, j1 = j0+1;
  int tid = threadIdx.x, w = tid>>6, lane = tid&63;
  __shared__ __align__(16) unsigned char ovl[26112];
  unsigned char* prB0 = ovl;
  unsigned char* prB1 = ovl + 8192;
  float* mQL0 = (float*)(ovl + 16384);
  float* rQL0 = (float*)(ovl + 17408);
  float* mQL1 = (float*)(ovl + 18432);
  float* rQL1 = (float*)(ovl + 19456);
  float* mK2  = (float*)(ovl + 20480);   // [2][16]
  float* rK2  = (float*)(ovl + 20608);   // [2][16]
  float* xpT  = (float*)ovl;             // overlay after AV
  float tv = fabsf(temp[0])+1e-4f;
  float inv = 1.f/(sqrtf(512.f)*tv);
  float ck0[8],cq0[8],ck1[8],cq1[8],aM0[8],aM1[8];
  #pragma unroll
  for(int m=0;m<8;m++){
    ck0[m]=cc[(b*16+m)*16+j0];  cq0[m]=cc[(b*16+m+8)*16+j0];
    ck1[m]=cc[(b*16+m)*16+j1];  cq1[m]=cc[(b*16+m+8)*16+j1];
    aM0[m]=ck0[m]*cq0[m];       aM1[m]=ck1[m]*cq1[m];
  }
  {
    int t = tid;
    float sk0=0,ssk0=0,sq0=0,ssq0=0,sk1=0,ssk1=0,sq1=0,ssq1=0;
    #pragma unroll
    for(int m=0;m<8;m++){
      float svk = Sv [(b*16+m)*256+t];
      float ssvk= SSv[(b*16+m)*256+t];
      float svq = Sv [(b*16+m+8)*256+t];
      float ssvq= SSv[(b*16+m+8)*256+t];
      sk0 += ck0[m]*svk;  ssk0 += ck0[m]*ck0[m]*ssvk;
      sq0 += cq0[m]*svq;  ssq0 += cq0[m]*cq0[m]*ssvq;
      sk1 += ck1[m]*svk;  ssk1 += ck1[m]*ck1[m]*ssvk;
      sq1 += cq1[m]*svq;  ssq1 += cq1[m]*cq1[m]*ssvq;
    }
    float mq0 = sq0*(1.f/512.f), mq1 = sq1*(1.f/512.f);
    mQL0[t]=mq0; rQL0[t]=rsqrtf(ssq0*(1.f/512.f)-mq0*mq0+EPSLN);
    mQL1[t]=mq1; rQL1[t]=rsqrtf(ssq1*(1.f/512.f)-mq1*mq1+EPSLN);
    if((t>>4)==st){
      int si = t&15;
      float mk0 = sk0*(1.f/512.f), mk1 = sk1*(1.f/512.f);
      mK2[si]   =mk0; rK2[si]   =rsqrtf(ssk0*(1.f/512.f)-mk0*mk0+EPSLN);
      mK2[16+si]=mk1; rK2[16+si]=rsqrtf(ssk1*(1.f/512.f)-mk1*mk1+EPSLN);
    }
  }
  __syncthreads();
  int bj0 = b*16+j0, bj1 = b*16+j1;
  const float* Gb = G + (size_t)(b*8)*65536;
  float4 mQ40 = *(const float4*)&mQL0[lane*4];
  float4 rQ40 = *(const float4*)&rQL0[lane*4];
  float4 mQ41 = *(const float4*)&mQL1[lane*4];
  float4 rQ41 = *(const float4*)&rQL1[lane*4];
  #pragma unroll
  for(int q=0;q<4;q++){
    int si = w*4+q;
    int s = st*16 + si;
    f32x4 dot0 = {0.f,0.f,0.f,0.f}, dot1 = {0.f,0.f,0.f,0.f};
    #pragma unroll
    for(int m=0;m<8;m++){
      f32x4 g4 = *(const f32x4*)(Gb + (size_t)m*65536 + s*256 + lane*4);
      dot0 += aM0[m]*g4;
      dot1 += aM1[m]*g4;
    }
    // defer-max: LN'd rows => |raw| <= sqrt(512)/tv ~ 22.6, exp safe without max-sub
    {
      float mKs = 512.f*mK2[si], rKs = rK2[si];
      float e0 = expf((dot0[0] - mKs*mQ40.x)*rKs*rQ40.x*inv);
      float e1 = expf((dot0[1] - mKs*mQ40.y)*rKs*rQ40.y*inv);
      float e2 = expf((dot0[2] - mKs*mQ40.z)*rKs*rQ40.z*inv);
      float e3 = expf((dot0[3] - mKs*mQ40.w)*rKs*rQ40.w*inv);
      float isf = 1.f/wsum(e0+e1+e2+e3);
      u16 pk[4] = {f2bf(e0*isf), f2bf(e1*isf), f2bf(e2*isf), f2bf(e3*isf)};
      *(ushort4*)(prB0 + ((si*512 + lane*8) ^ ((si&7)<<4))) = *(ushort4*)pk;
    }
    {
      float mKs = 512.f*mK2[16+si], rKs = rK2[16+si];
      float e0 = expf((dot1[0] - mKs*mQ41.x)*rKs*rQ41.x*inv);
      float e1 = expf((dot1[1] - mKs*mQ41.y)*rKs*rQ41.y*inv);
      float e2 = expf((dot1[2] - mKs*mQ41.z)*rKs*rQ41.z*inv);
      float e3 = expf((dot1[3] - mKs*mQ41.w)*rKs*rQ41.w*inv);
      float isf = 1.f/wsum(e0+e1+e2+e3);
      u16 pk[4] = {f2bf(e0*isf), f2bf(e1*isf), f2bf(e2*isf), f2bf(e3*isf)};
      *(ushort4*)(prB1 + ((si*512 + lane*8) ^ ((si&7)<<4))) = *(ushort4*)pk;
    }
  }
  __syncthreads();
  int m_ = lane&15, kb = lane>>4;
  f32x4 acc0 = {0.f,0.f,0.f,0.f}, acc1 = {0.f,0.f,0.f,0.f};
  const u16* xpB0 = xpB + (size_t)bj0*16384;
  const u16* xpB1 = xpB + (size_t)bj1*16384;
  #pragma unroll
  for(int ks=0;ks<8;ks++){
    int aoff = (m_*512 + ks*64 + kb*16) ^ ((m_&7)<<4);
    int boff = ((ks*4 + w)*64 + lane)*8;
    bf16x8 a0 = *(const bf16x8*)(prB0 + aoff);
    bf16x8 a1 = *(const bf16x8*)(prB1 + aoff);
    acc0 = __builtin_amdgcn_mfma_f32_16x16x32_bf16(a0, *(const bf16x8*)(xpB0 + boff), acc0, 0,0,0);
    acc1 = __builtin_amdgcn_mfma_f32_16x16x32_bf16(a1, *(const bf16x8*)(xpB1 + boff), acc1, 0,0,0);
  }
  __syncthreads();   // prob reads done; stats dead; overlay xpT
  for(int idx4 = tid; idx4 < 1536; idx4 += 256){
    int jj = idx4 / 768;
    int rem = idx4 - jj*768;
    int rr_i = rem >> 8;
    int pos = rem & 255;
    int ci = pos>>4, f4 = pos&15;
    int grow = st - 1 + rr_i;
    float4 v = {0.f,0.f,0.f,0.f};
    if(grow>=0 && grow<16){
      v = *(const float4*)(xp + ((size_t)(b*16+j0+jj)*256 + grow*16 + ci)*64 + f4*4);
    }
    *(float4*)(xpT + ((jj*3+rr_i)*16+ci)*68 + f4*4) = v;
  }
  __syncthreads();
  int f = w*16 + m_;
  #pragma unroll
  for(int jj=0;jj<2;jj++){
    int j = j0+jj;
    int bj = b*16+j;
    f32x4 acc = jj ? acc1 : acc0;
    float al = fabsf(alpha[j]), be=fabsf(beta[j]), th=fabsf(theta[j]), ga=gamma_[j];
    const float* wq = cw + (j*64+f)*9;
    float w0=wq[0],w1=wq[1],w2=wq[2],w3v=wq[3],w4=wq[4],w5=wq[5],w6=wq[6],w7=wq[7],w8=wq[8];
    #pragma unroll
    for(int r=0;r<4;r++){
      int si = kb*4 + r;
      int s = st*16 + si;
      float gl = acc[r];
      float cv=0.f;
      #pragma unroll
      for(int dr=0;dr<3;dr++){
        float kw0 = dr==0?w0:(dr==1?w3v:w6);
        float kw1 = dr==0?w1:(dr==1?w4:w7);
        float kw2 = dr==0?w2:(dr==1?w5:w8);
        const float* rowp = xpT + ((jj*3+dr)*16)*68;
        if(si>0)  cv += rowp[(si-1)*68+f]*kw0;
                  cv += rowp[(si  )*68+f]*kw1;
        if(si<15) cv += rowp[(si+1)*68+f]*kw2;
      }
      float diag = xpT[((jj*3+1)*16+si)*68+f];
      size_t gi = ((size_t)bj*256+s)*64+f;
      out[gi] = be*gl + al*diag + th*cv + ga*bf2f(xarrb[gi]);
    }
  }
}

extern "C" void kernel_launch(void* const* d_in, const int* in_sizes, int n_in,
                              void* d_out, int out_size, void* d_ws, size_t ws_size,
                              hipStream_t stream) {
  const float* xin = (const float*)d_in[0];
  const float* pxp = (const float*)d_in[1];
  const float* sw  = (const float*)d_in[2];
  const float* bs  = (const float*)d_in[3];
  const float* tau = (const float*)d_in[4];
  const float* temp= (const float*)d_in[5];
  const float* om  = (const float*)d_in[6];
  const float* W2  = (const float*)d_in[7];
  const float* bp  = (const float*)d_in[8];
  const float* lnw = (const float*)d_in[9];
  const float* lnb = (const float*)d_in[10];
  const float* alpha=(const float*)d_in[11];
  const float* beta= (const float*)d_in[12];
  const float* gam = (const float*)d_in[13];
  const float* theta=(const float*)d_in[14];
  const float* cw  = (const float*)d_in[15];
  float* outp = (float*)d_out;
  float* xpo  = outp + 2097152;   // x_prime = second output

  float* ws  = (float*)d_ws;
  float* xe  = ws;                // 32768
  float* xa  = xe + 32768;        // 32768
  float* Sv  = xa + 32768;        // 32768
  float* SSv = Sv + 32768;        // 32768
  float* er2 = SSv + 32768;       // 524288
  float* mask= er2 + 524288;      // 2048
  float* ccv = mask + 2048;       // 2048
  float* Gv  = ccv + 2048;        // 4194304
  u16* xvb = (u16*)(Gv + 4194304);    // 2097152 u16 (bf16 x)
  u16* xpB = xvb + 2097152;           // 2097152 u16
  u16* w2B = xpB + 2097152;           // 65536 u16
  u16* xinb= w2B + 65536;             // 2097152 u16
  u16* phi = xinb + 2097152;          // 2097152 u16
  u16* plo = phi + 2097152;           // 2097152 u16

  kA<<<1024,256,0,stream>>>(xin,pxp,W2,xe,xa,Sv,SSv,xinb,phi,plo,w2B);
  kBE<<<1152,256,0,stream>>>(xe,sw,bs,om,xa,tau,temp,er2,mask,ccv,phi,plo,Gv);
  kD<<<dim3(8,16,16),256,0,stream>>>(xinb,er2,mask,w2B,lnw,lnb,bp,xvb,xpo,xpB);
  kF<<<dim3(8,8,16),256,0,stream>>>(Gv,ccv,Sv,SSv,xpo,xpB,cw,xvb,temp,
                                    alpha,beta,gam,theta,outp);
}

// Round 15
// 56.469 us; speedup vs baseline: 1.2880x; 1.0272x over previous
//
#include <hip/hip_runtime.h>

#define EPSLN 1e-5f

typedef short bf16x8 __attribute__((ext_vector_type(8)));
typedef float f32x4 __attribute__((ext_vector_type(4)));
typedef unsigned short u16;
typedef unsigned short u16x8 __attribute__((ext_vector_type(8)));

__device__ __forceinline__ float wsum(float v){
  #pragma unroll
  for(int o=32;o;o>>=1) v += __shfl_xor(v,o);
  return v;
}
__device__ __forceinline__ float wmax(float v){
  #pragma unroll
  for(int o=32;o;o>>=1) v = fmaxf(v,__shfl_xor(v,o));
  return v;
}
__device__ __forceinline__ u16 f2bf(float f){
  unsigned int u = __float_as_uint(f);
  u = (u + 0x7FFFu + ((u>>16)&1u)) >> 16;
  return (u16)u;
}
__device__ __forceinline__ float bf2f(u16 h){
  return __uint_as_float(((unsigned int)h)<<16);
}

// A: eighth-row per thread. Blocks 0..15 also pack W2 into bf16 B-frag order.
__global__ void __launch_bounds__(256) kA(
                   const float* __restrict__ xin, const float* __restrict__ p,
                   const float* __restrict__ W2,
                   float* __restrict__ xe, float* __restrict__ xa,
                   float* __restrict__ Sv, float* __restrict__ SSv,
                   u16* __restrict__ xinb, u16* __restrict__ phi, u16* __restrict__ plo,
                   u16* __restrict__ w2B){
  int t = threadIdx.x;
  int rl = t>>3, q = t&7;
  int row = blockIdx.x*32 + rl;
  const float4* xr = (const float4*)(xin + row*64 + q*8);
  const float4* pr = (const float4*)(p   + row*64 + q*8);
  float s1=0.f,s2=0.f,s3=0.f,s4=0.f;
  u16x8 xb, ph, pl;
  #pragma unroll
  for(int k=0;k<2;k++){
    float4 xv = xr[k];
    float4 pv = pr[k];
    s1 += xv.x+xv.y+xv.z+xv.w;
    s2 += fabsf(xv.x)+fabsf(xv.y)+fabsf(xv.z)+fabsf(xv.w);
    s3 += pv.x+pv.y+pv.z+pv.w;
    s4 += pv.x*pv.x+pv.y*pv.y+pv.z*pv.z+pv.w*pv.w;
    int o = k*4;
    xb[o+0]=f2bf(xv.x); xb[o+1]=f2bf(xv.y); xb[o+2]=f2bf(xv.z); xb[o+3]=f2bf(xv.w);
    u16 h0=f2bf(pv.x), h1=f2bf(pv.y), h2=f2bf(pv.z), h3=f2bf(pv.w);
    ph[o+0]=h0; ph[o+1]=h1; ph[o+2]=h2; ph[o+3]=h3;
    pl[o+0]=f2bf(pv.x-bf2f(h0)); pl[o+1]=f2bf(pv.y-bf2f(h1));
    pl[o+2]=f2bf(pv.z-bf2f(h2)); pl[o+3]=f2bf(pv.w-bf2f(h3));
  }
  *(u16x8*)(xinb + row*64 + q*8) = xb;
  *(u16x8*)(phi  + row*64 + q*8) = ph;
  *(u16x8*)(plo  + row*64 + q*8) = pl;
  s1 += __shfl_xor(s1,1); s1 += __shfl_xor(s1,2); s1 += __shfl_xor(s1,4);
  s2 += __shfl_xor(s2,1); s2 += __shfl_xor(s2,2); s2 += __shfl_xor(s2,4);
  s3 += __shfl_xor(s3,1); s3 += __shfl_xor(s3,2); s3 += __shfl_xor(s3,4);
  s4 += __shfl_xor(s4,1); s4 += __shfl_xor(s4,2); s4 += __shfl_xor(s4,4);
  if(q==0){ xe[row]=s1*(1.f/64.f); xa[row]=s2*(1.f/64.f); Sv[row]=s3; SSv[row]=s4; }
  if(blockIdx.x<16){
    int j = blockIdx.x;
    for(int idx=threadIdx.x; idx<4096; idx+=256){
      int f = idx>>6, o = idx&63;
      float v = W2[j*4096 + idx];
      int ks = f>>5, kb = (f>>3)&3, i = f&7;
      int nt = o>>4, col = o&15;
      int ln = kb*16 + col;
      w2B[((j*2+ks)*4 + nt)*512 + ln*8 + i] = f2bf(v);
    }
  }
}

// BE: fused kB (blocks 0..127) + kE2 gram MFMA (blocks 128..1151). 32KB LDS union.
__global__ void __launch_bounds__(256) kBE(
                   const float* __restrict__ xe, const float* __restrict__ sw,
                   const float* __restrict__ bs, const float* __restrict__ om,
                   const float* __restrict__ xa, const float* __restrict__ tau,
                   const float* __restrict__ temp,
                   float* __restrict__ er2, float* __restrict__ mask,
                   float* __restrict__ cc,
                   const u16* __restrict__ phi, const u16* __restrict__ plo,
                   float* __restrict__ G){
  __shared__ __align__(16) unsigned char shm[32768];
  int tid = threadIdx.x;
  if(blockIdx.x < 128){
    // ---- kB body ----
    float* swL = (float*)shm;
    float* bsL = swL + 1072;
    float* omL = bsL + 16;
    float* red = omL + 16;
    float* redE= red + 4;              // [16][4]
    int bi = blockIdx.x;
    int i = bi & 15;
    int w = tid>>6, lane = tid&63;
    for(int k=tid;k<16*67;k+=256) swL[k] = sw[i*16*67 + k];
    if(tid<16){ bsL[tid]=bs[i*16+tid]; omL[tid]=fabsf(om[i*16+tid]); }
    float v = xe[bi*256+tid];
    float m = wmax(fabsf(v));
    if(lane==0) red[w]=m;
    __syncthreads();
    m = fmaxf(fmaxf(red[0],red[1]),fmaxf(red[2],red[3]));
    float xn = v/(m+1e-8f);
    xn = fminf(fmaxf(xn,-0.99f),0.99f);
    float sil = xn/(1.f+expf(-xn));
    float vv = (xn+1.f)*33.f;
    int c0 = (int)floorf(vv)-1;
    float acc[16];
    #pragma unroll
    for(int j=0;j<16;j++) acc[j]=0.f;
    #pragma unroll
    for(int k=0;k<4;k++){
      int c = c0+k;
      if(c<0||c>66) continue;
      float d = fabsf(vv-(float)c);
      float bas = d<1.f ? (2.f/3.f - d*d + d*d*d*0.5f)
                : (d<2.f ? (2.f-d)*(2.f-d)*(2.f-d)*(1.f/6.f) : 0.f);
      #pragma unroll
      for(int j=0;j<16;j++) acc[j] += bas*swL[j*67+c];
    }
    float xav = xa[bi*256+tid];
    #pragma unroll
    for(int j=0;j<16;j++){
      float ev = sil*bsL[j] + acc[j] + omL[j];
      er2[(bi*16+j)*256+tid] = ev;
      float pe = wsum(fabsf(ev)*xav);
      if(lane==0) redE[j*4+w]=pe;
    }
    __syncthreads();
    if(tid<16){
      float e = (redE[tid*4+0]+redE[tid*4+1]+redE[tid*4+2]+redE[tid*4+3])*(1.f/256.f);
      float tv = fabsf(temp[0])+1e-4f;
      float ta = fabsf(tau[i*16+tid]);
      float mk = 1.f/(1.f+expf(-(e-ta)/tv));
      mask[bi*16+tid]=mk;
      cc[bi*16+tid]= e/(ta+1e-8f)*mk;
    }
  } else {
    // ---- kE2 body ----
    u16* AfB = (u16*)shm;
    u16* BfB = AfB + 8192;
    int e = blockIdx.x - 128;
    int b = e&7, m = (e>>3)&7, sx = (e>>6)&3, ty = e>>8;  // b lowest -> XCD=b
    int bm = b*8+m;
    int s0 = sx*64, t0 = ty*64;
    int row = tid>>2, dseg = tid&3;
    size_t offA = ((size_t)(b*16+m  )*256 + s0 + row)*64 + dseg*16;
    size_t offB = ((size_t)(b*16+m+8)*256 + t0 + row)*64 + dseg*16;
    int d0 = dseg*16;
    int ks0 = d0>>5, kb0 = (d0>>3)&3;
    int ks1 = (d0+8)>>5, kb1 = ((d0+8)>>3)&3;
    int lr = row&15, stile = row>>4;
    #define AOFF(h,stl,ks,ln) (((((h)*4+(stl))*2+(ks))*64 + (ln))*8)
    {
      uint4 v0 = *(const uint4*)(phi + offA);
      uint4 v1 = *(const uint4*)(phi + offA + 8);
      *(uint4*)(AfB + AOFF(0,stile,ks0,kb0*16+lr)) = v0;
      *(uint4*)(AfB + AOFF(0,stile,ks1,kb1*16+lr)) = v1;
      uint4 w0 = *(const uint4*)(plo + offA);
      uint4 w1 = *(const uint4*)(plo + offA + 8);
      *(uint4*)(AfB + AOFF(1,stile,ks0,kb0*16+lr)) = w0;
      *(uint4*)(AfB + AOFF(1,stile,ks1,kb1*16+lr)) = w1;
      uint4 x0 = *(const uint4*)(phi + offB);
      uint4 x1 = *(const uint4*)(phi + offB + 8);
      *(uint4*)(BfB + AOFF(0,stile,ks0,kb0*16+lr)) = x0;
      *(uint4*)(BfB + AOFF(0,stile,ks1,kb1*16+lr)) = x1;
      uint4 y0 = *(const uint4*)(plo + offB);
      uint4 y1 = *(const uint4*)(plo + offB + 8);
      *(uint4*)(BfB + AOFF(1,stile,ks0,kb0*16+lr)) = y0;
      *(uint4*)(BfB + AOFF(1,stile,ks1,kb1*16+lr)) = y1;
    }
    __syncthreads();
    int w = tid>>6, lane = tid&63;
    bf16x8 ah0 = *(const bf16x8*)(AfB + AOFF(0,w,0,lane));
    bf16x8 ah1 = *(const bf16x8*)(AfB + AOFF(0,w,1,lane));
    bf16x8 al0 = *(const bf16x8*)(AfB + AOFF(1,w,0,lane));
    bf16x8 al1 = *(const bf16x8*)(AfB + AOFF(1,w,1,lane));
    f32x4 acc[4];
    #pragma unroll
    for(int tt=0;tt<4;tt++) acc[tt] = (f32x4){0.f,0.f,0.f,0.f};
    #pragma unroll
    for(int tt=0;tt<4;tt++){
      bf16x8 bh0 = *(const bf16x8*)(BfB + AOFF(0,tt,0,lane));
      bf16x8 bh1 = *(const bf16x8*)(BfB + AOFF(0,tt,1,lane));
      bf16x8 bl0 = *(const bf16x8*)(BfB + AOFF(1,tt,0,lane));
      bf16x8 bl1 = *(const bf16x8*)(BfB + AOFF(1,tt,1,lane));
      acc[tt] = __builtin_amdgcn_mfma_f32_16x16x32_bf16(ah0, bh0, acc[tt], 0,0,0);
      acc[tt] = __builtin_amdgcn_mfma_f32_16x16x32_bf16(ah1, bh1, acc[tt], 0,0,0);
      acc[tt] = __builtin_amdgcn_mfma_f32_16x16x32_bf16(ah0, bl0, acc[tt], 0,0,0);
      acc[tt] = __builtin_amdgcn_mfma_f32_16x16x32_bf16(ah1, bl1, acc[tt], 0,0,0);
      acc[tt] = __builtin_amdgcn_mfma_f32_16x16x32_bf16(al0, bh0, acc[tt], 0,0,0);
      acc[tt] = __builtin_amdgcn_mfma_f32_16x16x32_bf16(al1, bh1, acc[tt], 0,0,0);
    }
    int col = lane&15, r4 = lane>>4;
    #pragma unroll
    for(int tt=0;tt<4;tt++){
      #pragma unroll
      for(int r=0;r<4;r++){
        G[((size_t)bm*256 + s0 + w*16 + r4*4 + r)*256 + t0 + tt*16 + col] = acc[tt][r];
      }
    }
    #undef AOFF
  }
}

// D v2: vectorized gather — wave covers 4 s-rows x 64 f per load (512B);
// thread owns 4 f (ushort4). LN via 16-lane butterfly. MFMA part unchanged.
__global__ void __launch_bounds__(256) kD(
                   const u16* __restrict__ xinb, const float* __restrict__ er2,
                   const float* __restrict__ mask, const u16* __restrict__ w2B,
                   const float* __restrict__ lnw, const float* __restrict__ lnb,
                   const float* __restrict__ bp,
                   u16* __restrict__ xoutb, float* __restrict__ xp,
                   u16* __restrict__ xpB){
  int b = blockIdx.x, j = blockIdx.y, st = blockIdx.z;
  int tid = threadIdx.x, w = tid>>6, lane = tid&63;
  __shared__ __align__(16) u16 xnS[16*64];  // bf16, XOR-swizzled
  __shared__ float mcL[16];
  if(tid<16) mcL[tid]=mask[(b*16+tid)*16+j];
  __syncthreads();
  int bj = b*16+j;
  unsigned char* xnB = (unsigned char*)xnS;
  int ss = lane>>4, fq = lane&15;
  int sl = w*4 + ss;
  int s  = st*16 + sl;
  float4 lw4 = *(const float4*)(lnw + j*64 + fq*4);
  float4 lb4 = *(const float4*)(lnb + j*64 + fq*4);
  float acc0=0.f,acc1=0.f,acc2=0.f,acc3=0.f;
  #pragma unroll
  for(int i=0;i<16;i++){
    float er = er2[((b*16+i)*16+j)*256+s]*mcL[i];
    ushort4 xv = *(const ushort4*)(xinb + ((size_t)(b*16+i)*256+s)*64 + fq*4);
    acc0 += er*bf2f(xv.x);
    acc1 += er*bf2f(xv.y);
    acc2 += er*bf2f(xv.z);
    acc3 += er*bf2f(xv.w);
  }
  acc0*=(1.f/16.f); acc1*=(1.f/16.f); acc2*=(1.f/16.f); acc3*=(1.f/16.f);
  {
    u16 pk[4]={f2bf(acc0),f2bf(acc1),f2bf(acc2),f2bf(acc3)};
    *(ushort4*)(xoutb + ((size_t)bj*256+s)*64 + fq*4) = *(ushort4*)pk;
  }
  float part = acc0+acc1+acc2+acc3;
  part += __shfl_xor(part,1); part += __shfl_xor(part,2);
  part += __shfl_xor(part,4); part += __shfl_xor(part,8);
  float mu = part*(1.f/64.f);
  float d0=acc0-mu, d1=acc1-mu, d2=acc2-mu, d3=acc3-mu;
  float p2 = d0*d0+d1*d1+d2*d2+d3*d3;
  p2 += __shfl_xor(p2,1); p2 += __shfl_xor(p2,2);
  p2 += __shfl_xor(p2,4); p2 += __shfl_xor(p2,8);
  float rstd = rsqrtf(p2*(1.f/64.f)+EPSLN);
  {
    u16 xn[4] = { f2bf(d0*rstd*lw4.x + lb4.x), f2bf(d1*rstd*lw4.y + lb4.y),
                  f2bf(d2*rstd*lw4.z + lb4.z), f2bf(d3*rstd*lw4.w + lb4.w) };
    *(ushort4*)(xnB + ((sl*128 + fq*8) ^ ((sl&7)<<4))) = *(ushort4*)xn;
  }
  __syncthreads();
  f32x4 acc = {0.f,0.f,0.f,0.f};
  int m = lane&15, kb = lane>>4;
  #pragma unroll
  for(int ks=0;ks<2;ks++){
    bf16x8 a = *(const bf16x8*)(xnB + ((m*128 + ks*64 + kb*16) ^ ((m&7)<<4)));
    bf16x8 bfr = *(const bf16x8*)(w2B + ((j*2+ks)*4 + w)*512 + lane*8);
    acc = __builtin_amdgcn_mfma_f32_16x16x32_bf16(a, bfr, acc, 0, 0, 0);
  }
  int f = w*16 + m;
  u16 pk[4];
  #pragma unroll
  for(int r=0;r<4;r++){
    int si = kb*4 + r;
    int s2 = st*16 + si;
    float xpr = acc[r] + bp[((size_t)j*256+s2)*64+f];
    xp[((size_t)bj*256+s2)*64+f] = xpr;
    pk[r] = f2bf(xpr);
  }
  int s0 = st*16 + kb*4;
  int flat = ((s0>>5)*4 + w)*512 + ((s0>>3)&3)*128 + m*8 + (s0&7);
  *(ushort4*)(xpB + (size_t)bj*16384 + flat) = *(ushort4*)pk;
}

// F v2: 4 j per block (each G load feeds 4 dots; G L2 traffic halves);
//       __expf softmax (defer-max); MFMA AV x4; 2-pass LDS conv epilogue.
//       b in blockIdx.x -> XCD=b. LDS 41.5KB -> 2 blocks/CU, grid 512 resident.
__global__ void __launch_bounds__(256) kF(
    const float* __restrict__ G, const float* __restrict__ cc,
    const float* __restrict__ Sv, const float* __restrict__ SSv,
    const float* __restrict__ xp, const u16* __restrict__ xpB,
    const float* __restrict__ cw,
    const u16* __restrict__ xarrb, const float* __restrict__ temp,
    const float* __restrict__ alpha, const float* __restrict__ beta,
    const float* __restrict__ gamma_, const float* __restrict__ theta,
    float* __restrict__ out){
  int b = blockIdx.x, jp = blockIdx.y, st = blockIdx.z;
  int j0 = jp*4;
  int tid = threadIdx.x, w = tid>>6, lane = tid&63;
  __shared__ __align__(16) unsigned char ovl[41472];
  // [0,32768) probs[4][8192] | [32768,+4K) mQ[4][256] | [36864,+4K) rQ[4][256]
  // [40960,+256) mK[4][16] | [41216,+256) rK[4][16]
  // xpT [2][3][16][68] f32 overlays [0,26112) during epilogue passes.
  float* mQL = (float*)(ovl + 32768);
  float* rQL = (float*)(ovl + 36864);
  float* mKL = (float*)(ovl + 40960);
  float* rKL = (float*)(ovl + 41216);
  float* xpT = (float*)ovl;
  float tv = fabsf(temp[0])+1e-4f;
  float inv = 1.f/(sqrtf(512.f)*tv);
  float aM0[8],aM1[8],aM2[8],aM3[8];
  {
    int t = tid;
    float sk0=0,sk1=0,sk2=0,sk3=0, ssk0=0,ssk1=0,ssk2=0,ssk3=0;
    float sq0=0,sq1=0,sq2=0,sq3=0, ssq0=0,ssq1=0,ssq2=0,ssq3=0;
    #pragma unroll
    for(int m=0;m<8;m++){
      float4 ck = *(const float4*)(cc + (b*16+m  )*16 + j0);
      float4 cq = *(const float4*)(cc + (b*16+m+8)*16 + j0);
      aM0[m]=ck.x*cq.x; aM1[m]=ck.y*cq.y; aM2[m]=ck.z*cq.z; aM3[m]=ck.w*cq.w;
      float svk = Sv [(b*16+m)*256+t];
      float ssvk= SSv[(b*16+m)*256+t];
      float svq = Sv [(b*16+m+8)*256+t];
      float ssvq= SSv[(b*16+m+8)*256+t];
      sk0 += ck.x*svk; ssk0 += ck.x*ck.x*ssvk;
      sk1 += ck.y*svk; ssk1 += ck.y*ck.y*ssvk;
      sk2 += ck.z*svk; ssk2 += ck.z*ck.z*ssvk;
      sk3 += ck.w*svk; ssk3 += ck.w*ck.w*ssvk;
      sq0 += cq.x*svq; ssq0 += cq.x*cq.x*ssvq;
      sq1 += cq.y*svq; ssq1 += cq.y*cq.y*ssvq;
      sq2 += cq.z*svq; ssq2 += cq.z*cq.z*ssvq;
      sq3 += cq.w*svq; ssq3 += cq.w*cq.w*ssvq;
    }
    float mq;
    mq = sq0*(1.f/512.f); mQL[0*256+t]=mq; rQL[0*256+t]=rsqrtf(ssq0*(1.f/512.f)-mq*mq+EPSLN);
    mq = sq1*(1.f/512.f); mQL[1*256+t]=mq; rQL[1*256+t]=rsqrtf(ssq1*(1.f/512.f)-mq*mq+EPSLN);
    mq = sq2*(1.f/512.f); mQL[2*256+t]=mq; rQL[2*256+t]=rsqrtf(ssq2*(1.f/512.f)-mq*mq+EPSLN);
    mq = sq3*(1.f/512.f); mQL[3*256+t]=mq; rQL[3*256+t]=rsqrtf(ssq3*(1.f/512.f)-mq*mq+EPSLN);
    if((t>>4)==st){
      int si = t&15;
      float mk;
      mk = sk0*(1.f/512.f); mKL[0*16+si]=mk; rKL[0*16+si]=rsqrtf(ssk0*(1.f/512.f)-mk*mk+EPSLN);
      mk = sk1*(1.f/512.f); mKL[1*16+si]=mk; rKL[1*16+si]=rsqrtf(ssk1*(1.f/512.f)-mk*mk+EPSLN);
      mk = sk2*(1.f/512.f); mKL[2*16+si]=mk; rKL[2*16+si]=rsqrtf(ssk2*(1.f/512.f)-mk*mk+EPSLN);
      mk = sk3*(1.f/512.f); mKL[3*16+si]=mk; rKL[3*16+si]=rsqrtf(ssk3*(1.f/512.f)-mk*mk+EPSLN);
    }
  }
  __syncthreads();
  const float* Gb = G + (size_t)(b*8)*65536;
  float4 mQ4a = *(const float4*)&mQL[0*256+lane*4];
  float4 rQ4a = *(const float4*)&rQL[0*256+lane*4];
  float4 mQ4b = *(const float4*)&mQL[1*256+lane*4];
  float4 rQ4b = *(const float4*)&rQL[1*256+lane*4];
  float4 mQ4c = *(const float4*)&mQL[2*256+lane*4];
  float4 rQ4c = *(const float4*)&rQL[2*256+lane*4];
  float4 mQ4d = *(const float4*)&mQL[3*256+lane*4];
  float4 rQ4d = *(const float4*)&rQL[3*256+lane*4];
  #pragma unroll
  for(int q=0;q<4;q++){
    int si = w*4+q;
    int s = st*16 + si;
    f32x4 dt0={0.f,0.f,0.f,0.f}, dt1={0.f,0.f,0.f,0.f};
    f32x4 dt2={0.f,0.f,0.f,0.f}, dt3={0.f,0.f,0.f,0.f};
    #pragma unroll
    for(int m=0;m<8;m++){
      f32x4 g4 = *(const f32x4*)(Gb + (size_t)m*65536 + s*256 + lane*4);
      dt0 += aM0[m]*g4; dt1 += aM1[m]*g4;
      dt2 += aM2[m]*g4; dt3 += aM3[m]*g4;
    }
    // defer-max: LN'd rows => |raw| <= sqrt(512)/tv ~ 22.6, exp safe without max-sub
    #define SMAX(JJ, DT, MQ, RQ) { \
      float mKs = 512.f*mKL[JJ*16+si], rKs = rKL[JJ*16+si]; \
      float e0 = __expf((DT[0] - mKs*MQ.x)*rKs*RQ.x*inv); \
      float e1 = __expf((DT[1] - mKs*MQ.y)*rKs*RQ.y*inv); \
      float e2 = __expf((DT[2] - mKs*MQ.z)*rKs*RQ.z*inv); \
      float e3 = __expf((DT[3] - mKs*MQ.w)*rKs*RQ.w*inv); \
      float isf = 1.f/wsum(e0+e1+e2+e3); \
      u16 pk[4] = {f2bf(e0*isf), f2bf(e1*isf), f2bf(e2*isf), f2bf(e3*isf)}; \
      *(ushort4*)(ovl + JJ*8192 + ((si*512 + lane*8) ^ ((si&7)<<4))) = *(ushort4*)pk; }
    SMAX(0, dt0, mQ4a, rQ4a)
    SMAX(1, dt1, mQ4b, rQ4b)
    SMAX(2, dt2, mQ4c, rQ4c)
    SMAX(3, dt3, mQ4d, rQ4d)
    #undef SMAX
  }
  __syncthreads();
  int m_ = lane&15, kb = lane>>4;
  f32x4 av0={0.f,0.f,0.f,0.f}, av1={0.f,0.f,0.f,0.f};
  f32x4 av2={0.f,0.f,0.f,0.f}, av3={0.f,0.f,0.f,0.f};
  const u16* xpB0 = xpB + (size_t)(b*16+j0  )*16384;
  const u16* xpB1 = xpB + (size_t)(b*16+j0+1)*16384;
  const u16* xpB2 = xpB + (size_t)(b*16+j0+2)*16384;
  const u16* xpB3 = xpB + (size_t)(b*16+j0+3)*16384;
  #pragma unroll
  for(int ks=0;ks<8;ks++){
    int aoff = (m_*512 + ks*64 + kb*16) ^ ((m_&7)<<4);
    int boff = ((ks*4 + w)*64 + lane)*8;
    bf16x8 a0 = *(const bf16x8*)(ovl +         aoff);
    bf16x8 a1 = *(const bf16x8*)(ovl +  8192 + aoff);
    bf16x8 a2 = *(const bf16x8*)(ovl + 16384 + aoff);
    bf16x8 a3 = *(const bf16x8*)(ovl + 24576 + aoff);
    av0 = __builtin_amdgcn_mfma_f32_16x16x32_bf16(a0, *(const bf16x8*)(xpB0 + boff), av0, 0,0,0);
    av1 = __builtin_amdgcn_mfma_f32_16x16x32_bf16(a1, *(const bf16x8*)(xpB1 + boff), av1, 0,0,0);
    av2 = __builtin_amdgcn_mfma_f32_16x16x32_bf16(a2, *(const bf16x8*)(xpB2 + boff), av2, 0,0,0);
    av3 = __builtin_amdgcn_mfma_f32_16x16x32_bf16(a3, *(const bf16x8*)(xpB3 + boff), av3, 0,0,0);
  }
  int f = w*16 + m_;
  #pragma unroll
  for(int pass=0; pass<2; pass++){
    __syncthreads();   // previous ovl readers done (probs/stats or pass-0 xpT)
    // stage xpT window for j-pair (j0+pass*2, j0+pass*2+1)
    for(int idx4 = tid; idx4 < 1536; idx4 += 256){
      int jj = idx4 / 768;
      int rem = idx4 - jj*768;
      int rr_i = rem >> 8;
      int pos = rem & 255;
      int ci = pos>>4, f4 = pos&15;
      int grow = st - 1 + rr_i;
      float4 v = {0.f,0.f,0.f,0.f};
      if(grow>=0 && grow<16){
        v = *(const float4*)(xp + ((size_t)(b*16+j0+pass*2+jj)*256 + grow*16 + ci)*64 + f4*4);
      }
      *(float4*)(xpT + ((jj*3+rr_i)*16+ci)*68 + f4*4) = v;
    }
    __syncthreads();
    #pragma unroll
    for(int jj=0;jj<2;jj++){
      int j = j0 + pass*2 + jj;
      int bj = b*16+j;
      f32x4 acc = pass==0 ? (jj?av1:av0) : (jj?av3:av2);
      float al = fabsf(alpha[j]), be=fabsf(beta[j]), th=fabsf(theta[j]), ga=gamma_[j];
      const float* wq = cw + (j*64+f)*9;
      float w0=wq[0],w1=wq[1],w2=wq[2],w3v=wq[3],w4=wq[4],w5=wq[5],w6=wq[6],w7=wq[7],w8=wq[8];
      #pragma unroll
      for(int r=0;r<4;r++){
        int si = kb*4 + r;
        int s = st*16 + si;
        float gl = acc[r];
        float cv=0.f;
        #pragma unroll
        for(int dr=0;dr<3;dr++){
          float kw0 = dr==0?w0:(dr==1?w3v:w6);
          float kw1 = dr==0?w1:(dr==1?w4:w7);
          float kw2 = dr==0?w2:(dr==1?w5:w8);
          const float* rowp = xpT + ((jj*3+dr)*16)*68;
          if(si>0)  cv += rowp[(si-1)*68+f]*kw0;
                    cv += rowp[(si  )*68+f]*kw1;
          if(si<15) cv += rowp[(si+1)*68+f]*kw2;
        }
        float diag = xpT[((jj*3+1)*16+si)*68+f];
        size_t gi = ((size_t)bj*256+s)*64+f;
        out[gi] = be*gl + al*diag + th*cv + ga*bf2f(xarrb[gi]);
      }
    }
  }
}

extern "C" void kernel_launch(void* const* d_in, const int* in_sizes, int n_in,
                              void* d_out, int out_size, void* d_ws, size_t ws_size,
                              hipStream_t stream) {
  const float* xin = (const float*)d_in[0];
  const float* pxp = (const float*)d_in[1];
  const float* sw  = (const float*)d_in[2];
  const float* bs  = (const float*)d_in[3];
  const float* tau = (const float*)d_in[4];
  const float* temp= (const float*)d_in[5];
  const float* om  = (const float*)d_in[6];
  const float* W2  = (const float*)d_in[7];
  const float* bp  = (const float*)d_in[8];
  const float* lnw = (const float*)d_in[9];
  const float* lnb = (const float*)d_in[10];
  const float* alpha=(const float*)d_in[11];
  const float* beta= (const float*)d_in[12];
  const float* gam = (const float*)d_in[13];
  const float* theta=(const float*)d_in[14];
  const float* cw  = (const float*)d_in[15];
  float* outp = (float*)d_out;
  float* xpo  = outp + 2097152;   // x_prime = second output

  float* ws  = (float*)d_ws;
  float* xe  = ws;                // 32768
  float* xa  = xe + 32768;        // 32768
  float* Sv  = xa + 32768;        // 32768
  float* SSv = Sv + 32768;        // 32768
  float* er2 = SSv + 32768;       // 524288
  float* mask= er2 + 524288;      // 2048
  float* ccv = mask + 2048;       // 2048
  float* Gv  = ccv + 2048;        // 4194304
  u16* xvb = (u16*)(Gv + 4194304);    // 2097152 u16 (bf16 x)
  u16* xpB = xvb + 2097152;           // 2097152 u16
  u16* w2B = xpB + 2097152;           // 65536 u16
  u16* xinb= w2B + 65536;             // 2097152 u16
  u16* phi = xinb + 2097152;          // 2097152 u16
  u16* plo = phi + 2097152;           // 2097152 u16

  kA<<<1024,256,0,stream>>>(xin,pxp,W2,xe,xa,Sv,SSv,xinb,phi,plo,w2B);
  kBE<<<1152,256,0,stream>>>(xe,sw,bs,om,xa,tau,temp,er2,mask,ccv,phi,plo,Gv);
  kD<<<dim3(8,16,16),256,0,stream>>>(xinb,er2,mask,w2B,lnw,lnb,bp,xvb,xpo,xpB);
  kF<<<dim3(8,4,16),256,0,stream>>>(Gv,ccv,Sv,SSv,xpo,xpB,cw,xvb,temp,
                                    alpha,beta,gam,theta,outp);
}

// Round 16
// 55.258 us; speedup vs baseline: 1.3163x; 1.0219x over previous
//
#include <hip/hip_runtime.h>

#define EPSLN 1e-5f

typedef short bf16x8 __attribute__((ext_vector_type(8)));
typedef float f32x4 __attribute__((ext_vector_type(4)));
typedef unsigned short u16;
typedef unsigned short u16x8 __attribute__((ext_vector_type(8)));

__device__ __forceinline__ float wsum(float v){
  #pragma unroll
  for(int o=32;o;o>>=1) v += __shfl_xor(v,o);
  return v;
}
__device__ __forceinline__ float wmax(float v){
  #pragma unroll
  for(int o=32;o;o>>=1) v = fmaxf(v,__shfl_xor(v,o));
  return v;
}
__device__ __forceinline__ u16 f2bf(float f){
  unsigned int u = __float_as_uint(f);
  u = (u + 0x7FFFu + ((u>>16)&1u)) >> 16;
  return (u16)u;
}
__device__ __forceinline__ float bf2f(u16 h){
  return __uint_as_float(((unsigned int)h)<<16);
}

// A: eighth-row per thread. Blocks 0..15 also pack W2 into bf16 B-frag order.
__global__ void __launch_bounds__(256) kA(
                   const float* __restrict__ xin, const float* __restrict__ p,
                   const float* __restrict__ W2,
                   float* __restrict__ xe, float* __restrict__ xa,
                   float* __restrict__ Sv, float* __restrict__ SSv,
                   u16* __restrict__ xinb, u16* __restrict__ phi, u16* __restrict__ plo,
                   u16* __restrict__ w2B){
  int t = threadIdx.x;
  int rl = t>>3, q = t&7;
  int row = blockIdx.x*32 + rl;
  const float4* xr = (const float4*)(xin + row*64 + q*8);
  const float4* pr = (const float4*)(p   + row*64 + q*8);
  float s1=0.f,s2=0.f,s3=0.f,s4=0.f;
  u16x8 xb, ph, pl;
  #pragma unroll
  for(int k=0;k<2;k++){
    float4 xv = xr[k];
    float4 pv = pr[k];
    s1 += xv.x+xv.y+xv.z+xv.w;
    s2 += fabsf(xv.x)+fabsf(xv.y)+fabsf(xv.z)+fabsf(xv.w);
    s3 += pv.x+pv.y+pv.z+pv.w;
    s4 += pv.x*pv.x+pv.y*pv.y+pv.z*pv.z+pv.w*pv.w;
    int o = k*4;
    xb[o+0]=f2bf(xv.x); xb[o+1]=f2bf(xv.y); xb[o+2]=f2bf(xv.z); xb[o+3]=f2bf(xv.w);
    u16 h0=f2bf(pv.x), h1=f2bf(pv.y), h2=f2bf(pv.z), h3=f2bf(pv.w);
    ph[o+0]=h0; ph[o+1]=h1; ph[o+2]=h2; ph[o+3]=h3;
    pl[o+0]=f2bf(pv.x-bf2f(h0)); pl[o+1]=f2bf(pv.y-bf2f(h1));
    pl[o+2]=f2bf(pv.z-bf2f(h2)); pl[o+3]=f2bf(pv.w-bf2f(h3));
  }
  *(u16x8*)(xinb + row*64 + q*8) = xb;
  *(u16x8*)(phi  + row*64 + q*8) = ph;
  *(u16x8*)(plo  + row*64 + q*8) = pl;
  s1 += __shfl_xor(s1,1); s1 += __shfl_xor(s1,2); s1 += __shfl_xor(s1,4);
  s2 += __shfl_xor(s2,1); s2 += __shfl_xor(s2,2); s2 += __shfl_xor(s2,4);
  s3 += __shfl_xor(s3,1); s3 += __shfl_xor(s3,2); s3 += __shfl_xor(s3,4);
  s4 += __shfl_xor(s4,1); s4 += __shfl_xor(s4,2); s4 += __shfl_xor(s4,4);
  if(q==0){ xe[row]=s1*(1.f/64.f); xa[row]=s2*(1.f/64.f); Sv[row]=s3; SSv[row]=s4; }
  if(blockIdx.x<16){
    int j = blockIdx.x;
    for(int idx=threadIdx.x; idx<4096; idx+=256){
      int f = idx>>6, o = idx&63;
      float v = W2[j*4096 + idx];
      int ks = f>>5, kb = (f>>3)&3, i = f&7;
      int nt = o>>4, col = o&15;
      int ln = kb*16 + col;
      w2B[((j*2+ks)*4 + nt)*512 + ln*8 + i] = f2bf(v);
    }
  }
}

// BE: fused kB (blocks 0..127, er2 out in bf16) + kE2 gram MFMA (blocks 128..1151).
__global__ void __launch_bounds__(256) kBE(
                   const float* __restrict__ xe, const float* __restrict__ sw,
                   const float* __restrict__ bs, const float* __restrict__ om,
                   const float* __restrict__ xa, const float* __restrict__ tau,
                   const float* __restrict__ temp,
                   u16* __restrict__ er2b, float* __restrict__ mask,
                   float* __restrict__ cc,
                   const u16* __restrict__ phi, const u16* __restrict__ plo,
                   float* __restrict__ G){
  __shared__ __align__(16) unsigned char shm[32768];
  int tid = threadIdx.x;
  if(blockIdx.x < 128){
    // ---- kB body ----
    float* swL = (float*)shm;
    float* bsL = swL + 1072;
    float* omL = bsL + 16;
    float* red = omL + 16;
    float* redE= red + 4;              // [16][4]
    int bi = blockIdx.x;
    int i = bi & 15;
    int w = tid>>6, lane = tid&63;
    for(int k=tid;k<16*67;k+=256) swL[k] = sw[i*16*67 + k];
    if(tid<16){ bsL[tid]=bs[i*16+tid]; omL[tid]=fabsf(om[i*16+tid]); }
    float v = xe[bi*256+tid];
    float m = wmax(fabsf(v));
    if(lane==0) red[w]=m;
    __syncthreads();
    m = fmaxf(fmaxf(red[0],red[1]),fmaxf(red[2],red[3]));
    float xn = v/(m+1e-8f);
    xn = fminf(fmaxf(xn,-0.99f),0.99f);
    float sil = xn/(1.f+expf(-xn));
    float vv = (xn+1.f)*33.f;
    int c0 = (int)floorf(vv)-1;
    float acc[16];
    #pragma unroll
    for(int j=0;j<16;j++) acc[j]=0.f;
    #pragma unroll
    for(int k=0;k<4;k++){
      int c = c0+k;
      if(c<0||c>66) continue;
      float d = fabsf(vv-(float)c);
      float bas = d<1.f ? (2.f/3.f - d*d + d*d*d*0.5f)
                : (d<2.f ? (2.f-d)*(2.f-d)*(2.f-d)*(1.f/6.f) : 0.f);
      #pragma unroll
      for(int j=0;j<16;j++) acc[j] += bas*swL[j*67+c];
    }
    float xav = xa[bi*256+tid];
    #pragma unroll
    for(int j=0;j<16;j++){
      float ev = sil*bsL[j] + acc[j] + omL[j];
      er2b[(bi*16+j)*256+tid] = f2bf(ev);
      float pe = wsum(fabsf(ev)*xav);
      if(lane==0) redE[j*4+w]=pe;
    }
    __syncthreads();
    if(tid<16){
      float e = (redE[tid*4+0]+redE[tid*4+1]+redE[tid*4+2]+redE[tid*4+3])*(1.f/256.f);
      float tv = fabsf(temp[0])+1e-4f;
      float ta = fabsf(tau[i*16+tid]);
      float mk = 1.f/(1.f+expf(-(e-ta)/tv));
      mask[bi*16+tid]=mk;
      cc[bi*16+tid]= e/(ta+1e-8f)*mk;
    }
  } else {
    // ---- kE2 body ----
    u16* AfB = (u16*)shm;
    u16* BfB = AfB + 8192;
    int e = blockIdx.x - 128;
    int b = e&7, m = (e>>3)&7, sx = (e>>6)&3, ty = e>>8;  // b lowest -> XCD=b
    int bm = b*8+m;
    int s0 = sx*64, t0 = ty*64;
    int row = tid>>2, dseg = tid&3;
    size_t offA = ((size_t)(b*16+m  )*256 + s0 + row)*64 + dseg*16;
    size_t offB = ((size_t)(b*16+m+8)*256 + t0 + row)*64 + dseg*16;
    int d0 = dseg*16;
    int ks0 = d0>>5, kb0 = (d0>>3)&3;
    int ks1 = (d0+8)>>5, kb1 = ((d0+8)>>3)&3;
    int lr = row&15, stile = row>>4;
    #define AOFF(h,stl,ks,ln) (((((h)*4+(stl))*2+(ks))*64 + (ln))*8)
    {
      uint4 v0 = *(const uint4*)(phi + offA);
      uint4 v1 = *(const uint4*)(phi + offA + 8);
      *(uint4*)(AfB + AOFF(0,stile,ks0,kb0*16+lr)) = v0;
      *(uint4*)(AfB + AOFF(0,stile,ks1,kb1*16+lr)) = v1;
      uint4 w0 = *(const uint4*)(plo + offA);
      uint4 w1 = *(const uint4*)(plo + offA + 8);
      *(uint4*)(AfB + AOFF(1,stile,ks0,kb0*16+lr)) = w0;
      *(uint4*)(AfB + AOFF(1,stile,ks1,kb1*16+lr)) = w1;
      uint4 x0 = *(const uint4*)(phi + offB);
      uint4 x1 = *(const uint4*)(phi + offB + 8);
      *(uint4*)(BfB + AOFF(0,stile,ks0,kb0*16+lr)) = x0;
      *(uint4*)(BfB + AOFF(0,stile,ks1,kb1*16+lr)) = x1;
      uint4 y0 = *(const uint4*)(plo + offB);
      uint4 y1 = *(const uint4*)(plo + offB + 8);
      *(uint4*)(BfB + AOFF(1,stile,ks0,kb0*16+lr)) = y0;
      *(uint4*)(BfB + AOFF(1,stile,ks1,kb1*16+lr)) = y1;
    }
    __syncthreads();
    int w = tid>>6, lane = tid&63;
    bf16x8 ah0 = *(const bf16x8*)(AfB + AOFF(0,w,0,lane));
    bf16x8 ah1 = *(const bf16x8*)(AfB + AOFF(0,w,1,lane));
    bf16x8 al0 = *(const bf16x8*)(AfB + AOFF(1,w,0,lane));
    bf16x8 al1 = *(const bf16x8*)(AfB + AOFF(1,w,1,lane));
    f32x4 acc[4];
    #pragma unroll
    for(int tt=0;tt<4;tt++) acc[tt] = (f32x4){0.f,0.f,0.f,0.f};
    #pragma unroll
    for(int tt=0;tt<4;tt++){
      bf16x8 bh0 = *(const bf16x8*)(BfB + AOFF(0,tt,0,lane));
      bf16x8 bh1 = *(const bf16x8*)(BfB + AOFF(0,tt,1,lane));
      bf16x8 bl0 = *(const bf16x8*)(BfB + AOFF(1,tt,0,lane));
      bf16x8 bl1 = *(const bf16x8*)(BfB + AOFF(1,tt,1,lane));
      acc[tt] = __builtin_amdgcn_mfma_f32_16x16x32_bf16(ah0, bh0, acc[tt], 0,0,0);
      acc[tt] = __builtin_amdgcn_mfma_f32_16x16x32_bf16(ah1, bh1, acc[tt], 0,0,0);
      acc[tt] = __builtin_amdgcn_mfma_f32_16x16x32_bf16(ah0, bl0, acc[tt], 0,0,0);
      acc[tt] = __builtin_amdgcn_mfma_f32_16x16x32_bf16(ah1, bl1, acc[tt], 0,0,0);
      acc[tt] = __builtin_amdgcn_mfma_f32_16x16x32_bf16(al0, bh0, acc[tt], 0,0,0);
      acc[tt] = __builtin_amdgcn_mfma_f32_16x16x32_bf16(al1, bh1, acc[tt], 0,0,0);
    }
    int col = lane&15, r4 = lane>>4;
    #pragma unroll
    for(int tt=0;tt<4;tt++){
      #pragma unroll
      for(int r=0;r<4;r++){
        G[((size_t)bm*256 + s0 + w*16 + r4*4 + r)*256 + t0 + tt*16 + col] = acc[tt][r];
      }
    }
    #undef AOFF
  }
}

// D v2: vectorized gather (er2 now bf16); LN via 16-lane butterfly; MFMA W2.
__global__ void __launch_bounds__(256) kD(
                   const u16* __restrict__ xinb, const u16* __restrict__ er2b,
                   const float* __restrict__ mask, const u16* __restrict__ w2B,
                   const float* __restrict__ lnw, const float* __restrict__ lnb,
                   const float* __restrict__ bp,
                   u16* __restrict__ xoutb, float* __restrict__ xp,
                   u16* __restrict__ xpB){
  int b = blockIdx.x, j = blockIdx.y, st = blockIdx.z;
  int tid = threadIdx.x, w = tid>>6, lane = tid&63;
  __shared__ __align__(16) u16 xnS[16*64];  // bf16, XOR-swizzled
  __shared__ float mcL[16];
  if(tid<16) mcL[tid]=mask[(b*16+tid)*16+j];
  __syncthreads();
  int bj = b*16+j;
  unsigned char* xnB = (unsigned char*)xnS;
  int ss = lane>>4, fq = lane&15;
  int sl = w*4 + ss;
  int s  = st*16 + sl;
  float4 lw4 = *(const float4*)(lnw + j*64 + fq*4);
  float4 lb4 = *(const float4*)(lnb + j*64 + fq*4);
  float acc0=0.f,acc1=0.f,acc2=0.f,acc3=0.f;
  #pragma unroll
  for(int i=0;i<16;i++){
    float er = bf2f(er2b[((b*16+i)*16+j)*256+s])*mcL[i];
    ushort4 xv = *(const ushort4*)(xinb + ((size_t)(b*16+i)*256+s)*64 + fq*4);
    acc0 += er*bf2f(xv.x);
    acc1 += er*bf2f(xv.y);
    acc2 += er*bf2f(xv.z);
    acc3 += er*bf2f(xv.w);
  }
  acc0*=(1.f/16.f); acc1*=(1.f/16.f); acc2*=(1.f/16.f); acc3*=(1.f/16.f);
  {
    u16 pk[4]={f2bf(acc0),f2bf(acc1),f2bf(acc2),f2bf(acc3)};
    *(ushort4*)(xoutb + ((size_t)bj*256+s)*64 + fq*4) = *(ushort4*)pk;
  }
  float part = acc0+acc1+acc2+acc3;
  part += __shfl_xor(part,1); part += __shfl_xor(part,2);
  part += __shfl_xor(part,4); part += __shfl_xor(part,8);
  float mu = part*(1.f/64.f);
  float d0=acc0-mu, d1=acc1-mu, d2=acc2-mu, d3=acc3-mu;
  float p2 = d0*d0+d1*d1+d2*d2+d3*d3;
  p2 += __shfl_xor(p2,1); p2 += __shfl_xor(p2,2);
  p2 += __shfl_xor(p2,4); p2 += __shfl_xor(p2,8);
  float rstd = rsqrtf(p2*(1.f/64.f)+EPSLN);
  {
    u16 xn[4] = { f2bf(d0*rstd*lw4.x + lb4.x), f2bf(d1*rstd*lw4.y + lb4.y),
                  f2bf(d2*rstd*lw4.z + lb4.z), f2bf(d3*rstd*lw4.w + lb4.w) };
    *(ushort4*)(xnB + ((sl*128 + fq*8) ^ ((sl&7)<<4))) = *(ushort4*)xn;
  }
  __syncthreads();
  f32x4 acc = {0.f,0.f,0.f,0.f};
  int m = lane&15, kb = lane>>4;
  #pragma unroll
  for(int ks=0;ks<2;ks++){
    bf16x8 a = *(const bf16x8*)(xnB + ((m*128 + ks*64 + kb*16) ^ ((m&7)<<4)));
    bf16x8 bfr = *(const bf16x8*)(w2B + ((j*2+ks)*4 + w)*512 + lane*8);
    acc = __builtin_amdgcn_mfma_f32_16x16x32_bf16(a, bfr, acc, 0, 0, 0);
  }
  int f = w*16 + m;
  u16 pk[4];
  #pragma unroll
  for(int r=0;r<4;r++){
    int si = kb*4 + r;
    int s2 = st*16 + si;
    float xpr = acc[r] + bp[((size_t)j*256+s2)*64+f];
    xp[((size_t)bj*256+s2)*64+f] = xpr;
    pk[r] = f2bf(xpr);
  }
  int s0 = st*16 + kb*4;
  int flat = ((s0>>5)*4 + w)*512 + ((s0>>3)&3)*128 + m*8 + (s0&7);
  *(ushort4*)(xpB + (size_t)bj*16384 + flat) = *(ushort4*)pk;
}

// F v3: 4 j per block, but only 2 prob panels (16KB) live at once — j2/j3 probs
//       held in registers, spilled to the reused panels between AV passes.
//       LDS 25.5KB -> 6 blocks/CU (3x occupancy of v2). b in blockIdx.x -> XCD=b.
__global__ void __launch_bounds__(256) kF(
    const float* __restrict__ G, const float* __restrict__ cc,
    const float* __restrict__ Sv, const float* __restrict__ SSv,
    const float* __restrict__ xp, const u16* __restrict__ xpB,
    const float* __restrict__ cw,
    const u16* __restrict__ xarrb, const float* __restrict__ temp,
    const float* __restrict__ alpha, const float* __restrict__ beta,
    const float* __restrict__ gamma_, const float* __restrict__ theta,
    float* __restrict__ out){
  int b = blockIdx.x, jp = blockIdx.y, st = blockIdx.z;
  int j0 = jp*4;
  int tid = threadIdx.x, w = tid>>6, lane = tid&63;
  __shared__ __align__(16) unsigned char ovl[26112];
  // [0,8192) prob panel A | [8192,16384) prob panel B
  // [16384,+4K) mQ[4][256] | [20480,+4K) rQ[4][256] | [24576,+256) mK[4][16] | [24832,+256) rK
  // xpT [2][3][16][68] f32 overlays [0,26112) during epilogue.
  unsigned char* prA = ovl;
  unsigned char* prB = ovl + 8192;
  float* mQL = (float*)(ovl + 16384);
  float* rQL = (float*)(ovl + 20480);
  float* mKL = (float*)(ovl + 24576);
  float* rKL = (float*)(ovl + 24832);
  float* xpT = (float*)ovl;
  float tv = fabsf(temp[0])+1e-4f;
  float inv = 1.f/(sqrtf(512.f)*tv);
  float aM0[8],aM1[8],aM2[8],aM3[8];
  {
    int t = tid;
    float sk0=0,sk1=0,sk2=0,sk3=0, ssk0=0,ssk1=0,ssk2=0,ssk3=0;
    float sq0=0,sq1=0,sq2=0,sq3=0, ssq0=0,ssq1=0,ssq2=0,ssq3=0;
    #pragma unroll
    for(int m=0;m<8;m++){
      float4 ck = *(const float4*)(cc + (b*16+m  )*16 + j0);
      float4 cq = *(const float4*)(cc + (b*16+m+8)*16 + j0);
      aM0[m]=ck.x*cq.x; aM1[m]=ck.y*cq.y; aM2[m]=ck.z*cq.z; aM3[m]=ck.w*cq.w;
      float svk = Sv [(b*16+m)*256+t];
      float ssvk= SSv[(b*16+m)*256+t];
      float svq = Sv [(b*16+m+8)*256+t];
      float ssvq= SSv[(b*16+m+8)*256+t];
      sk0 += ck.x*svk; ssk0 += ck.x*ck.x*ssvk;
      sk1 += ck.y*svk; ssk1 += ck.y*ck.y*ssvk;
      sk2 += ck.z*svk; ssk2 += ck.z*ck.z*ssvk;
      sk3 += ck.w*svk; ssk3 += ck.w*ck.w*ssvk;
      sq0 += cq.x*svq; ssq0 += cq.x*cq.x*ssvq;
      sq1 += cq.y*svq; ssq1 += cq.y*cq.y*ssvq;
      sq2 += cq.z*svq; ssq2 += cq.z*cq.z*ssvq;
      sq3 += cq.w*svq; ssq3 += cq.w*cq.w*ssvq;
    }
    float mq;
    mq = sq0*(1.f/512.f); mQL[0*256+t]=mq; rQL[0*256+t]=rsqrtf(ssq0*(1.f/512.f)-mq*mq+EPSLN);
    mq = sq1*(1.f/512.f); mQL[1*256+t]=mq; rQL[1*256+t]=rsqrtf(ssq1*(1.f/512.f)-mq*mq+EPSLN);
    mq = sq2*(1.f/512.f); mQL[2*256+t]=mq; rQL[2*256+t]=rsqrtf(ssq2*(1.f/512.f)-mq*mq+EPSLN);
    mq = sq3*(1.f/512.f); mQL[3*256+t]=mq; rQL[3*256+t]=rsqrtf(ssq3*(1.f/512.f)-mq*mq+EPSLN);
    if((t>>4)==st){
      int si = t&15;
      float mk;
      mk = sk0*(1.f/512.f); mKL[0*16+si]=mk; rKL[0*16+si]=rsqrtf(ssk0*(1.f/512.f)-mk*mk+EPSLN);
      mk = sk1*(1.f/512.f); mKL[1*16+si]=mk; rKL[1*16+si]=rsqrtf(ssk1*(1.f/512.f)-mk*mk+EPSLN);
      mk = sk2*(1.f/512.f); mKL[2*16+si]=mk; rKL[2*16+si]=rsqrtf(ssk2*(1.f/512.f)-mk*mk+EPSLN);
      mk = sk3*(1.f/512.f); mKL[3*16+si]=mk; rKL[3*16+si]=rsqrtf(ssk3*(1.f/512.f)-mk*mk+EPSLN);
    }
  }
  __syncthreads();
  const float* Gb = G + (size_t)(b*8)*65536;
  float4 mQ4a = *(const float4*)&mQL[0*256+lane*4];
  float4 rQ4a = *(const float4*)&rQL[0*256+lane*4];
  float4 mQ4b = *(const float4*)&mQL[1*256+lane*4];
  float4 rQ4b = *(const float4*)&rQL[1*256+lane*4];
  float4 mQ4c = *(const float4*)&mQL[2*256+lane*4];
  float4 rQ4c = *(const float4*)&rQL[2*256+lane*4];
  float4 mQ4d = *(const float4*)&mQL[3*256+lane*4];
  float4 rQ4d = *(const float4*)&rQL[3*256+lane*4];
  ushort4 pk2[4], pk3[4];   // j2/j3 probs held in registers
  #pragma unroll
  for(int q=0;q<4;q++){
    int si = w*4+q;
    int s = st*16 + si;
    f32x4 dt0={0.f,0.f,0.f,0.f}, dt1={0.f,0.f,0.f,0.f};
    f32x4 dt2={0.f,0.f,0.f,0.f}, dt3={0.f,0.f,0.f,0.f};
    #pragma unroll
    for(int m=0;m<8;m++){
      f32x4 g4 = *(const f32x4*)(Gb + (size_t)m*65536 + s*256 + lane*4);
      dt0 += aM0[m]*g4; dt1 += aM1[m]*g4;
      dt2 += aM2[m]*g4; dt3 += aM3[m]*g4;
    }
    // defer-max: LN'd rows => |raw| <= sqrt(512)/tv ~ 22.6, exp safe without max-sub
    #define SMK(JJ, DT, MQ, RQ, PKOUT) { \
      float mKs = 512.f*mKL[JJ*16+si], rKs = rKL[JJ*16+si]; \
      float e0 = __expf((DT[0] - mKs*MQ.x)*rKs*RQ.x*inv); \
      float e1 = __expf((DT[1] - mKs*MQ.y)*rKs*RQ.y*inv); \
      float e2 = __expf((DT[2] - mKs*MQ.z)*rKs*RQ.z*inv); \
      float e3 = __expf((DT[3] - mKs*MQ.w)*rKs*RQ.w*inv); \
      float isf = 1.f/wsum(e0+e1+e2+e3); \
      u16 pk[4] = {f2bf(e0*isf), f2bf(e1*isf), f2bf(e2*isf), f2bf(e3*isf)}; \
      PKOUT = *(ushort4*)pk; }
    ushort4 t0v, t1v;
    SMK(0, dt0, mQ4a, rQ4a, t0v)
    SMK(1, dt1, mQ4b, rQ4b, t1v)
    int poff = (si*512 + lane*8) ^ ((si&7)<<4);
    *(ushort4*)(prA + poff) = t0v;
    *(ushort4*)(prB + poff) = t1v;
    SMK(2, dt2, mQ4c, rQ4c, pk2[q])
    SMK(3, dt3, mQ4d, rQ4d, pk3[q])
    #undef SMK
  }
  __syncthreads();
  int m_ = lane&15, kb = lane>>4;
  f32x4 av0={0.f,0.f,0.f,0.f}, av1={0.f,0.f,0.f,0.f};
  f32x4 av2={0.f,0.f,0.f,0.f}, av3={0.f,0.f,0.f,0.f};
  const u16* xpB0 = xpB + (size_t)(b*16+j0  )*16384;
  const u16* xpB1 = xpB + (size_t)(b*16+j0+1)*16384;
  const u16* xpB2 = xpB + (size_t)(b*16+j0+2)*16384;
  const u16* xpB3 = xpB + (size_t)(b*16+j0+3)*16384;
  #pragma unroll
  for(int ks=0;ks<8;ks++){
    int aoff = (m_*512 + ks*64 + kb*16) ^ ((m_&7)<<4);
    int boff = ((ks*4 + w)*64 + lane)*8;
    bf16x8 a0 = *(const bf16x8*)(prA + aoff);
    bf16x8 a1 = *(const bf16x8*)(prB + aoff);
    av0 = __builtin_amdgcn_mfma_f32_16x16x32_bf16(a0, *(const bf16x8*)(xpB0 + boff), av0, 0,0,0);
    av1 = __builtin_amdgcn_mfma_f32_16x16x32_bf16(a1, *(const bf16x8*)(xpB1 + boff), av1, 0,0,0);
  }
  __syncthreads();   // AV(j0,j1) prob reads done -> panels reusable
  #pragma unroll
  for(int q=0;q<4;q++){
    int si = w*4+q;
    int poff = (si*512 + lane*8) ^ ((si&7)<<4);
    *(ushort4*)(prA + poff) = pk2[q];
    *(ushort4*)(prB + poff) = pk3[q];
  }
  __syncthreads();
  #pragma unroll
  for(int ks=0;ks<8;ks++){
    int aoff = (m_*512 + ks*64 + kb*16) ^ ((m_&7)<<4);
    int boff = ((ks*4 + w)*64 + lane)*8;
    bf16x8 a2 = *(const bf16x8*)(prA + aoff);
    bf16x8 a3 = *(const bf16x8*)(prB + aoff);
    av2 = __builtin_amdgcn_mfma_f32_16x16x32_bf16(a2, *(const bf16x8*)(xpB2 + boff), av2, 0,0,0);
    av3 = __builtin_amdgcn_mfma_f32_16x16x32_bf16(a3, *(const bf16x8*)(xpB3 + boff), av3, 0,0,0);
  }
  int f = w*16 + m_;
  #pragma unroll
  for(int pass=0; pass<2; pass++){
    __syncthreads();   // previous ovl readers done (probs or pass-0 xpT)
    for(int idx4 = tid; idx4 < 1536; idx4 += 256){
      int jj = idx4 / 768;
      int rem = idx4 - jj*768;
      int rr_i = rem >> 8;
      int pos = rem & 255;
      int ci = pos>>4, f4 = pos&15;
      int grow = st - 1 + rr_i;
      float4 v = {0.f,0.f,0.f,0.f};
      if(grow>=0 && grow<16){
        v = *(const float4*)(xp + ((size_t)(b*16+j0+pass*2+jj)*256 + grow*16 + ci)*64 + f4*4);
      }
      *(float4*)(xpT + ((jj*3+rr_i)*16+ci)*68 + f4*4) = v;
    }
    __syncthreads();
    #pragma unroll
    for(int jj=0;jj<2;jj++){
      int j = j0 + pass*2 + jj;
      int bj = b*16+j;
      f32x4 acc = pass==0 ? (jj?av1:av0) : (jj?av3:av2);
      float al = fabsf(alpha[j]), be=fabsf(beta[j]), th=fabsf(theta[j]), ga=gamma_[j];
      const float* wq = cw + (j*64+f)*9;
      float w0=wq[0],w1=wq[1],w2=wq[2],w3v=wq[3],w4=wq[4],w5=wq[5],w6=wq[6],w7=wq[7],w8=wq[8];
      #pragma unroll
      for(int r=0;r<4;r++){
        int si = kb*4 + r;
        int s = st*16 + si;
        float gl = acc[r];
        float cv=0.f;
        #pragma unroll
        for(int dr=0;dr<3;dr++){
          float kw0 = dr==0?w0:(dr==1?w3v:w6);
          float kw1 = dr==0?w1:(dr==1?w4:w7);
          float kw2 = dr==0?w2:(dr==1?w5:w8);
          const float* rowp = xpT + ((jj*3+dr)*16)*68;
          if(si>0)  cv += rowp[(si-1)*68+f]*kw0;
                    cv += rowp[(si  )*68+f]*kw1;
          if(si<15) cv += rowp[(si+1)*68+f]*kw2;
        }
        float diag = xpT[((jj*3+1)*16+si)*68+f];
        size_t gi = ((size_t)bj*256+s)*64+f;
        out[gi] = be*gl + al*diag + th*cv + ga*bf2f(xarrb[gi]);
      }
    }
  }
}

extern "C" void kernel_launch(void* const* d_in, const int* in_sizes, int n_in,
                              void* d_out, int out_size, void* d_ws, size_t ws_size,
                              hipStream_t stream) {
  const float* xin = (const float*)d_in[0];
  const float* pxp = (const float*)d_in[1];
  const float* sw  = (const float*)d_in[2];
  const float* bs  = (const float*)d_in[3];
  const float* tau = (const float*)d_in[4];
  const float* temp= (const float*)d_in[5];
  const float* om  = (const float*)d_in[6];
  const float* W2  = (const float*)d_in[7];
  const float* bp  = (const float*)d_in[8];
  const float* lnw = (const float*)d_in[9];
  const float* lnb = (const float*)d_in[10];
  const float* alpha=(const float*)d_in[11];
  const float* beta= (const float*)d_in[12];
  const float* gam = (const float*)d_in[13];
  const float* theta=(const float*)d_in[14];
  const float* cw  = (const float*)d_in[15];
  float* outp = (float*)d_out;
  float* xpo  = outp + 2097152;   // x_prime = second output

  float* ws  = (float*)d_ws;
  float* xe  = ws;                // 32768
  float* xa  = xe + 32768;        // 32768
  float* Sv  = xa + 32768;        // 32768
  float* SSv = Sv + 32768;        // 32768
  u16*   er2b= (u16*)(SSv + 32768);   // 524288 u16 (bf16 er2; slot reserves 2MB)
  float* mask= (float*)(er2b) + 524288;  // keep offsets stable (er2 slot = 524288 f32)
  float* ccv = mask + 2048;       // 2048
  float* Gv  = ccv + 2048;        // 4194304
  u16* xvb = (u16*)(Gv + 4194304);    // 2097152 u16 (bf16 x)
  u16* xpB = xvb + 2097152;           // 2097152 u16
  u16* w2B = xpB + 2097152;           // 65536 u16
  u16* xinb= w2B + 65536;             // 2097152 u16
  u16* phi = xinb + 2097152;          // 2097152 u16
  u16* plo = phi + 2097152;           // 2097152 u16

  kA<<<1024,256,0,stream>>>(xin,pxp,W2,xe,xa,Sv,SSv,xinb,phi,plo,w2B);
  kBE<<<1152,256,0,stream>>>(xe,sw,bs,om,xa,tau,temp,er2b,mask,ccv,phi,plo,Gv);
  kD<<<dim3(8,16,16),256,0,stream>>>(xinb,er2b,mask,w2B,lnw,lnb,bp,xvb,xpo,xpB);
  kF<<<dim3(8,4,16),256,0,stream>>>(Gv,ccv,Sv,SSv,xpo,xpB,cw,xvb,temp,
                                    alpha,beta,gam,theta,outp);
}

// Round 17
// 54.611 us; speedup vs baseline: 1.3319x; 1.0118x over previous
//
#include <hip/hip_runtime.h>

#define EPSLN 1e-5f

typedef short bf16x8 __attribute__((ext_vector_type(8)));
typedef float f32x4 __attribute__((ext_vector_type(4)));
typedef unsigned short u16;
typedef unsigned short u16x8 __attribute__((ext_vector_type(8)));

__device__ __forceinline__ float wsum(float v){
  #pragma unroll
  for(int o=32;o;o>>=1) v += __shfl_xor(v,o);
  return v;
}
__device__ __forceinline__ float wmax(float v){
  #pragma unroll
  for(int o=32;o;o>>=1) v = fmaxf(v,__shfl_xor(v,o));
  return v;
}
__device__ __forceinline__ u16 f2bf(float f){
  unsigned int u = __float_as_uint(f);
  u = (u + 0x7FFFu + ((u>>16)&1u)) >> 16;
  return (u16)u;
}
__device__ __forceinline__ float bf2f(u16 h){
  return __uint_as_float(((unsigned int)h)<<16);
}

// A: eighth-row per thread. Blocks 0..15 also pack W2 into bf16 B-frag order.
__global__ void __launch_bounds__(256) kA(
                   const float* __restrict__ xin, const float* __restrict__ p,
                   const float* __restrict__ W2,
                   float* __restrict__ xe, float* __restrict__ xa,
                   float* __restrict__ Sv, float* __restrict__ SSv,
                   u16* __restrict__ xinb, u16* __restrict__ phi, u16* __restrict__ plo,
                   u16* __restrict__ w2B){
  int t = threadIdx.x;
  int rl = t>>3, q = t&7;
  int row = blockIdx.x*32 + rl;
  const float4* xr = (const float4*)(xin + row*64 + q*8);
  const float4* pr = (const float4*)(p   + row*64 + q*8);
  float s1=0.f,s2=0.f,s3=0.f,s4=0.f;
  u16x8 xb, ph, pl;
  #pragma unroll
  for(int k=0;k<2;k++){
    float4 xv = xr[k];
    float4 pv = pr[k];
    s1 += xv.x+xv.y+xv.z+xv.w;
    s2 += fabsf(xv.x)+fabsf(xv.y)+fabsf(xv.z)+fabsf(xv.w);
    s3 += pv.x+pv.y+pv.z+pv.w;
    s4 += pv.x*pv.x+pv.y*pv.y+pv.z*pv.z+pv.w*pv.w;
    int o = k*4;
    xb[o+0]=f2bf(xv.x); xb[o+1]=f2bf(xv.y); xb[o+2]=f2bf(xv.z); xb[o+3]=f2bf(xv.w);
    u16 h0=f2bf(pv.x), h1=f2bf(pv.y), h2=f2bf(pv.z), h3=f2bf(pv.w);
    ph[o+0]=h0; ph[o+1]=h1; ph[o+2]=h2; ph[o+3]=h3;
    pl[o+0]=f2bf(pv.x-bf2f(h0)); pl[o+1]=f2bf(pv.y-bf2f(h1));
    pl[o+2]=f2bf(pv.z-bf2f(h2)); pl[o+3]=f2bf(pv.w-bf2f(h3));
  }
  *(u16x8*)(xinb + row*64 + q*8) = xb;
  *(u16x8*)(phi  + row*64 + q*8) = ph;
  *(u16x8*)(plo  + row*64 + q*8) = pl;
  s1 += __shfl_xor(s1,1); s1 += __shfl_xor(s1,2); s1 += __shfl_xor(s1,4);
  s2 += __shfl_xor(s2,1); s2 += __shfl_xor(s2,2); s2 += __shfl_xor(s2,4);
  s3 += __shfl_xor(s3,1); s3 += __shfl_xor(s3,2); s3 += __shfl_xor(s3,4);
  s4 += __shfl_xor(s4,1); s4 += __shfl_xor(s4,2); s4 += __shfl_xor(s4,4);
  if(q==0){ xe[row]=s1*(1.f/64.f); xa[row]=s2*(1.f/64.f); Sv[row]=s3; SSv[row]=s4; }
  if(blockIdx.x<16){
    int j = blockIdx.x;
    for(int idx=threadIdx.x; idx<4096; idx+=256){
      int f = idx>>6, o = idx&63;
      float v = W2[j*4096 + idx];
      int ks = f>>5, kb = (f>>3)&3, i = f&7;
      int nt = o>>4, col = o&15;
      int ln = kb*16 + col;
      w2B[((j*2+ks)*4 + nt)*512 + ln*8 + i] = f2bf(v);
    }
  }
}

// BE: fused kB (blocks 0..127, er2 out in bf16) + kE2 gram MFMA (blocks 128..1151).
__global__ void __launch_bounds__(256) kBE(
                   const float* __restrict__ xe, const float* __restrict__ sw,
                   const float* __restrict__ bs, const float* __restrict__ om,
                   const float* __restrict__ xa, const float* __restrict__ tau,
                   const float* __restrict__ temp,
                   u16* __restrict__ er2b, float* __restrict__ mask,
                   float* __restrict__ cc,
                   const u16* __restrict__ phi, const u16* __restrict__ plo,
                   float* __restrict__ G){
  __shared__ __align__(16) unsigned char shm[32768];
  int tid = threadIdx.x;
  if(blockIdx.x < 128){
    // ---- kB body ----
    float* swL = (float*)shm;
    float* bsL = swL + 1072;
    float* omL = bsL + 16;
    float* red = omL + 16;
    float* redE= red + 4;              // [16][4]
    int bi = blockIdx.x;
    int i = bi & 15;
    int w = tid>>6, lane = tid&63;
    for(int k=tid;k<16*67;k+=256) swL[k] = sw[i*16*67 + k];
    if(tid<16){ bsL[tid]=bs[i*16+tid]; omL[tid]=fabsf(om[i*16+tid]); }
    float v = xe[bi*256+tid];
    float m = wmax(fabsf(v));
    if(lane==0) red[w]=m;
    __syncthreads();
    m = fmaxf(fmaxf(red[0],red[1]),fmaxf(red[2],red[3]));
    float xn = v/(m+1e-8f);
    xn = fminf(fmaxf(xn,-0.99f),0.99f);
    float sil = xn/(1.f+expf(-xn));
    float vv = (xn+1.f)*33.f;
    int c0 = (int)floorf(vv)-1;
    float acc[16];
    #pragma unroll
    for(int j=0;j<16;j++) acc[j]=0.f;
    #pragma unroll
    for(int k=0;k<4;k++){
      int c = c0+k;
      if(c<0||c>66) continue;
      float d = fabsf(vv-(float)c);
      float bas = d<1.f ? (2.f/3.f - d*d + d*d*d*0.5f)
                : (d<2.f ? (2.f-d)*(2.f-d)*(2.f-d)*(1.f/6.f) : 0.f);
      #pragma unroll
      for(int j=0;j<16;j++) acc[j] += bas*swL[j*67+c];
    }
    float xav = xa[bi*256+tid];
    #pragma unroll
    for(int j=0;j<16;j++){
      float ev = sil*bsL[j] + acc[j] + omL[j];
      er2b[(bi*16+j)*256+tid] = f2bf(ev);
      float pe = wsum(fabsf(ev)*xav);
      if(lane==0) redE[j*4+w]=pe;
    }
    __syncthreads();
    if(tid<16){
      float e = (redE[tid*4+0]+redE[tid*4+1]+redE[tid*4+2]+redE[tid*4+3])*(1.f/256.f);
      float tv = fabsf(temp[0])+1e-4f;
      float ta = fabsf(tau[i*16+tid]);
      float mk = 1.f/(1.f+expf(-(e-ta)/tv));
      mask[bi*16+tid]=mk;
      cc[bi*16+tid]= e/(ta+1e-8f)*mk;
    }
  } else {
    // ---- kE2 body ----
    u16* AfB = (u16*)shm;
    u16* BfB = AfB + 8192;
    int e = blockIdx.x - 128;
    int b = e&7, m = (e>>3)&7, sx = (e>>6)&3, ty = e>>8;  // b lowest -> XCD=b
    int bm = b*8+m;
    int s0 = sx*64, t0 = ty*64;
    int row = tid>>2, dseg = tid&3;
    size_t offA = ((size_t)(b*16+m  )*256 + s0 + row)*64 + dseg*16;
    size_t offB = ((size_t)(b*16+m+8)*256 + t0 + row)*64 + dseg*16;
    int d0 = dseg*16;
    int ks0 = d0>>5, kb0 = (d0>>3)&3;
    int ks1 = (d0+8)>>5, kb1 = ((d0+8)>>3)&3;
    int lr = row&15, stile = row>>4;
    #define AOFF(h,stl,ks,ln) (((((h)*4+(stl))*2+(ks))*64 + (ln))*8)
    {
      uint4 v0 = *(const uint4*)(phi + offA);
      uint4 v1 = *(const uint4*)(phi + offA + 8);
      *(uint4*)(AfB + AOFF(0,stile,ks0,kb0*16+lr)) = v0;
      *(uint4*)(AfB + AOFF(0,stile,ks1,kb1*16+lr)) = v1;
      uint4 w0 = *(const uint4*)(plo + offA);
      uint4 w1 = *(const uint4*)(plo + offA + 8);
      *(uint4*)(AfB + AOFF(1,stile,ks0,kb0*16+lr)) = w0;
      *(uint4*)(AfB + AOFF(1,stile,ks1,kb1*16+lr)) = w1;
      uint4 x0 = *(const uint4*)(phi + offB);
      uint4 x1 = *(const uint4*)(phi + offB + 8);
      *(uint4*)(BfB + AOFF(0,stile,ks0,kb0*16+lr)) = x0;
      *(uint4*)(BfB + AOFF(0,stile,ks1,kb1*16+lr)) = x1;
      uint4 y0 = *(const uint4*)(plo + offB);
      uint4 y1 = *(const uint4*)(plo + offB + 8);
      *(uint4*)(BfB + AOFF(1,stile,ks0,kb0*16+lr)) = y0;
      *(uint4*)(BfB + AOFF(1,stile,ks1,kb1*16+lr)) = y1;
    }
    __syncthreads();
    int w = tid>>6, lane = tid&63;
    bf16x8 ah0 = *(const bf16x8*)(AfB + AOFF(0,w,0,lane));
    bf16x8 ah1 = *(const bf16x8*)(AfB + AOFF(0,w,1,lane));
    bf16x8 al0 = *(const bf16x8*)(AfB + AOFF(1,w,0,lane));
    bf16x8 al1 = *(const bf16x8*)(AfB + AOFF(1,w,1,lane));
    f32x4 acc[4];
    #pragma unroll
    for(int tt=0;tt<4;tt++) acc[tt] = (f32x4){0.f,0.f,0.f,0.f};
    #pragma unroll
    for(int tt=0;tt<4;tt++){
      bf16x8 bh0 = *(const bf16x8*)(BfB + AOFF(0,tt,0,lane));
      bf16x8 bh1 = *(const bf16x8*)(BfB + AOFF(0,tt,1,lane));
      bf16x8 bl0 = *(const bf16x8*)(BfB + AOFF(1,tt,0,lane));
      bf16x8 bl1 = *(const bf16x8*)(BfB + AOFF(1,tt,1,lane));
      acc[tt] = __builtin_amdgcn_mfma_f32_16x16x32_bf16(ah0, bh0, acc[tt], 0,0,0);
      acc[tt] = __builtin_amdgcn_mfma_f32_16x16x32_bf16(ah1, bh1, acc[tt], 0,0,0);
      acc[tt] = __builtin_amdgcn_mfma_f32_16x16x32_bf16(ah0, bl0, acc[tt], 0,0,0);
      acc[tt] = __builtin_amdgcn_mfma_f32_16x16x32_bf16(ah1, bl1, acc[tt], 0,0,0);
      acc[tt] = __builtin_amdgcn_mfma_f32_16x16x32_bf16(al0, bh0, acc[tt], 0,0,0);
      acc[tt] = __builtin_amdgcn_mfma_f32_16x16x32_bf16(al1, bh1, acc[tt], 0,0,0);
    }
    int col = lane&15, r4 = lane>>4;
    #pragma unroll
    for(int tt=0;tt<4;tt++){
      #pragma unroll
      for(int r=0;r<4;r++){
        G[((size_t)bm*256 + s0 + w*16 + r4*4 + r)*256 + t0 + tt*16 + col] = acc[tt][r];
      }
    }
    #undef AOFF
  }
}

// D v3: flattened grid 2176 = 2048 main blocks + 128 LN-stats blocks (old kE1).
__global__ void __launch_bounds__(256) kD(
                   const u16* __restrict__ xinb, const u16* __restrict__ er2b,
                   const float* __restrict__ mask, const u16* __restrict__ w2B,
                   const float* __restrict__ lnw, const float* __restrict__ lnb,
                   const float* __restrict__ bp,
                   u16* __restrict__ xoutb, float* __restrict__ xp,
                   u16* __restrict__ xpB,
                   const float* __restrict__ Sv, const float* __restrict__ SSv,
                   const float* __restrict__ cc,
                   float* __restrict__ mKv, float* __restrict__ rKv,
                   float* __restrict__ mQv, float* __restrict__ rQv){
  int bid = blockIdx.x;
  int tid = threadIdx.x;
  if(bid >= 2048){
    // ---- LN stats for (b,j): closed form from Sv/SSv (old kE1) ----
    int sid = bid - 2048;
    int b = sid&7, j = sid>>3;
    int t = tid;
    float sk=0,ssk=0,sq=0,ssq=0;
    #pragma unroll
    for(int m=0;m<8;m++){
      float ck = cc[(b*16+m)*16+j];
      float cq = cc[(b*16+m+8)*16+j];
      sk  += ck*Sv[(b*16+m)*256+t];
      ssk += ck*ck*SSv[(b*16+m)*256+t];
      sq  += cq*Sv[(b*16+m+8)*256+t];
      ssq += cq*cq*SSv[(b*16+m+8)*256+t];
    }
    float mk = sk*(1.f/512.f);
    float vk = ssk*(1.f/512.f) - mk*mk;
    float mq = sq*(1.f/512.f);
    float vq = ssq*(1.f/512.f) - mq*mq;
    int o = (b*16+j)*256+t;
    mKv[o]=mk; rKv[o]=rsqrtf(vk+EPSLN);
    mQv[o]=mq; rQv[o]=rsqrtf(vq+EPSLN);
    return;
  }
  int b = bid&7, j = (bid>>3)&15, st = bid>>7;   // XCD = b
  int w = tid>>6, lane = tid&63;
  __shared__ __align__(16) u16 xnS[16*64];  // bf16, XOR-swizzled
  __shared__ float mcL[16];
  if(tid<16) mcL[tid]=mask[(b*16+tid)*16+j];
  __syncthreads();
  int bj = b*16+j;
  unsigned char* xnB = (unsigned char*)xnS;
  int ss = lane>>4, fq = lane&15;
  int sl = w*4 + ss;
  int s  = st*16 + sl;
  float4 lw4 = *(const float4*)(lnw + j*64 + fq*4);
  float4 lb4 = *(const float4*)(lnb + j*64 + fq*4);
  float acc0=0.f,acc1=0.f,acc2=0.f,acc3=0.f;
  #pragma unroll
  for(int i=0;i<16;i++){
    float er = bf2f(er2b[((b*16+i)*16+j)*256+s])*mcL[i];
    ushort4 xv = *(const ushort4*)(xinb + ((size_t)(b*16+i)*256+s)*64 + fq*4);
    acc0 += er*bf2f(xv.x);
    acc1 += er*bf2f(xv.y);
    acc2 += er*bf2f(xv.z);
    acc3 += er*bf2f(xv.w);
  }
  acc0*=(1.f/16.f); acc1*=(1.f/16.f); acc2*=(1.f/16.f); acc3*=(1.f/16.f);
  {
    u16 pk[4]={f2bf(acc0),f2bf(acc1),f2bf(acc2),f2bf(acc3)};
    *(ushort4*)(xoutb + ((size_t)bj*256+s)*64 + fq*4) = *(ushort4*)pk;
  }
  float part = acc0+acc1+acc2+acc3;
  part += __shfl_xor(part,1); part += __shfl_xor(part,2);
  part += __shfl_xor(part,4); part += __shfl_xor(part,8);
  float mu = part*(1.f/64.f);
  float d0=acc0-mu, d1=acc1-mu, d2=acc2-mu, d3=acc3-mu;
  float p2 = d0*d0+d1*d1+d2*d2+d3*d3;
  p2 += __shfl_xor(p2,1); p2 += __shfl_xor(p2,2);
  p2 += __shfl_xor(p2,4); p2 += __shfl_xor(p2,8);
  float rstd = rsqrtf(p2*(1.f/64.f)+EPSLN);
  {
    u16 xn[4] = { f2bf(d0*rstd*lw4.x + lb4.x), f2bf(d1*rstd*lw4.y + lb4.y),
                  f2bf(d2*rstd*lw4.z + lb4.z), f2bf(d3*rstd*lw4.w + lb4.w) };
    *(ushort4*)(xnB + ((sl*128 + fq*8) ^ ((sl&7)<<4))) = *(ushort4*)xn;
  }
  __syncthreads();
  f32x4 acc = {0.f,0.f,0.f,0.f};
  int m = lane&15, kb = lane>>4;
  #pragma unroll
  for(int ks=0;ks<2;ks++){
    bf16x8 a = *(const bf16x8*)(xnB + ((m*128 + ks*64 + kb*16) ^ ((m&7)<<4)));
    bf16x8 bfr = *(const bf16x8*)(w2B + ((j*2+ks)*4 + w)*512 + lane*8);
    acc = __builtin_amdgcn_mfma_f32_16x16x32_bf16(a, bfr, acc, 0, 0, 0);
  }
  int f = w*16 + m;
  u16 pk[4];
  #pragma unroll
  for(int r=0;r<4;r++){
    int si = kb*4 + r;
    int s2 = st*16 + si;
    float xpr = acc[r] + bp[((size_t)j*256+s2)*64+f];
    xp[((size_t)bj*256+s2)*64+f] = xpr;
    pk[r] = f2bf(xpr);
  }
  int s0 = st*16 + kb*4;
  int flat = ((s0>>5)*4 + w)*512 + ((s0>>3)&3)*128 + m*8 + (s0&7);
  *(ushort4*)(xpB + (size_t)bj*16384 + flat) = *(ushort4*)pk;
}

// F v4: stats precomputed (mKv/rKv/mQv/rQv direct loads) — no prologue, no
//       Sv/SSv re-reads, one less barrier. 4 j per block, 2 prob panels.
//       LDS 25.5KB -> 6 blocks/CU. b in blockIdx.x -> XCD=b.
__global__ void __launch_bounds__(256) kF(
    const float* __restrict__ G, const float* __restrict__ cc,
    const float* __restrict__ mKv, const float* __restrict__ rKv,
    const float* __restrict__ mQv, const float* __restrict__ rQv,
    const float* __restrict__ xp, const u16* __restrict__ xpB,
    const float* __restrict__ cw,
    const u16* __restrict__ xarrb, const float* __restrict__ temp,
    const float* __restrict__ alpha, const float* __restrict__ beta,
    const float* __restrict__ gamma_, const float* __restrict__ theta,
    float* __restrict__ out){
  int b = blockIdx.x, jp = blockIdx.y, st = blockIdx.z;
  int j0 = jp*4;
  int tid = threadIdx.x, w = tid>>6, lane = tid&63;
  __shared__ __align__(16) unsigned char ovl[26112];
  // [0,8192) prob panel A | [8192,16384) prob panel B
  // xpT [2][3][16][68] f32 overlays [0,26112) during epilogue.
  unsigned char* prA = ovl;
  unsigned char* prB = ovl + 8192;
  float* xpT = (float*)ovl;
  float tv = fabsf(temp[0])+1e-4f;
  float inv = 1.f/(sqrtf(512.f)*tv);
  float aM0[8],aM1[8],aM2[8],aM3[8];
  #pragma unroll
  for(int m=0;m<8;m++){
    float4 ck = *(const float4*)(cc + (b*16+m  )*16 + j0);
    float4 cq = *(const float4*)(cc + (b*16+m+8)*16 + j0);
    aM0[m]=ck.x*cq.x; aM1[m]=ck.y*cq.y; aM2[m]=ck.z*cq.z; aM3[m]=ck.w*cq.w;
  }
  int bj0 = b*16+j0;
  float4 mQ4a = *(const float4*)(mQv + (size_t)(bj0  )*256 + lane*4);
  float4 rQ4a = *(const float4*)(rQv + (size_t)(bj0  )*256 + lane*4);
  float4 mQ4b = *(const float4*)(mQv + (size_t)(bj0+1)*256 + lane*4);
  float4 rQ4b = *(const float4*)(rQv + (size_t)(bj0+1)*256 + lane*4);
  float4 mQ4c = *(const float4*)(mQv + (size_t)(bj0+2)*256 + lane*4);
  float4 rQ4c = *(const float4*)(rQv + (size_t)(bj0+2)*256 + lane*4);
  float4 mQ4d = *(const float4*)(mQv + (size_t)(bj0+3)*256 + lane*4);
  float4 rQ4d = *(const float4*)(rQv + (size_t)(bj0+3)*256 + lane*4);
  const float* Gb = G + (size_t)(b*8)*65536;
  ushort4 pk2[4], pk3[4];   // j2/j3 probs held in registers
  #pragma unroll
  for(int q=0;q<4;q++){
    int si = w*4+q;
    int s = st*16 + si;
    f32x4 dt0={0.f,0.f,0.f,0.f}, dt1={0.f,0.f,0.f,0.f};
    f32x4 dt2={0.f,0.f,0.f,0.f}, dt3={0.f,0.f,0.f,0.f};
    #pragma unroll
    for(int m=0;m<8;m++){
      f32x4 g4 = *(const f32x4*)(Gb + (size_t)m*65536 + s*256 + lane*4);
      dt0 += aM0[m]*g4; dt1 += aM1[m]*g4;
      dt2 += aM2[m]*g4; dt3 += aM3[m]*g4;
    }
    // defer-max: LN'd rows => |raw| <= sqrt(512)/tv ~ 22.6, exp safe without max-sub
    #define SMK(JJ, DT, MQ, RQ, PKOUT) { \
      float mKs = 512.f*mKv[(size_t)(bj0+JJ)*256 + s], rKs = rKv[(size_t)(bj0+JJ)*256 + s]; \
      float e0 = __expf((DT[0] - mKs*MQ.x)*rKs*RQ.x*inv); \
      float e1 = __expf((DT[1] - mKs*MQ.y)*rKs*RQ.y*inv); \
      float e2 = __expf((DT[2] - mKs*MQ.z)*rKs*RQ.z*inv); \
      float e3 = __expf((DT[3] - mKs*MQ.w)*rKs*RQ.w*inv); \
      float isf = 1.f/wsum(e0+e1+e2+e3); \
      u16 pk[4] = {f2bf(e0*isf), f2bf(e1*isf), f2bf(e2*isf), f2bf(e3*isf)}; \
      PKOUT = *(ushort4*)pk; }
    ushort4 t0v, t1v;
    SMK(0, dt0, mQ4a, rQ4a, t0v)
    SMK(1, dt1, mQ4b, rQ4b, t1v)
    int poff = (si*512 + lane*8) ^ ((si&7)<<4);
    *(ushort4*)(prA + poff) = t0v;
    *(ushort4*)(prB + poff) = t1v;
    SMK(2, dt2, mQ4c, rQ4c, pk2[q])
    SMK(3, dt3, mQ4d, rQ4d, pk3[q])
    #undef SMK
  }
  __syncthreads();
  int m_ = lane&15, kb = lane>>4;
  f32x4 av0={0.f,0.f,0.f,0.f}, av1={0.f,0.f,0.f,0.f};
  f32x4 av2={0.f,0.f,0.f,0.f}, av3={0.f,0.f,0.f,0.f};
  const u16* xpB0 = xpB + (size_t)(bj0  )*16384;
  const u16* xpB1 = xpB + (size_t)(bj0+1)*16384;
  const u16* xpB2 = xpB + (size_t)(bj0+2)*16384;
  const u16* xpB3 = xpB + (size_t)(bj0+3)*16384;
  #pragma unroll
  for(int ks=0;ks<8;ks++){
    int aoff = (m_*512 + ks*64 + kb*16) ^ ((m_&7)<<4);
    int boff = ((ks*4 + w)*64 + lane)*8;
    bf16x8 a0 = *(const bf16x8*)(prA + aoff);
    bf16x8 a1 = *(const bf16x8*)(prB + aoff);
    av0 = __builtin_amdgcn_mfma_f32_16x16x32_bf16(a0, *(const bf16x8*)(xpB0 + boff), av0, 0,0,0);
    av1 = __builtin_amdgcn_mfma_f32_16x16x32_bf16(a1, *(const bf16x8*)(xpB1 + boff), av1, 0,0,0);
  }
  __syncthreads();   // AV(j0,j1) prob reads done -> panels reusable
  #pragma unroll
  for(int q=0;q<4;q++){
    int si = w*4+q;
    int poff = (si*512 + lane*8) ^ ((si&7)<<4);
    *(ushort4*)(prA + poff) = pk2[q];
    *(ushort4*)(prB + poff) = pk3[q];
  }
  __syncthreads();
  #pragma unroll
  for(int ks=0;ks<8;ks++){
    int aoff = (m_*512 + ks*64 + kb*16) ^ ((m_&7)<<4);
    int boff = ((ks*4 + w)*64 + lane)*8;
    bf16x8 a2 = *(const bf16x8*)(prA + aoff);
    bf16x8 a3 = *(const bf16x8*)(prB + aoff);
    av2 = __builtin_amdgcn_mfma_f32_16x16x32_bf16(a2, *(const bf16x8*)(xpB2 + boff), av2, 0,0,0);
    av3 = __builtin_amdgcn_mfma_f32_16x16x32_bf16(a3, *(const bf16x8*)(xpB3 + boff), av3, 0,0,0);
  }
  int f = w*16 + m_;
  #pragma unroll
  for(int pass=0; pass<2; pass++){
    __syncthreads();   // previous ovl readers done (probs or pass-0 xpT)
    for(int idx4 = tid; idx4 < 1536; idx4 += 256){
      int jj = idx4 / 768;
      int rem = idx4 - jj*768;
      int rr_i = rem >> 8;
      int pos = rem & 255;
      int ci = pos>>4, f4 = pos&15;
      int grow = st - 1 + rr_i;
      float4 v = {0.f,0.f,0.f,0.f};
      if(grow>=0 && grow<16){
        v = *(const float4*)(xp + ((size_t)(b*16+j0+pass*2+jj)*256 + grow*16 + ci)*64 + f4*4);
      }
      *(float4*)(xpT + ((jj*3+rr_i)*16+ci)*68 + f4*4) = v;
    }
    __syncthreads();
    #pragma unroll
    for(int jj=0;jj<2;jj++){
      int j = j0 + pass*2 + jj;
      int bj = b*16+j;
      f32x4 acc = pass==0 ? (jj?av1:av0) : (jj?av3:av2);
      float al = fabsf(alpha[j]), be=fabsf(beta[j]), th=fabsf(theta[j]), ga=gamma_[j];
      const float* wq = cw + (j*64+f)*9;
      float w0=wq[0],w1=wq[1],w2=wq[2],w3v=wq[3],w4=wq[4],w5=wq[5],w6=wq[6],w7=wq[7],w8=wq[8];
      #pragma unroll
      for(int r=0;r<4;r++){
        int si = kb*4 + r;
        int s = st*16 + si;
        float gl = acc[r];
        float cv=0.f;
        #pragma unroll
        for(int dr=0;dr<3;dr++){
          float kw0 = dr==0?w0:(dr==1?w3v:w6);
          float kw1 = dr==0?w1:(dr==1?w4:w7);
          float kw2 = dr==0?w2:(dr==1?w5:w8);
          const float* rowp = xpT + ((jj*3+dr)*16)*68;
          if(si>0)  cv += rowp[(si-1)*68+f]*kw0;
                    cv += rowp[(si  )*68+f]*kw1;
          if(si<15) cv += rowp[(si+1)*68+f]*kw2;
        }
        float diag = xpT[((jj*3+1)*16+si)*68+f];
        size_t gi = ((size_t)bj*256+s)*64+f;
        out[gi] = be*gl + al*diag + th*cv + ga*bf2f(xarrb[gi]);
      }
    }
  }
}

extern "C" void kernel_launch(void* const* d_in, const int* in_sizes, int n_in,
                              void* d_out, int out_size, void* d_ws, size_t ws_size,
                              hipStream_t stream) {
  const float* xin = (const float*)d_in[0];
  const float* pxp = (const float*)d_in[1];
  const float* sw  = (const float*)d_in[2];
  const float* bs  = (const float*)d_in[3];
  const float* tau = (const float*)d_in[4];
  const float* temp= (const float*)d_in[5];
  const float* om  = (const float*)d_in[6];
  const float* W2  = (const float*)d_in[7];
  const float* bp  = (const float*)d_in[8];
  const float* lnw = (const float*)d_in[9];
  const float* lnb = (const float*)d_in[10];
  const float* alpha=(const float*)d_in[11];
  const float* beta= (const float*)d_in[12];
  const float* gam = (const float*)d_in[13];
  const float* theta=(const float*)d_in[14];
  const float* cw  = (const float*)d_in[15];
  float* outp = (float*)d_out;
  float* xpo  = outp + 2097152;   // x_prime = second output

  float* ws  = (float*)d_ws;
  float* xe  = ws;                // 32768
  float* xa  = xe + 32768;        // 32768
  float* Sv  = xa + 32768;        // 32768
  float* SSv = Sv + 32768;        // 32768
  u16*   er2b= (u16*)(SSv + 32768);   // 524288 u16 (slot = 524288 f32 kept)
  float* mask= (float*)(er2b) + 524288;
  float* ccv = mask + 2048;       // 2048
  float* mKv = ccv + 2048;        // 32768
  float* rKv = mKv + 32768;       // 32768
  float* mQv = rKv + 32768;       // 32768
  float* rQv = mQv + 32768;       // 32768
  float* Gv  = rQv + 32768;       // 4194304
  u16* xvb = (u16*)(Gv + 4194304);    // 2097152 u16 (bf16 x)
  u16* xpB = xvb + 2097152;           // 2097152 u16
  u16* w2B = xpB + 2097152;           // 65536 u16
  u16* xinb= w2B + 65536;             // 2097152 u16
  u16* phi = xinb + 2097152;          // 2097152 u16
  u16* plo = phi + 2097152;           // 2097152 u16

  kA<<<1024,256,0,stream>>>(xin,pxp,W2,xe,xa,Sv,SSv,xinb,phi,plo,w2B);
  kBE<<<1152,256,0,stream>>>(xe,sw,bs,om,xa,tau,temp,er2b,mask,ccv,phi,plo,Gv);
  kD<<<2176,256,0,stream>>>(xinb,er2b,mask,w2B,lnw,lnb,bp,xvb,xpo,xpB,
                            Sv,SSv,ccv,mKv,rKv,mQv,rQv);
  kF<<<dim3(8,4,16),256,0,stream>>>(Gv,ccv,mKv,rKv,mQv,rQv,xpo,xpB,cw,xvb,temp,
                                    alpha,beta,gam,theta,outp);
}

// Round 18
// 52.659 us; speedup vs baseline: 1.3812x; 1.0371x over previous
//
#include <hip/hip_runtime.h>

#define EPSLN 1e-5f

typedef short bf16x8 __attribute__((ext_vector_type(8)));
typedef float f32x4 __attribute__((ext_vector_type(4)));
typedef unsigned short u16;
typedef unsigned short u16x8 __attribute__((ext_vector_type(8)));

__device__ __forceinline__ float wsum(float v){
  #pragma unroll
  for(int o=32;o;o>>=1) v += __shfl_xor(v,o);
  return v;
}
__device__ __forceinline__ float wmax(float v){
  #pragma unroll
  for(int o=32;o;o>>=1) v = fmaxf(v,__shfl_xor(v,o));
  return v;
}
__device__ __forceinline__ u16 f2bf(float f){
  unsigned int u = __float_as_uint(f);
  u = (u + 0x7FFFu + ((u>>16)&1u)) >> 16;
  return (u16)u;
}
__device__ __forceinline__ float bf2f(u16 h){
  return __uint_as_float(((unsigned int)h)<<16);
}

// A: eighth-row per thread. Blocks 0..15 also pack W2 into bf16 B-frag order.
__global__ void __launch_bounds__(256) kA(
                   const float* __restrict__ xin, const float* __restrict__ p,
                   const float* __restrict__ W2,
                   float* __restrict__ xe, float* __restrict__ xa,
                   float* __restrict__ Sv, float* __restrict__ SSv,
                   u16* __restrict__ xinb, u16* __restrict__ phi, u16* __restrict__ plo,
                   u16* __restrict__ w2B){
  int t = threadIdx.x;
  int rl = t>>3, q = t&7;
  int row = blockIdx.x*32 + rl;
  const float4* xr = (const float4*)(xin + row*64 + q*8);
  const float4* pr = (const float4*)(p   + row*64 + q*8);
  float s1=0.f,s2=0.f,s3=0.f,s4=0.f;
  u16x8 xb, ph, pl;
  #pragma unroll
  for(int k=0;k<2;k++){
    float4 xv = xr[k];
    float4 pv = pr[k];
    s1 += xv.x+xv.y+xv.z+xv.w;
    s2 += fabsf(xv.x)+fabsf(xv.y)+fabsf(xv.z)+fabsf(xv.w);
    s3 += pv.x+pv.y+pv.z+pv.w;
    s4 += pv.x*pv.x+pv.y*pv.y+pv.z*pv.z+pv.w*pv.w;
    int o = k*4;
    xb[o+0]=f2bf(xv.x); xb[o+1]=f2bf(xv.y); xb[o+2]=f2bf(xv.z); xb[o+3]=f2bf(xv.w);
    u16 h0=f2bf(pv.x), h1=f2bf(pv.y), h2=f2bf(pv.z), h3=f2bf(pv.w);
    ph[o+0]=h0; ph[o+1]=h1; ph[o+2]=h2; ph[o+3]=h3;
    pl[o+0]=f2bf(pv.x-bf2f(h0)); pl[o+1]=f2bf(pv.y-bf2f(h1));
    pl[o+2]=f2bf(pv.z-bf2f(h2)); pl[o+3]=f2bf(pv.w-bf2f(h3));
  }
  *(u16x8*)(xinb + row*64 + q*8) = xb;
  *(u16x8*)(phi  + row*64 + q*8) = ph;
  *(u16x8*)(plo  + row*64 + q*8) = pl;
  s1 += __shfl_xor(s1,1); s1 += __shfl_xor(s1,2); s1 += __shfl_xor(s1,4);
  s2 += __shfl_xor(s2,1); s2 += __shfl_xor(s2,2); s2 += __shfl_xor(s2,4);
  s3 += __shfl_xor(s3,1); s3 += __shfl_xor(s3,2); s3 += __shfl_xor(s3,4);
  s4 += __shfl_xor(s4,1); s4 += __shfl_xor(s4,2); s4 += __shfl_xor(s4,4);
  if(q==0){ xe[row]=s1*(1.f/64.f); xa[row]=s2*(1.f/64.f); Sv[row]=s3; SSv[row]=s4; }
  if(blockIdx.x<16){
    int j = blockIdx.x;
    for(int idx=threadIdx.x; idx<4096; idx+=256){
      int f = idx>>6, o = idx&63;
      float v = W2[j*4096 + idx];
      int ks = f>>5, kb = (f>>3)&3, i = f&7;
      int nt = o>>4, col = o&15;
      int ln = kb*16 + col;
      w2B[((j*2+ks)*4 + nt)*512 + ln*8 + i] = f2bf(v);
    }
  }
}

// BE: fused kB (blocks 0..127, er2 out bf16 in [bi][s][16 j] layout, vector
//     stores) + kE2 gram MFMA (blocks 128..1151). 32KB LDS union.
__global__ void __launch_bounds__(256) kBE(
                   const float* __restrict__ xe, const float* __restrict__ sw,
                   const float* __restrict__ bs, const float* __restrict__ om,
                   const float* __restrict__ xa, const float* __restrict__ tau,
                   const float* __restrict__ temp,
                   u16* __restrict__ er2b, float* __restrict__ mask,
                   float* __restrict__ cc,
                   const u16* __restrict__ phi, const u16* __restrict__ plo,
                   float* __restrict__ G){
  __shared__ __align__(16) unsigned char shm[32768];
  int tid = threadIdx.x;
  if(blockIdx.x < 128){
    // ---- kB body ----
    float* swL = (float*)shm;
    float* bsL = swL + 1072;
    float* omL = bsL + 16;
    float* red = omL + 16;
    float* redE= red + 4;              // [16][4]
    int bi = blockIdx.x;
    int i = bi & 15;
    int w = tid>>6, lane = tid&63;
    for(int k=tid;k<16*67;k+=256) swL[k] = sw[i*16*67 + k];
    if(tid<16){ bsL[tid]=bs[i*16+tid]; omL[tid]=fabsf(om[i*16+tid]); }
    float v = xe[bi*256+tid];
    float m = wmax(fabsf(v));
    if(lane==0) red[w]=m;
    __syncthreads();
    m = fmaxf(fmaxf(red[0],red[1]),fmaxf(red[2],red[3]));
    float xn = v/(m+1e-8f);
    xn = fminf(fmaxf(xn,-0.99f),0.99f);
    float sil = xn/(1.f+expf(-xn));
    float vv = (xn+1.f)*33.f;
    int c0 = (int)floorf(vv)-1;
    float acc[16];
    #pragma unroll
    for(int j=0;j<16;j++) acc[j]=0.f;
    #pragma unroll
    for(int k=0;k<4;k++){
      int c = c0+k;
      if(c<0||c>66) continue;
      float d = fabsf(vv-(float)c);
      float bas = d<1.f ? (2.f/3.f - d*d + d*d*d*0.5f)
                : (d<2.f ? (2.f-d)*(2.f-d)*(2.f-d)*(1.f/6.f) : 0.f);
      #pragma unroll
      for(int j=0;j<16;j++) acc[j] += bas*swL[j*67+c];
    }
    float xav = xa[bi*256+tid];
    u16 evb[16];
    #pragma unroll
    for(int j=0;j<16;j++){
      float ev = sil*bsL[j] + acc[j] + omL[j];
      evb[j] = f2bf(ev);
      float pe = wsum(fabsf(ev)*xav);
      if(lane==0) redE[j*4+w]=pe;
    }
    *(u16x8*)(er2b + ((size_t)bi*256+tid)*16    ) = *(u16x8*)&evb[0];
    *(u16x8*)(er2b + ((size_t)bi*256+tid)*16 + 8) = *(u16x8*)&evb[8];
    __syncthreads();
    if(tid<16){
      float e = (redE[tid*4+0]+redE[tid*4+1]+redE[tid*4+2]+redE[tid*4+3])*(1.f/256.f);
      float tv = fabsf(temp[0])+1e-4f;
      float ta = fabsf(tau[i*16+tid]);
      float mk = 1.f/(1.f+expf(-(e-ta)/tv));
      mask[bi*16+tid]=mk;
      cc[bi*16+tid]= e/(ta+1e-8f)*mk;
    }
  } else {
    // ---- kE2 body ----
    u16* AfB = (u16*)shm;
    u16* BfB = AfB + 8192;
    int e = blockIdx.x - 128;
    int b = e&7, m = (e>>3)&7, sx = (e>>6)&3, ty = e>>8;  // b lowest -> XCD=b
    int bm = b*8+m;
    int s0 = sx*64, t0 = ty*64;
    int row = tid>>2, dseg = tid&3;
    size_t offA = ((size_t)(b*16+m  )*256 + s0 + row)*64 + dseg*16;
    size_t offB = ((size_t)(b*16+m+8)*256 + t0 + row)*64 + dseg*16;
    int d0 = dseg*16;
    int ks0 = d0>>5, kb0 = (d0>>3)&3;
    int ks1 = (d0+8)>>5, kb1 = ((d0+8)>>3)&3;
    int lr = row&15, stile = row>>4;
    #define AOFF(h,stl,ks,ln) (((((h)*4+(stl))*2+(ks))*64 + (ln))*8)
    {
      uint4 v0 = *(const uint4*)(phi + offA);
      uint4 v1 = *(const uint4*)(phi + offA + 8);
      *(uint4*)(AfB + AOFF(0,stile,ks0,kb0*16+lr)) = v0;
      *(uint4*)(AfB + AOFF(0,stile,ks1,kb1*16+lr)) = v1;
      uint4 w0 = *(const uint4*)(plo + offA);
      uint4 w1 = *(const uint4*)(plo + offA + 8);
      *(uint4*)(AfB + AOFF(1,stile,ks0,kb0*16+lr)) = w0;
      *(uint4*)(AfB + AOFF(1,stile,ks1,kb1*16+lr)) = w1;
      uint4 x0 = *(const uint4*)(phi + offB);
      uint4 x1 = *(const uint4*)(phi + offB + 8);
      *(uint4*)(BfB + AOFF(0,stile,ks0,kb0*16+lr)) = x0;
      *(uint4*)(BfB + AOFF(0,stile,ks1,kb1*16+lr)) = x1;
      uint4 y0 = *(const uint4*)(plo + offB);
      uint4 y1 = *(const uint4*)(plo + offB + 8);
      *(uint4*)(BfB + AOFF(1,stile,ks0,kb0*16+lr)) = y0;
      *(uint4*)(BfB + AOFF(1,stile,ks1,kb1*16+lr)) = y1;
    }
    __syncthreads();
    int w = tid>>6, lane = tid&63;
    bf16x8 ah0 = *(const bf16x8*)(AfB + AOFF(0,w,0,lane));
    bf16x8 ah1 = *(const bf16x8*)(AfB + AOFF(0,w,1,lane));
    bf16x8 al0 = *(const bf16x8*)(AfB + AOFF(1,w,0,lane));
    bf16x8 al1 = *(const bf16x8*)(AfB + AOFF(1,w,1,lane));
    f32x4 acc[4];
    #pragma unroll
    for(int tt=0;tt<4;tt++) acc[tt] = (f32x4){0.f,0.f,0.f,0.f};
    #pragma unroll
    for(int tt=0;tt<4;tt++){
      bf16x8 bh0 = *(const bf16x8*)(BfB + AOFF(0,tt,0,lane));
      bf16x8 bh1 = *(const bf16x8*)(BfB + AOFF(0,tt,1,lane));
      bf16x8 bl0 = *(const bf16x8*)(BfB + AOFF(1,tt,0,lane));
      bf16x8 bl1 = *(const bf16x8*)(BfB + AOFF(1,tt,1,lane));
      acc[tt] = __builtin_amdgcn_mfma_f32_16x16x32_bf16(ah0, bh0, acc[tt], 0,0,0);
      acc[tt] = __builtin_amdgcn_mfma_f32_16x16x32_bf16(ah1, bh1, acc[tt], 0,0,0);
      acc[tt] = __builtin_amdgcn_mfma_f32_16x16x32_bf16(ah0, bl0, acc[tt], 0,0,0);
      acc[tt] = __builtin_amdgcn_mfma_f32_16x16x32_bf16(ah1, bl1, acc[tt], 0,0,0);
      acc[tt] = __builtin_amdgcn_mfma_f32_16x16x32_bf16(al0, bh0, acc[tt], 0,0,0);
      acc[tt] = __builtin_amdgcn_mfma_f32_16x16x32_bf16(al1, bh1, acc[tt], 0,0,0);
    }
    int col = lane&15, r4 = lane>>4;
    #pragma unroll
    for(int tt=0;tt<4;tt++){
      #pragma unroll
      for(int r=0;r<4;r++){
        G[((size_t)bm*256 + s0 + w*16 + r4*4 + r)*256 + t0 + tt*16 + col] = acc[tt][r];
      }
    }
    #undef AOFF
  }
}

// D v4: 2 j per block (xinb loads shared) + er2 j-innermost ushort2 loads.
// Flattened grid 1152 = 1024 main + 128 LN-stats blocks.
__global__ void __launch_bounds__(256) kD(
                   const u16* __restrict__ xinb, const u16* __restrict__ er2b,
                   const float* __restrict__ mask, const u16* __restrict__ w2B,
                   const float* __restrict__ lnw, const float* __restrict__ lnb,
                   const float* __restrict__ bp,
                   u16* __restrict__ xoutb, float* __restrict__ xp,
                   u16* __restrict__ xpB,
                   const float* __restrict__ Sv, const float* __restrict__ SSv,
                   const float* __restrict__ cc,
                   float* __restrict__ mKv, float* __restrict__ rKv,
                   float* __restrict__ mQv, float* __restrict__ rQv){
  int bid = blockIdx.x;
  int tid = threadIdx.x;
  if(bid >= 1024){
    // ---- LN stats for (b,j): closed form from Sv/SSv ----
    int sid = bid - 1024;
    int b = sid&7, j = sid>>3;
    int t = tid;
    float sk=0,ssk=0,sq=0,ssq=0;
    #pragma unroll
    for(int m=0;m<8;m++){
      float ck = cc[(b*16+m)*16+j];
      float cq = cc[(b*16+m+8)*16+j];
      sk  += ck*Sv[(b*16+m)*256+t];
      ssk += ck*ck*SSv[(b*16+m)*256+t];
      sq  += cq*Sv[(b*16+m+8)*256+t];
      ssq += cq*cq*SSv[(b*16+m+8)*256+t];
    }
    float mk = sk*(1.f/512.f);
    float vk = ssk*(1.f/512.f) - mk*mk;
    float mq = sq*(1.f/512.f);
    float vq = ssq*(1.f/512.f) - mq*mq;
    int o = (b*16+j)*256+t;
    mKv[o]=mk; rKv[o]=rsqrtf(vk+EPSLN);
    mQv[o]=mq; rQv[o]=rsqrtf(vq+EPSLN);
    return;
  }
  int b = bid&7, jq = (bid>>3)&7, st = bid>>6;   // XCD = b
  int j0 = jq*2;
  int w = tid>>6, lane = tid&63;
  __shared__ __align__(16) u16 xnS[2][16*64];  // bf16, XOR-swizzled, per j
  __shared__ float mcL[32];                    // [i][jj]
  if(tid<32) mcL[tid] = mask[(b*16+(tid>>1))*16 + j0 + (tid&1)];
  __syncthreads();
  int ss = lane>>4, fq = lane&15;
  int sl = w*4 + ss;
  int s  = st*16 + sl;
  float a00=0.f,a01=0.f,a02=0.f,a03=0.f;   // jj=0
  float a10=0.f,a11=0.f,a12=0.f,a13=0.f;   // jj=1
  #pragma unroll
  for(int i=0;i<16;i++){
    unsigned int epk = *(const unsigned int*)(er2b + ((size_t)((b*16+i)*256+s))*16 + j0);
    float e0 = bf2f((u16)(epk&0xFFFFu))*mcL[i*2+0];
    float e1 = bf2f((u16)(epk>>16))   *mcL[i*2+1];
    ushort4 xv = *(const ushort4*)(xinb + ((size_t)(b*16+i)*256+s)*64 + fq*4);
    float x0=bf2f(xv.x), x1=bf2f(xv.y), x2=bf2f(xv.z), x3=bf2f(xv.w);
    a00 += e0*x0; a01 += e0*x1; a02 += e0*x2; a03 += e0*x3;
    a10 += e1*x0; a11 += e1*x1; a12 += e1*x2; a13 += e1*x3;
  }
  #pragma unroll
  for(int jj=0;jj<2;jj++){
    int j = j0+jj;
    int bj = b*16+j;
    float acc0 = (jj? a10:a00)*(1.f/16.f);
    float acc1 = (jj? a11:a01)*(1.f/16.f);
    float acc2 = (jj? a12:a02)*(1.f/16.f);
    float acc3 = (jj? a13:a03)*(1.f/16.f);
    {
      u16 pk[4]={f2bf(acc0),f2bf(acc1),f2bf(acc2),f2bf(acc3)};
      *(ushort4*)(xoutb + ((size_t)bj*256+s)*64 + fq*4) = *(ushort4*)pk;
    }
    float part = acc0+acc1+acc2+acc3;
    part += __shfl_xor(part,1); part += __shfl_xor(part,2);
    part += __shfl_xor(part,4); part += __shfl_xor(part,8);
    float mu = part*(1.f/64.f);
    float d0=acc0-mu, d1=acc1-mu, d2=acc2-mu, d3=acc3-mu;
    float p2 = d0*d0+d1*d1+d2*d2+d3*d3;
    p2 += __shfl_xor(p2,1); p2 += __shfl_xor(p2,2);
    p2 += __shfl_xor(p2,4); p2 += __shfl_xor(p2,8);
    float rstd = rsqrtf(p2*(1.f/64.f)+EPSLN);
    float4 lw4 = *(const float4*)(lnw + j*64 + fq*4);
    float4 lb4 = *(const float4*)(lnb + j*64 + fq*4);
    u16 xn[4] = { f2bf(d0*rstd*lw4.x + lb4.x), f2bf(d1*rstd*lw4.y + lb4.y),
                  f2bf(d2*rstd*lw4.z + lb4.z), f2bf(d3*rstd*lw4.w + lb4.w) };
    *(ushort4*)((unsigned char*)&xnS[jj][0] + ((sl*128 + fq*8) ^ ((sl&7)<<4))) = *(ushort4*)xn;
  }
  __syncthreads();
  int m = lane&15, kb = lane>>4;
  #pragma unroll
  for(int jj=0;jj<2;jj++){
    int j = j0+jj;
    int bj = b*16+j;
    f32x4 acc = {0.f,0.f,0.f,0.f};
    unsigned char* xnB = (unsigned char*)&xnS[jj][0];
    #pragma unroll
    for(int ks=0;ks<2;ks++){
      bf16x8 a = *(const bf16x8*)(xnB + ((m*128 + ks*64 + kb*16) ^ ((m&7)<<4)));
      bf16x8 bfr = *(const bf16x8*)(w2B + ((j*2+ks)*4 + w)*512 + lane*8);
      acc = __builtin_amdgcn_mfma_f32_16x16x32_bf16(a, bfr, acc, 0, 0, 0);
    }
    int f = w*16 + m;
    u16 pk[4];
    #pragma unroll
    for(int r=0;r<4;r++){
      int si = kb*4 + r;
      int s2 = st*16 + si;
      float xpr = acc[r] + bp[((size_t)j*256+s2)*64+f];
      xp[((size_t)bj*256+s2)*64+f] = xpr;
      pk[r] = f2bf(xpr);
    }
    int s0 = st*16 + kb*4;
    int flat = ((s0>>5)*4 + w)*512 + ((s0>>3)&3)*128 + m*8 + (s0&7);
    *(ushort4*)(xpB + (size_t)bj*16384 + flat) = *(ushort4*)pk;
  }
}

// F v4: stats precomputed; 4 j per block, 2 prob panels; LDS 25.5KB.
__global__ void __launch_bounds__(256) kF(
    const float* __restrict__ G, const float* __restrict__ cc,
    const float* __restrict__ mKv, const float* __restrict__ rKv,
    const float* __restrict__ mQv, const float* __restrict__ rQv,
    const float* __restrict__ xp, const u16* __restrict__ xpB,
    const float* __restrict__ cw,
    const u16* __restrict__ xarrb, const float* __restrict__ temp,
    const float* __restrict__ alpha, const float* __restrict__ beta,
    const float* __restrict__ gamma_, const float* __restrict__ theta,
    float* __restrict__ out){
  int b = blockIdx.x, jp = blockIdx.y, st = blockIdx.z;
  int j0 = jp*4;
  int tid = threadIdx.x, w = tid>>6, lane = tid&63;
  __shared__ __align__(16) unsigned char ovl[26112];
  unsigned char* prA = ovl;
  unsigned char* prB = ovl + 8192;
  float* xpT = (float*)ovl;
  float tv = fabsf(temp[0])+1e-4f;
  float inv = 1.f/(sqrtf(512.f)*tv);
  float aM0[8],aM1[8],aM2[8],aM3[8];
  #pragma unroll
  for(int m=0;m<8;m++){
    float4 ck = *(const float4*)(cc + (b*16+m  )*16 + j0);
    float4 cq = *(const float4*)(cc + (b*16+m+8)*16 + j0);
    aM0[m]=ck.x*cq.x; aM1[m]=ck.y*cq.y; aM2[m]=ck.z*cq.z; aM3[m]=ck.w*cq.w;
  }
  int bj0 = b*16+j0;
  float4 mQ4a = *(const float4*)(mQv + (size_t)(bj0  )*256 + lane*4);
  float4 rQ4a = *(const float4*)(rQv + (size_t)(bj0  )*256 + lane*4);
  float4 mQ4b = *(const float4*)(mQv + (size_t)(bj0+1)*256 + lane*4);
  float4 rQ4b = *(const float4*)(rQv + (size_t)(bj0+1)*256 + lane*4);
  float4 mQ4c = *(const float4*)(mQv + (size_t)(bj0+2)*256 + lane*4);
  float4 rQ4c = *(const float4*)(rQv + (size_t)(bj0+2)*256 + lane*4);
  float4 mQ4d = *(const float4*)(mQv + (size_t)(bj0+3)*256 + lane*4);
  float4 rQ4d = *(const float4*)(rQv + (size_t)(bj0+3)*256 + lane*4);
  const float* Gb = G + (size_t)(b*8)*65536;
  ushort4 pk2[4], pk3[4];   // j2/j3 probs held in registers
  #pragma unroll
  for(int q=0;q<4;q++){
    int si = w*4+q;
    int s = st*16 + si;
    f32x4 dt0={0.f,0.f,0.f,0.f}, dt1={0.f,0.f,0.f,0.f};
    f32x4 dt2={0.f,0.f,0.f,0.f}, dt3={0.f,0.f,0.f,0.f};
    #pragma unroll
    for(int m=0;m<8;m++){
      f32x4 g4 = *(const f32x4*)(Gb + (size_t)m*65536 + s*256 + lane*4);
      dt0 += aM0[m]*g4; dt1 += aM1[m]*g4;
      dt2 += aM2[m]*g4; dt3 += aM3[m]*g4;
    }
    // defer-max: LN'd rows => |raw| <= sqrt(512)/tv ~ 22.6, exp safe without max-sub
    #define SMK(JJ, DT, MQ, RQ, PKOUT) { \
      float mKs = 512.f*mKv[(size_t)(bj0+JJ)*256 + s], rKs = rKv[(size_t)(bj0+JJ)*256 + s]; \
      float e0 = __expf((DT[0] - mKs*MQ.x)*rKs*RQ.x*inv); \
      float e1 = __expf((DT[1] - mKs*MQ.y)*rKs*RQ.y*inv); \
      float e2 = __expf((DT[2] - mKs*MQ.z)*rKs*RQ.z*inv); \
      float e3 = __expf((DT[3] - mKs*MQ.w)*rKs*RQ.w*inv); \
      float isf = 1.f/wsum(e0+e1+e2+e3); \
      u16 pk[4] = {f2bf(e0*isf), f2bf(e1*isf), f2bf(e2*isf), f2bf(e3*isf)}; \
      PKOUT = *(ushort4*)pk; }
    ushort4 t0v, t1v;
    SMK(0, dt0, mQ4a, rQ4a, t0v)
    SMK(1, dt1, mQ4b, rQ4b, t1v)
    int poff = (si*512 + lane*8) ^ ((si&7)<<4);
    *(ushort4*)(prA + poff) = t0v;
    *(ushort4*)(prB + poff) = t1v;
    SMK(2, dt2, mQ4c, rQ4c, pk2[q])
    SMK(3, dt3, mQ4d, rQ4d, pk3[q])
    #undef SMK
  }
  __syncthreads();
  int m_ = lane&15, kb = lane>>4;
  f32x4 av0={0.f,0.f,0.f,0.f}, av1={0.f,0.f,0.f,0.f};
  f32x4 av2={0.f,0.f,0.f,0.f}, av3={0.f,0.f,0.f,0.f};
  const u16* xpB0 = xpB + (size_t)(bj0  )*16384;
  const u16* xpB1 = xpB + (size_t)(bj0+1)*16384;
  const u16* xpB2 = xpB + (size_t)(bj0+2)*16384;
  const u16* xpB3 = xpB + (size_t)(bj0+3)*16384;
  #pragma unroll
  for(int ks=0;ks<8;ks++){
    int aoff = (m_*512 + ks*64 + kb*16) ^ ((m_&7)<<4);
    int boff = ((ks*4 + w)*64 + lane)*8;
    bf16x8 a0 = *(const bf16x8*)(prA + aoff);
    bf16x8 a1 = *(const bf16x8*)(prB + aoff);
    av0 = __builtin_amdgcn_mfma_f32_16x16x32_bf16(a0, *(const bf16x8*)(xpB0 + boff), av0, 0,0,0);
    av1 = __builtin_amdgcn_mfma_f32_16x16x32_bf16(a1, *(const bf16x8*)(xpB1 + boff), av1, 0,0,0);
  }
  __syncthreads();   // AV(j0,j1) prob reads done -> panels reusable
  #pragma unroll
  for(int q=0;q<4;q++){
    int si = w*4+q;
    int poff = (si*512 + lane*8) ^ ((si&7)<<4);
    *(ushort4*)(prA + poff) = pk2[q];
    *(ushort4*)(prB + poff) = pk3[q];
  }
  __syncthreads();
  #pragma unroll
  for(int ks=0;ks<8;ks++){
    int aoff = (m_*512 + ks*64 + kb*16) ^ ((m_&7)<<4);
    int boff = ((ks*4 + w)*64 + lane)*8;
    bf16x8 a2 = *(const bf16x8*)(prA + aoff);
    bf16x8 a3 = *(const bf16x8*)(prB + aoff);
    av2 = __builtin_amdgcn_mfma_f32_16x16x32_bf16(a2, *(const bf16x8*)(xpB2 + boff), av2, 0,0,0);
    av3 = __builtin_amdgcn_mfma_f32_16x16x32_bf16(a3, *(const bf16x8*)(xpB3 + boff), av3, 0,0,0);
  }
  int f = w*16 + m_;
  #pragma unroll
  for(int pass=0; pass<2; pass++){
    __syncthreads();   // previous ovl readers done (probs or pass-0 xpT)
    for(int idx4 = tid; idx4 < 1536; idx4 += 256){
      int jj = idx4 / 768;
      int rem = idx4 - jj*768;
      int rr_i = rem >> 8;
      int pos = rem & 255;
      int ci = pos>>4, f4 = pos&15;
      int grow = st - 1 + rr_i;
      float4 v = {0.f,0.f,0.f,0.f};
      if(grow>=0 && grow<16){
        v = *(const float4*)(xp + ((size_t)(b*16+j0+pass*2+jj)*256 + grow*16 + ci)*64 + f4*4);
      }
      *(float4*)(xpT + ((jj*3+rr_i)*16+ci)*68 + f4*4) = v;
    }
    __syncthreads();
    #pragma unroll
    for(int jj=0;jj<2;jj++){
      int j = j0 + pass*2 + jj;
      int bj = b*16+j;
      f32x4 acc = pass==0 ? (jj?av1:av0) : (jj?av3:av2);
      float al = fabsf(alpha[j]), be=fabsf(beta[j]), th=fabsf(theta[j]), ga=gamma_[j];
      const float* wq = cw + (j*64+f)*9;
      float w0=wq[0],w1=wq[1],w2=wq[2],w3v=wq[3],w4=wq[4],w5=wq[5],w6=wq[6],w7=wq[7],w8=wq[8];
      #pragma unroll
      for(int r=0;r<4;r++){
        int si = kb*4 + r;
        int s = st*16 + si;
        float gl = acc[r];
        float cv=0.f;
        #pragma unroll
        for(int dr=0;dr<3;dr++){
          float kw0 = dr==0?w0:(dr==1?w3v:w6);
          float kw1 = dr==0?w1:(dr==1?w4:w7);
          float kw2 = dr==0?w2:(dr==1?w5:w8);
          const float* rowp = xpT + ((jj*3+dr)*16)*68;
          if(si>0)  cv += rowp[(si-1)*68+f]*kw0;
                    cv += rowp[(si  )*68+f]*kw1;
          if(si<15) cv += rowp[(si+1)*68+f]*kw2;
        }
        float diag = xpT[((jj*3+1)*16+si)*68+f];
        size_t gi = ((size_t)bj*256+s)*64+f;
        out[gi] = be*gl + al*diag + th*cv + ga*bf2f(xarrb[gi]);
      }
    }
  }
}

extern "C" void kernel_launch(void* const* d_in, const int* in_sizes, int n_in,
                              void* d_out, int out_size, void* d_ws, size_t ws_size,
                              hipStream_t stream) {
  const float* xin = (const float*)d_in[0];
  const float* pxp = (const float*)d_in[1];
  const float* sw  = (const float*)d_in[2];
  const float* bs  = (const float*)d_in[3];
  const float* tau = (const float*)d_in[4];
  const float* temp= (const float*)d_in[5];
  const float* om  = (const float*)d_in[6];
  const float* W2  = (const float*)d_in[7];
  const float* bp  = (const float*)d_in[8];
  const float* lnw = (const float*)d_in[9];
  const float* lnb = (const float*)d_in[10];
  const float* alpha=(const float*)d_in[11];
  const float* beta= (const float*)d_in[12];
  const float* gam = (const float*)d_in[13];
  const float* theta=(const float*)d_in[14];
  const float* cw  = (const float*)d_in[15];
  float* outp = (float*)d_out;
  float* xpo  = outp + 2097152;   // x_prime = second output

  float* ws  = (float*)d_ws;
  float* xe  = ws;                // 32768
  float* xa  = xe + 32768;        // 32768
  float* Sv  = xa + 32768;        // 32768
  float* SSv = Sv + 32768;        // 32768
  u16*   er2b= (u16*)(SSv + 32768);   // 524288 u16, layout [bi][s][16 j]
  float* mask= (float*)(er2b) + 524288;
  float* ccv = mask + 2048;       // 2048
  float* mKv = ccv + 2048;        // 32768
  float* rKv = mKv + 32768;       // 32768
  float* mQv = rKv + 32768;       // 32768
  float* rQv = mQv + 32768;       // 32768
  float* Gv  = rQv + 32768;       // 4194304
  u16* xvb = (u16*)(Gv + 4194304);    // 2097152 u16 (bf16 x)
  u16* xpB = xvb + 2097152;           // 2097152 u16
  u16* w2B = xpB + 2097152;           // 65536 u16
  u16* xinb= w2B + 65536;             // 2097152 u16
  u16* phi = xinb + 2097152;          // 2097152 u16
  u16* plo = phi + 2097152;           // 2097152 u16

  kA<<<1024,256,0,stream>>>(xin,pxp,W2,xe,xa,Sv,SSv,xinb,phi,plo,w2B);
  kBE<<<1152,256,0,stream>>>(xe,sw,bs,om,xa,tau,temp,er2b,mask,ccv,phi,plo,Gv);
  kD<<<1152,256,0,stream>>>(xinb,er2b,mask,w2B,lnw,lnb,bp,xvb,xpo,xpB,
                            Sv,SSv,ccv,mKv,rKv,mQv,rQv);
  kF<<<dim3(8,4,16),256,0,stream>>>(Gv,ccv,mKv,rKv,mQv,rQv,xpo,xpB,cw,xvb,temp,
                                    alpha,beta,gam,theta,outp);
}

// Round 19
// 50.192 us; speedup vs baseline: 1.4491x; 1.0491x over previous
//
#include <hip/hip_runtime.h>

#define EPSLN 1e-5f

typedef short bf16x8 __attribute__((ext_vector_type(8)));
typedef float f32x4 __attribute__((ext_vector_type(4)));
typedef unsigned short u16;
typedef unsigned short u16x8 __attribute__((ext_vector_type(8)));

__device__ __forceinline__ float wsum(float v){
  #pragma unroll
  for(int o=32;o;o>>=1) v += __shfl_xor(v,o);
  return v;
}
__device__ __forceinline__ float wmax(float v){
  #pragma unroll
  for(int o=32;o;o>>=1) v = fmaxf(v,__shfl_xor(v,o));
  return v;
}
__device__ __forceinline__ u16 f2bf(float f){
  unsigned int u = __float_as_uint(f);
  u = (u + 0x7FFFu + ((u>>16)&1u)) >> 16;
  return (u16)u;
}
__device__ __forceinline__ float bf2f(u16 h){
  return __uint_as_float(((unsigned int)h)<<16);
}

// k1: blocks 0..127 = kB-self (xe/xa recomputed from xin; er2 bf16 [bi][s][16j]);
//     blocks 128..1151 = kA-lite (Sv/SSv + bf16 packs; W2 pack on 128..143).
__global__ void __launch_bounds__(256) k1(
    const float* __restrict__ xin, const float* __restrict__ pxp,
    const float* __restrict__ W2,  const float* __restrict__ sw,
    const float* __restrict__ bs,  const float* __restrict__ om,
    const float* __restrict__ tau, const float* __restrict__ temp,
    float* __restrict__ Sv, float* __restrict__ SSv,
    u16* __restrict__ xinb, u16* __restrict__ phi, u16* __restrict__ plo,
    u16* __restrict__ w2B,
    u16* __restrict__ er2b, float* __restrict__ mask, float* __restrict__ cc){
  __shared__ float shmF[1172];   // swL 1072 | bsL 16 | omL 16 | red 4 | redE 64
  int tid = threadIdx.x;
  if(blockIdx.x < 128){
    // ---- kB body (xe/xa self-computed) ----
    float* swL = shmF;
    float* bsL = swL + 1072;
    float* omL = bsL + 16;
    float* red = omL + 16;
    float* redE= red + 4;              // [16][4]
    int bi = blockIdx.x;               // (b*16+i)
    int i = bi & 15;
    int w = tid>>6, lane = tid&63;
    for(int k=tid;k<16*67;k+=256) swL[k] = sw[i*16*67 + k];
    if(tid<16){ bsL[tid]=bs[i*16+tid]; omL[tid]=fabsf(om[i*16+tid]); }
    float xs=0.f, xas=0.f;
    {
      const float4* xr = (const float4*)(xin + ((size_t)bi*256 + tid)*64);
      #pragma unroll
      for(int k=0;k<16;k++){
        float4 v4 = xr[k];
        xs  += v4.x+v4.y+v4.z+v4.w;
        xas += fabsf(v4.x)+fabsf(v4.y)+fabsf(v4.z)+fabsf(v4.w);
      }
    }
    float v   = xs *(1.f/64.f);
    float xav = xas*(1.f/64.f);
    float m = wmax(fabsf(v));
    if(lane==0) red[w]=m;
    __syncthreads();
    m = fmaxf(fmaxf(red[0],red[1]),fmaxf(red[2],red[3]));
    float xn = v/(m+1e-8f);
    xn = fminf(fmaxf(xn,-0.99f),0.99f);
    float sil = xn/(1.f+expf(-xn));
    float vv = (xn+1.f)*33.f;
    int c0 = (int)floorf(vv)-1;
    float acc[16];
    #pragma unroll
    for(int j=0;j<16;j++) acc[j]=0.f;
    #pragma unroll
    for(int k=0;k<4;k++){
      int c = c0+k;
      if(c<0||c>66) continue;
      float d = fabsf(vv-(float)c);
      float bas = d<1.f ? (2.f/3.f - d*d + d*d*d*0.5f)
                : (d<2.f ? (2.f-d)*(2.f-d)*(2.f-d)*(1.f/6.f) : 0.f);
      #pragma unroll
      for(int j=0;j<16;j++) acc[j] += bas*swL[j*67+c];
    }
    u16 evb[16];
    #pragma unroll
    for(int j=0;j<16;j++){
      float ev = sil*bsL[j] + acc[j] + omL[j];
      evb[j] = f2bf(ev);
      float pe = wsum(fabsf(ev)*xav);
      if(lane==0) redE[j*4+w]=pe;
    }
    *(u16x8*)(er2b + ((size_t)bi*256+tid)*16    ) = *(u16x8*)&evb[0];
    *(u16x8*)(er2b + ((size_t)bi*256+tid)*16 + 8) = *(u16x8*)&evb[8];
    __syncthreads();
    if(tid<16){
      float e = (redE[tid*4+0]+redE[tid*4+1]+redE[tid*4+2]+redE[tid*4+3])*(1.f/256.f);
      float tv = fabsf(temp[0])+1e-4f;
      float ta = fabsf(tau[i*16+tid]);
      float mk = 1.f/(1.f+expf(-(e-ta)/tv));
      mask[bi*16+tid]=mk;
      cc[bi*16+tid]= e/(ta+1e-8f)*mk;
    }
  } else {
    // ---- kA-lite body ----
    int ab = blockIdx.x - 128;
    int rl = tid>>3, q = tid&7;
    int row = ab*32 + rl;
    const float4* xr = (const float4*)(xin + row*64 + q*8);
    const float4* pr = (const float4*)(pxp + row*64 + q*8);
    float s3=0.f,s4=0.f;
    u16x8 xb, ph, pl;
    #pragma unroll
    for(int k=0;k<2;k++){
      float4 xv = xr[k];
      float4 pv = pr[k];
      s3 += pv.x+pv.y+pv.z+pv.w;
      s4 += pv.x*pv.x+pv.y*pv.y+pv.z*pv.z+pv.w*pv.w;
      int o = k*4;
      xb[o+0]=f2bf(xv.x); xb[o+1]=f2bf(xv.y); xb[o+2]=f2bf(xv.z); xb[o+3]=f2bf(xv.w);
      u16 h0=f2bf(pv.x), h1=f2bf(pv.y), h2=f2bf(pv.z), h3=f2bf(pv.w);
      ph[o+0]=h0; ph[o+1]=h1; ph[o+2]=h2; ph[o+3]=h3;
      pl[o+0]=f2bf(pv.x-bf2f(h0)); pl[o+1]=f2bf(pv.y-bf2f(h1));
      pl[o+2]=f2bf(pv.z-bf2f(h2)); pl[o+3]=f2bf(pv.w-bf2f(h3));
    }
    *(u16x8*)(xinb + row*64 + q*8) = xb;
    *(u16x8*)(phi  + row*64 + q*8) = ph;
    *(u16x8*)(plo  + row*64 + q*8) = pl;
    s3 += __shfl_xor(s3,1); s3 += __shfl_xor(s3,2); s3 += __shfl_xor(s3,4);
    s4 += __shfl_xor(s4,1); s4 += __shfl_xor(s4,2); s4 += __shfl_xor(s4,4);
    if(q==0){ Sv[row]=s3; SSv[row]=s4; }
    if(ab<16){
      int j = ab;
      for(int idx=tid; idx<4096; idx+=256){
        int f = idx>>6, o = idx&63;
        float vw = W2[j*4096 + idx];
        int ks = f>>5, kb = (f>>3)&3, ii = f&7;
        int nt = o>>4, col = o&15;
        int ln = kb*16 + col;
        w2B[((j*2+ks)*4 + nt)*512 + ln*8 + ii] = f2bf(vw);
      }
    }
  }
}

// k2: blocks 0..1023 = E2 gram MFMA (LDS-staged); blocks 1024..2047 = kD-2j;
//     blocks 2048..2175 = LN stats. 32KB LDS union (kD 4/CU < 5/CU cap).
__global__ void __launch_bounds__(256) k2(
    const u16* __restrict__ phi, const u16* __restrict__ plo, float* __restrict__ G,
    const u16* __restrict__ xinb, const u16* __restrict__ er2b,
    const float* __restrict__ mask, const u16* __restrict__ w2B,
    const float* __restrict__ lnw, const float* __restrict__ lnb,
    const float* __restrict__ bp,
    u16* __restrict__ xvb, float* __restrict__ xp, u16* __restrict__ xpB,
    const float* __restrict__ Sv, const float* __restrict__ SSv,
    const float* __restrict__ cc,
    float* __restrict__ mKv, float* __restrict__ rKv,
    float* __restrict__ mQv, float* __restrict__ rQv){
  __shared__ __align__(16) unsigned char shm[32768];
  int tid = threadIdx.x;
  int bid = blockIdx.x;
  if(bid < 1024){
    // ---- E2 body (LDS-staged, proven) ----
    u16* AfB = (u16*)shm;
    u16* BfB = AfB + 8192;
    int e = bid;
    int b = e&7, m = (e>>3)&7, sx = (e>>6)&3, ty = e>>8;  // b lowest -> XCD=b
    int bm = b*8+m;
    int s0 = sx*64, t0 = ty*64;
    int row = tid>>2, dseg = tid&3;
    size_t offA = ((size_t)(b*16+m  )*256 + s0 + row)*64 + dseg*16;
    size_t offB = ((size_t)(b*16+m+8)*256 + t0 + row)*64 + dseg*16;
    int d0 = dseg*16;
    int ks0 = d0>>5, kb0 = (d0>>3)&3;
    int ks1 = (d0+8)>>5, kb1 = ((d0+8)>>3)&3;
    int lr = row&15, stile = row>>4;
    #define AOFF(h,stl,ks,ln) (((((h)*4+(stl))*2+(ks))*64 + (ln))*8)
    {
      uint4 v0 = *(const uint4*)(phi + offA);
      uint4 v1 = *(const uint4*)(phi + offA + 8);
      *(uint4*)(AfB + AOFF(0,stile,ks0,kb0*16+lr)) = v0;
      *(uint4*)(AfB + AOFF(0,stile,ks1,kb1*16+lr)) = v1;
      uint4 w0 = *(const uint4*)(plo + offA);
      uint4 w1 = *(const uint4*)(plo + offA + 8);
      *(uint4*)(AfB + AOFF(1,stile,ks0,kb0*16+lr)) = w0;
      *(uint4*)(AfB + AOFF(1,stile,ks1,kb1*16+lr)) = w1;
      uint4 x0 = *(const uint4*)(phi + offB);
      uint4 x1 = *(const uint4*)(phi + offB + 8);
      *(uint4*)(BfB + AOFF(0,stile,ks0,kb0*16+lr)) = x0;
      *(uint4*)(BfB + AOFF(0,stile,ks1,kb1*16+lr)) = x1;
      uint4 y0 = *(const uint4*)(plo + offB);
      uint4 y1 = *(const uint4*)(plo + offB + 8);
      *(uint4*)(BfB + AOFF(1,stile,ks0,kb0*16+lr)) = y0;
      *(uint4*)(BfB + AOFF(1,stile,ks1,kb1*16+lr)) = y1;
    }
    __syncthreads();
    int w = tid>>6, lane = tid&63;
    bf16x8 ah0 = *(const bf16x8*)(AfB + AOFF(0,w,0,lane));
    bf16x8 ah1 = *(const bf16x8*)(AfB + AOFF(0,w,1,lane));
    bf16x8 al0 = *(const bf16x8*)(AfB + AOFF(1,w,0,lane));
    bf16x8 al1 = *(const bf16x8*)(AfB + AOFF(1,w,1,lane));
    f32x4 acc[4];
    #pragma unroll
    for(int tt=0;tt<4;tt++) acc[tt] = (f32x4){0.f,0.f,0.f,0.f};
    #pragma unroll
    for(int tt=0;tt<4;tt++){
      bf16x8 bh0 = *(const bf16x8*)(BfB + AOFF(0,tt,0,lane));
      bf16x8 bh1 = *(const bf16x8*)(BfB + AOFF(0,tt,1,lane));
      bf16x8 bl0 = *(const bf16x8*)(BfB + AOFF(1,tt,0,lane));
      bf16x8 bl1 = *(const bf16x8*)(BfB + AOFF(1,tt,1,lane));
      acc[tt] = __builtin_amdgcn_mfma_f32_16x16x32_bf16(ah0, bh0, acc[tt], 0,0,0);
      acc[tt] = __builtin_amdgcn_mfma_f32_16x16x32_bf16(ah1, bh1, acc[tt], 0,0,0);
      acc[tt] = __builtin_amdgcn_mfma_f32_16x16x32_bf16(ah0, bl0, acc[tt], 0,0,0);
      acc[tt] = __builtin_amdgcn_mfma_f32_16x16x32_bf16(ah1, bl1, acc[tt], 0,0,0);
      acc[tt] = __builtin_amdgcn_mfma_f32_16x16x32_bf16(al0, bh0, acc[tt], 0,0,0);
      acc[tt] = __builtin_amdgcn_mfma_f32_16x16x32_bf16(al1, bh1, acc[tt], 0,0,0);
    }
    int col = lane&15, r4 = lane>>4;
    #pragma unroll
    for(int tt=0;tt<4;tt++){
      #pragma unroll
      for(int r=0;r<4;r++){
        G[((size_t)bm*256 + s0 + w*16 + r4*4 + r)*256 + t0 + tt*16 + col] = acc[tt][r];
      }
    }
    #undef AOFF
  } else if(bid < 2048){
    // ---- kD-2j body ----
    int idx = bid - 1024;               // 1024%8==0 -> XCD = b preserved
    int b = idx&7, jq = (idx>>3)&7, st = idx>>6;
    int j0 = jq*2;
    int w = tid>>6, lane = tid&63;
    u16* xnS = (u16*)shm;               // [2][1024] u16
    float* mcL = (float*)(shm + 4096);  // [32]
    if(tid<32) mcL[tid] = mask[(b*16+(tid>>1))*16 + j0 + (tid&1)];
    __syncthreads();
    int ss = lane>>4, fq = lane&15;
    int sl = w*4 + ss;
    int s  = st*16 + sl;
    float a00=0.f,a01=0.f,a02=0.f,a03=0.f;
    float a10=0.f,a11=0.f,a12=0.f,a13=0.f;
    #pragma unroll
    for(int i=0;i<16;i++){
      unsigned int epk = *(const unsigned int*)(er2b + ((size_t)((b*16+i)*256+s))*16 + j0);
      float e0 = bf2f((u16)(epk&0xFFFFu))*mcL[i*2+0];
      float e1 = bf2f((u16)(epk>>16))   *mcL[i*2+1];
      ushort4 xv = *(const ushort4*)(xinb + ((size_t)(b*16+i)*256+s)*64 + fq*4);
      float x0=bf2f(xv.x), x1=bf2f(xv.y), x2=bf2f(xv.z), x3=bf2f(xv.w);
      a00 += e0*x0; a01 += e0*x1; a02 += e0*x2; a03 += e0*x3;
      a10 += e1*x0; a11 += e1*x1; a12 += e1*x2; a13 += e1*x3;
    }
    #pragma unroll
    for(int jj=0;jj<2;jj++){
      int j = j0+jj;
      int bj = b*16+j;
      float acc0 = (jj? a10:a00)*(1.f/16.f);
      float acc1 = (jj? a11:a01)*(1.f/16.f);
      float acc2 = (jj? a12:a02)*(1.f/16.f);
      float acc3 = (jj? a13:a03)*(1.f/16.f);
      {
        u16 pk[4]={f2bf(acc0),f2bf(acc1),f2bf(acc2),f2bf(acc3)};
        *(ushort4*)(xvb + ((size_t)bj*256+s)*64 + fq*4) = *(ushort4*)pk;
      }
      float part = acc0+acc1+acc2+acc3;
      part += __shfl_xor(part,1); part += __shfl_xor(part,2);
      part += __shfl_xor(part,4); part += __shfl_xor(part,8);
      float mu = part*(1.f/64.f);
      float d0=acc0-mu, d1=acc1-mu, d2=acc2-mu, d3=acc3-mu;
      float p2 = d0*d0+d1*d1+d2*d2+d3*d3;
      p2 += __shfl_xor(p2,1); p2 += __shfl_xor(p2,2);
      p2 += __shfl_xor(p2,4); p2 += __shfl_xor(p2,8);
      float rstd = rsqrtf(p2*(1.f/64.f)+EPSLN);
      float4 lw4 = *(const float4*)(lnw + j*64 + fq*4);
      float4 lb4 = *(const float4*)(lnb + j*64 + fq*4);
      u16 xn[4] = { f2bf(d0*rstd*lw4.x + lb4.x), f2bf(d1*rstd*lw4.y + lb4.y),
                    f2bf(d2*rstd*lw4.z + lb4.z), f2bf(d3*rstd*lw4.w + lb4.w) };
      *(ushort4*)((unsigned char*)(xnS + jj*1024) + ((sl*128 + fq*8) ^ ((sl&7)<<4))) = *(ushort4*)xn;
    }
    __syncthreads();
    int m = lane&15, kb = lane>>4;
    #pragma unroll
    for(int jj=0;jj<2;jj++){
      int j = j0+jj;
      int bj = b*16+j;
      f32x4 acc = {0.f,0.f,0.f,0.f};
      unsigned char* xnB = (unsigned char*)(xnS + jj*1024);
      #pragma unroll
      for(int ks=0;ks<2;ks++){
        bf16x8 a = *(const bf16x8*)(xnB + ((m*128 + ks*64 + kb*16) ^ ((m&7)<<4)));
        bf16x8 bfr = *(const bf16x8*)(w2B + ((j*2+ks)*4 + w)*512 + lane*8);
        acc = __builtin_amdgcn_mfma_f32_16x16x32_bf16(a, bfr, acc, 0, 0, 0);
      }
      int f = w*16 + m;
      u16 pk[4];
      #pragma unroll
      for(int r=0;r<4;r++){
        int si = kb*4 + r;
        int s2 = st*16 + si;
        float xpr = acc[r] + bp[((size_t)j*256+s2)*64+f];
        xp[((size_t)bj*256+s2)*64+f] = xpr;
        pk[r] = f2bf(xpr);
      }
      int s0 = st*16 + kb*4;
      int flat = ((s0>>5)*4 + w)*512 + ((s0>>3)&3)*128 + m*8 + (s0&7);
      *(ushort4*)(xpB + (size_t)bj*16384 + flat) = *(ushort4*)pk;
    }
  } else {
    // ---- LN stats for (b,j): closed form from Sv/SSv ----
    int sid = bid - 2048;
    int b = sid&7, j = sid>>3;
    int t = tid;
    float sk=0,ssk=0,sq=0,ssq=0;
    #pragma unroll
    for(int m=0;m<8;m++){
      float ck = cc[(b*16+m)*16+j];
      float cq = cc[(b*16+m+8)*16+j];
      sk  += ck*Sv[(b*16+m)*256+t];
      ssk += ck*ck*SSv[(b*16+m)*256+t];
      sq  += cq*Sv[(b*16+m+8)*256+t];
      ssq += cq*cq*SSv[(b*16+m+8)*256+t];
    }
    float mk = sk*(1.f/512.f);
    float vk = ssk*(1.f/512.f) - mk*mk;
    float mq = sq*(1.f/512.f);
    float vq = ssq*(1.f/512.f) - mq*mq;
    int o = (b*16+j)*256+t;
    mKv[o]=mk; rKv[o]=rsqrtf(vk+EPSLN);
    mQv[o]=mq; rQv[o]=rsqrtf(vq+EPSLN);
  }
}

// F v4: stats precomputed; 4 j per block, 2 prob panels; LDS 25.5KB.
__global__ void __launch_bounds__(256) kF(
    const float* __restrict__ G, const float* __restrict__ cc,
    const float* __restrict__ mKv, const float* __restrict__ rKv,
    const float* __restrict__ mQv, const float* __restrict__ rQv,
    const float* __restrict__ xp, const u16* __restrict__ xpB,
    const float* __restrict__ cw,
    const u16* __restrict__ xarrb, const float* __restrict__ temp,
    const float* __restrict__ alpha, const float* __restrict__ beta,
    const float* __restrict__ gamma_, const float* __restrict__ theta,
    float* __restrict__ out){
  int b = blockIdx.x, jp = blockIdx.y, st = blockIdx.z;
  int j0 = jp*4;
  int tid = threadIdx.x, w = tid>>6, lane = tid&63;
  __shared__ __align__(16) unsigned char ovl[26112];
  unsigned char* prA = ovl;
  unsigned char* prB = ovl + 8192;
  float* xpT = (float*)ovl;
  float tv = fabsf(temp[0])+1e-4f;
  float inv = 1.f/(sqrtf(512.f)*tv);
  float aM0[8],aM1[8],aM2[8],aM3[8];
  #pragma unroll
  for(int m=0;m<8;m++){
    float4 ck = *(const float4*)(cc + (b*16+m  )*16 + j0);
    float4 cq = *(const float4*)(cc + (b*16+m+8)*16 + j0);
    aM0[m]=ck.x*cq.x; aM1[m]=ck.y*cq.y; aM2[m]=ck.z*cq.z; aM3[m]=ck.w*cq.w;
  }
  int bj0 = b*16+j0;
  float4 mQ4a = *(const float4*)(mQv + (size_t)(bj0  )*256 + lane*4);
  float4 rQ4a = *(const float4*)(rQv + (size_t)(bj0  )*256 + lane*4);
  float4 mQ4b = *(const float4*)(mQv + (size_t)(bj0+1)*256 + lane*4);
  float4 rQ4b = *(const float4*)(rQv + (size_t)(bj0+1)*256 + lane*4);
  float4 mQ4c = *(const float4*)(mQv + (size_t)(bj0+2)*256 + lane*4);
  float4 rQ4c = *(const float4*)(rQv + (size_t)(bj0+2)*256 + lane*4);
  float4 mQ4d = *(const float4*)(mQv + (size_t)(bj0+3)*256 + lane*4);
  float4 rQ4d = *(const float4*)(rQv + (size_t)(bj0+3)*256 + lane*4);
  const float* Gb = G + (size_t)(b*8)*65536;
  ushort4 pk2[4], pk3[4];   // j2/j3 probs held in registers
  #pragma unroll
  for(int q=0;q<4;q++){
    int si = w*4+q;
    int s = st*16 + si;
    f32x4 dt0={0.f,0.f,0.f,0.f}, dt1={0.f,0.f,0.f,0.f};
    f32x4 dt2={0.f,0.f,0.f,0.f}, dt3={0.f,0.f,0.f,0.f};
    #pragma unroll
    for(int m=0;m<8;m++){
      f32x4 g4 = *(const f32x4*)(Gb + (size_t)m*65536 + s*256 + lane*4);
      dt0 += aM0[m]*g4; dt1 += aM1[m]*g4;
      dt2 += aM2[m]*g4; dt3 += aM3[m]*g4;
    }
    // defer-max: LN'd rows => |raw| <= sqrt(512)/tv ~ 22.6, exp safe without max-sub
    #define SMK(JJ, DT, MQ, RQ, PKOUT) { \
      float mKs = 512.f*mKv[(size_t)(bj0+JJ)*256 + s], rKs = rKv[(size_t)(bj0+JJ)*256 + s]; \
      float e0 = __expf((DT[0] - mKs*MQ.x)*rKs*RQ.x*inv); \
      float e1 = __expf((DT[1] - mKs*MQ.y)*rKs*RQ.y*inv); \
      float e2 = __expf((DT[2] - mKs*MQ.z)*rKs*RQ.z*inv); \
      float e3 = __expf((DT[3] - mKs*MQ.w)*rKs*RQ.w*inv); \
      float isf = 1.f/wsum(e0+e1+e2+e3); \
      u16 pk[4] = {f2bf(e0*isf), f2bf(e1*isf), f2bf(e2*isf), f2bf(e3*isf)}; \
      PKOUT = *(ushort4*)pk; }
    ushort4 t0v, t1v;
    SMK(0, dt0, mQ4a, rQ4a, t0v)
    SMK(1, dt1, mQ4b, rQ4b, t1v)
    int poff = (si*512 + lane*8) ^ ((si&7)<<4);
    *(ushort4*)(prA + poff) = t0v;
    *(ushort4*)(prB + poff) = t1v;
    SMK(2, dt2, mQ4c, rQ4c, pk2[q])
    SMK(3, dt3, mQ4d, rQ4d, pk3[q])
    #undef SMK
  }
  __syncthreads();
  int m_ = lane&15, kb = lane>>4;
  f32x4 av0={0.f,0.f,0.f,0.f}, av1={0.f,0.f,0.f,0.f};
  f32x4 av2={0.f,0.f,0.f,0.f}, av3={0.f,0.f,0.f,0.f};
  const u16* xpB0 = xpB + (size_t)(bj0  )*16384;
  const u16* xpB1 = xpB + (size_t)(bj0+1)*16384;
  const u16* xpB2 = xpB + (size_t)(bj0+2)*16384;
  const u16* xpB3 = xpB + (size_t)(bj0+3)*16384;
  #pragma unroll
  for(int ks=0;ks<8;ks++){
    int aoff = (m_*512 + ks*64 + kb*16) ^ ((m_&7)<<4);
    int boff = ((ks*4 + w)*64 + lane)*8;
    bf16x8 a0 = *(const bf16x8*)(prA + aoff);
    bf16x8 a1 = *(const bf16x8*)(prB + aoff);
    av0 = __builtin_amdgcn_mfma_f32_16x16x32_bf16(a0, *(const bf16x8*)(xpB0 + boff), av0, 0,0,0);
    av1 = __builtin_amdgcn_mfma_f32_16x16x32_bf16(a1, *(const bf16x8*)(xpB1 + boff), av1, 0,0,0);
  }
  __syncthreads();   // AV(j0,j1) prob reads done -> panels reusable
  #pragma unroll
  for(int q=0;q<4;q++){
    int si = w*4+q;
    int poff = (si*512 + lane*8) ^ ((si&7)<<4);
    *(ushort4*)(prA + poff) = pk2[q];
    *(ushort4*)(prB + poff) = pk3[q];
  }
  __syncthreads();
  #pragma unroll
  for(int ks=0;ks<8;ks++){
    int aoff = (m_*512 + ks*64 + kb*16) ^ ((m_&7)<<4);
    int boff = ((ks*4 + w)*64 + lane)*8;
    bf16x8 a2 = *(const bf16x8*)(prA + aoff);
    bf16x8 a3 = *(const bf16x8*)(prB + aoff);
    av2 = __builtin_amdgcn_mfma_f32_16x16x32_bf16(a2, *(const bf16x8*)(xpB2 + boff), av2, 0,0,0);
    av3 = __builtin_amdgcn_mfma_f32_16x16x32_bf16(a3, *(const bf16x8*)(xpB3 + boff), av3, 0,0,0);
  }
  int f = w*16 + m_;
  #pragma unroll
  for(int pass=0; pass<2; pass++){
    __syncthreads();   // previous ovl readers done (probs or pass-0 xpT)
    for(int idx4 = tid; idx4 < 1536; idx4 += 256){
      int jj = idx4 / 768;
      int rem = idx4 - jj*768;
      int rr_i = rem >> 8;
      int pos = rem & 255;
      int ci = pos>>4, f4 = pos&15;
      int grow = st - 1 + rr_i;
      float4 v = {0.f,0.f,0.f,0.f};
      if(grow>=0 && grow<16){
        v = *(const float4*)(xp + ((size_t)(b*16+j0+pass*2+jj)*256 + grow*16 + ci)*64 + f4*4);
      }
      *(float4*)(xpT + ((jj*3+rr_i)*16+ci)*68 + f4*4) = v;
    }
    __syncthreads();
    #pragma unroll
    for(int jj=0;jj<2;jj++){
      int j = j0 + pass*2 + jj;
      int bj = b*16+j;
      f32x4 acc = pass==0 ? (jj?av1:av0) : (jj?av3:av2);
      float al = fabsf(alpha[j]), be=fabsf(beta[j]), th=fabsf(theta[j]), ga=gamma_[j];
      const float* wq = cw + (j*64+f)*9;
      float w0=wq[0],w1=wq[1],w2=wq[2],w3v=wq[3],w4=wq[4],w5=wq[5],w6=wq[6],w7=wq[7],w8=wq[8];
      #pragma unroll
      for(int r=0;r<4;r++){
        int si = kb*4 + r;
        int s = st*16 + si;
        float gl = acc[r];
        float cv=0.f;
        #pragma unroll
        for(int dr=0;dr<3;dr++){
          float kw0 = dr==0?w0:(dr==1?w3v:w6);
          float kw1 = dr==0?w1:(dr==1?w4:w7);
          float kw2 = dr==0?w2:(dr==1?w5:w8);
          const float* rowp = xpT + ((jj*3+dr)*16)*68;
          if(si>0)  cv += rowp[(si-1)*68+f]*kw0;
                    cv += rowp[(si  )*68+f]*kw1;
          if(si<15) cv += rowp[(si+1)*68+f]*kw2;
        }
        float diag = xpT[((jj*3+1)*16+si)*68+f];
        size_t gi = ((size_t)bj*256+s)*64+f;
        out[gi] = be*gl + al*diag + th*cv + ga*bf2f(xarrb[gi]);
      }
    }
  }
}

extern "C" void kernel_launch(void* const* d_in, const int* in_sizes, int n_in,
                              void* d_out, int out_size, void* d_ws, size_t ws_size,
                              hipStream_t stream) {
  const float* xin = (const float*)d_in[0];
  const float* pxp = (const float*)d_in[1];
  const float* sw  = (const float*)d_in[2];
  const float* bs  = (const float*)d_in[3];
  const float* tau = (const float*)d_in[4];
  const float* temp= (const float*)d_in[5];
  const float* om  = (const float*)d_in[6];
  const float* W2  = (const float*)d_in[7];
  const float* bp  = (const float*)d_in[8];
  const float* lnw = (const float*)d_in[9];
  const float* lnb = (const float*)d_in[10];
  const float* alpha=(const float*)d_in[11];
  const float* beta= (const float*)d_in[12];
  const float* gam = (const float*)d_in[13];
  const float* theta=(const float*)d_in[14];
  const float* cw  = (const float*)d_in[15];
  float* outp = (float*)d_out;
  float* xpo  = outp + 2097152;   // x_prime = second output

  float* ws  = (float*)d_ws;
  float* Sv  = ws;                // 32768
  float* SSv = Sv + 32768;        // 32768
  u16*   er2b= (u16*)(SSv + 32768);   // 524288 u16, layout [bi][s][16 j]
  float* mask= (float*)(er2b) + 524288;
  float* ccv = mask + 2048;       // 2048
  float* mKv = ccv + 2048;        // 32768
  float* rKv = mKv + 32768;       // 32768
  float* mQv = rKv + 32768;       // 32768
  float* rQv = mQv + 32768;       // 32768
  float* Gv  = rQv + 32768;       // 4194304
  u16* xvb = (u16*)(Gv + 4194304);    // 2097152 u16 (bf16 x)
  u16* xpB = xvb + 2097152;           // 2097152 u16
  u16* w2B = xpB + 2097152;           // 65536 u16
  u16* xinb= w2B + 65536;             // 2097152 u16
  u16* phi = xinb + 2097152;          // 2097152 u16
  u16* plo = phi + 2097152;           // 2097152 u16

  k1<<<1152,256,0,stream>>>(xin,pxp,W2,sw,bs,om,tau,temp,
                            Sv,SSv,xinb,phi,plo,w2B,er2b,mask,ccv);
  k2<<<2176,256,0,stream>>>(phi,plo,Gv,xinb,er2b,mask,w2B,lnw,lnb,bp,
                            xvb,xpo,xpB,Sv,SSv,ccv,mKv,rKv,mQv,rQv);
  kF<<<dim3(8,4,16),256,0,stream>>>(Gv,ccv,mKv,rKv,mQv,rQv,xpo,xpB,cw,xvb,temp,
                                    alpha,beta,gam,theta,outp);
}